// Round 2
// baseline (2141.154 us; speedup 1.0000x reference)
//
#include <hip/hip_runtime.h>
#include <hip/hip_bf16.h>
#include <math.h>

#define HD 128
#define N_OP 100000
#define N_L1 400000   // rows needed after layer1: operator..operation (contiguous)
#define NB 2048

// relation tables (from reference EDGES/OFFS)
static const int REL_E[14]    = {100000,100000,100000,100000,100000,100000,100000,100000,100000,50000,50000,20000,120000,60000};
static const int REL_SOFF[14] = {100000,240000,120000,120000,0,300000,300000,400000,450000,400000,450000,100000,120000,240000};
static const int REL_DSZ[14]  = {100000,100000,100000,100000,100000,100000,60000,100000,100000,50000,50000,20000,120000,60000};
static const int CNT_OFF[14]  = {0,100000,200000,300000,400000,500000,600000,660000,760000,860000,910000,960000,980000,1100000};
#define CNT_TOT 1160000
// src node-type of each relation (0=operator,1=table,2=column,3=predicate,4=operation,5=literal,6=numeral)
static const int SRC_T[14] = {1,3,2,2,0,4,4,5,6,5,6,1,2,3};
static const int TSZ[7] = {100000,20000,120000,60000,100000,50000,50000};
static const int TF[7]  = {4,2,10,4,8,1,1};
// raw-feature aggregate offsets (floats), rels 9/10 unused (dead after DCE)
static const size_t AGR_OFF[14] = {0,200000,600000,1600000,2600000,3000000,3800000,4280000,4380000,0,0,4480000,4520000,5720000};
#define AGR_TOT 5960000

// ---------------- dtype helpers ----------------
__device__ inline float ld1(const float* p) { return *p; }
__device__ inline float ld1(const __hip_bfloat16* p) { return __bfloat162float(*p); }
__device__ inline void st1(float* p, float v) { *p = v; }
__device__ inline void st1(__hip_bfloat16* p, float v) { *p = __float2bfloat16(v); }
__device__ inline float bfu2f(unsigned short u) {
  union { unsigned int i; float f; } v; v.i = ((unsigned int)u) << 16; return v.f;
}
__device__ inline float4 load4(const float* p) { return *(const float4*)p; }
__device__ inline float4 load4(const __hip_bfloat16* p) {
  ushort4 u = *(const ushort4*)p;
  return make_float4(bfu2f(u.x), bfu2f(u.y), bfu2f(u.z), bfu2f(u.w));
}

// ---------------- precompute: Wout = A(F,128) @ Mtx(128,128); bout = bin@Mtx + extra ----------------
__global__ void combine_kernel(const float* __restrict__ A, const float* __restrict__ bin,
                               const float* __restrict__ Mtx, const float* __restrict__ extra,
                               float* __restrict__ Wout, float* __restrict__ bout, int F) {
  int f = blockIdx.x, c = threadIdx.x;
  if (f < F) {
    float s = 0.f;
    for (int k = 0; k < HD; ++k) s = fmaf(A[f * HD + k], Mtx[k * HD + c], s);
    Wout[f * HD + c] = s;
  } else {
    float s = extra ? extra[c] : 0.f;
    for (int k = 0; k < HD; ++k) s = fmaf(bin[k], Mtx[k * HD + c], s);
    bout[c] = s;
  }
}

// ---------------- per-relation degree counts ----------------
__global__ void count_kernel(const int* __restrict__ dst, float* __restrict__ cnt, int E) {
  int e = blockIdx.x * 256 + threadIdx.x;
  if (e < E) atomicAdd(&cnt[dst[e]], 1.0f);
}

__global__ void recip_kernel(float* __restrict__ c, int n) {
  int i = blockIdx.x * 256 + threadIdx.x;
  if (i < n) {
    float v = c[i];
    c[i] = (v > 0.0f) ? (1.0f / v) : 0.0f;  // 0 marks empty dst (term skipped)
  }
}

// ---------------- layer-1 raw-feature scatter: S[dst,:F] += x[src,:F] ----------------
__global__ void scatter_raw(const float* __restrict__ x, const int* __restrict__ src,
                            const int* __restrict__ dst, float* __restrict__ S, int E, int F) {
  int e = blockIdx.x * 256 + threadIdx.x;
  if (e >= E) return;
  int s = src[e], d = dst[e];
  for (int f = 0; f < F; ++f) atomicAdd(&S[(size_t)d * F + f], x[(size_t)s * F + f]);
}

// ---------------- layer-1 fused: out[row,c] = sum_terms (scale*S@W + bias) ----------------
struct Term { const float* S; const float* W; const float* B; const float* recip; int F; };
struct TermPack { Term t[6]; int n; };

template <typename T>
__global__ void layer1_kernel(TermPack P, T* __restrict__ out, int M) {
  int tid = blockIdx.x * 256 + threadIdx.x;
  int row = tid >> 7, c = tid & 127;
  if (row >= M) return;
  float acc = 0.f;
  for (int q = 0; q < P.n; ++q) {
    const Term tm = P.t[q];
    float scale = 1.f;
    bool add = true;
    if (tm.recip) { scale = tm.recip[row]; add = (scale > 0.f); }
    if (add) {
      float s = 0.f;
      for (int f = 0; f < tm.F; ++f) s = fmaf(tm.S[(size_t)row * tm.F + f], tm.W[f * HD + c], s);
      acc += s * scale + tm.B[c];
    }
  }
  st1(&out[(size_t)row * HD + c], acc);
}

// ---------------- layer-2 edge scatter: agg[dst,:] += X[src+soff,:] ----------------
template <typename T>
__global__ void scatter_kernel(const T* __restrict__ X, const int* __restrict__ src,
                               const int* __restrict__ dst, float* __restrict__ agg,
                               int E, int soff) {
  int tid = blockIdx.x * 256 + threadIdx.x;
  int e = tid >> 7;
  int c = tid & 127;
  if (e >= E) return;
  atomicAdd(&agg[(size_t)dst[e] * HD + c], ld1(&X[(size_t)(src[e] + soff) * HD + c]));
}

// ---------------- tall-skinny GEMM: Y[M,128] (+)= diag(recip?)*Xin[M,128] @ W[128,128] (+bias)
#define TM 128
#define KT 32
#define LDX 33

template <typename TI, bool ACCUM, bool SCALE, bool BIAS>
__global__ __launch_bounds__(256, 4)
void gemm128(const TI* __restrict__ Xin, const float* __restrict__ W,
             float* __restrict__ Y, const float* __restrict__ recip,
             const float* __restrict__ bias, int M) {
  __shared__ float Xs[TM * LDX];
  __shared__ float Ws[KT * HD];
  const int t = threadIdx.x;
  const int m0 = blockIdx.x * TM;
  const int rg = t >> 4;
  const int cg = t & 15;
  const int r8 = rg * 8;
  const int c8 = cg * 8;

  float acc[8][8];
#pragma unroll
  for (int i = 0; i < 8; ++i)
#pragma unroll
    for (int j = 0; j < 8; ++j) acc[i][j] = 0.0f;

  for (int kt = 0; kt < HD; kt += KT) {
    __syncthreads();
#pragma unroll
    for (int it = 0; it < 4; ++it) {
      int f4 = it * 256 + t;
      int kk = f4 >> 5;
      int c4 = f4 & 31;
      *(float4*)&Ws[kk * HD + c4 * 4] = *(const float4*)&W[(size_t)(kt + kk) * HD + c4 * 4];
    }
#pragma unroll
    for (int it = 0; it < 4; ++it) {
      int f4 = it * 256 + t;
      int row = f4 >> 3;
      int k4 = f4 & 7;
      float4 v = make_float4(0.f, 0.f, 0.f, 0.f);
      int m = m0 + row;
      if (m < M) {
        v = load4(&Xin[(size_t)m * HD + kt + k4 * 4]);
        if (SCALE) {
          float sc = recip[m];
          v.x *= sc; v.y *= sc; v.z *= sc; v.w *= sc;
        }
      }
      float* xp = &Xs[row * LDX + k4 * 4];
      xp[0] = v.x; xp[1] = v.y; xp[2] = v.z; xp[3] = v.w;
    }
    __syncthreads();

#pragma unroll 4
    for (int kk = 0; kk < KT; ++kk) {
      float b[8];
      const float4 b0 = *(const float4*)&Ws[kk * HD + c8];
      const float4 b1 = *(const float4*)&Ws[kk * HD + c8 + 4];
      b[0] = b0.x; b[1] = b0.y; b[2] = b0.z; b[3] = b0.w;
      b[4] = b1.x; b[5] = b1.y; b[6] = b1.z; b[7] = b1.w;
      float a[8];
#pragma unroll
      for (int i = 0; i < 8; ++i) a[i] = Xs[(r8 + i) * LDX + kk];
#pragma unroll
      for (int i = 0; i < 8; ++i)
#pragma unroll
        for (int j = 0; j < 8; ++j) acc[i][j] = fmaf(a[i], b[j], acc[i][j]);
    }
  }

  float bi[8];
  if (BIAS) {
    const float4 q0 = *(const float4*)&bias[c8];
    const float4 q1 = *(const float4*)&bias[c8 + 4];
    bi[0] = q0.x; bi[1] = q0.y; bi[2] = q0.z; bi[3] = q0.w;
    bi[4] = q1.x; bi[5] = q1.y; bi[6] = q1.z; bi[7] = q1.w;
  }
#pragma unroll
  for (int i = 0; i < 8; ++i) {
    int m = m0 + r8 + i;
    if (m < M) {
      float* yp = &Y[(size_t)m * HD + c8];
      float o[8];
#pragma unroll
      for (int j = 0; j < 8; ++j) o[j] = acc[i][j];
      if (BIAS) {
#pragma unroll
        for (int j = 0; j < 8; ++j) o[j] += bi[j];
      }
      if (ACCUM) {
        float4 y0 = *(const float4*)&yp[0];
        float4 y1 = *(const float4*)&yp[4];
        o[0] += y0.x; o[1] += y0.y; o[2] += y0.z; o[3] += y0.w;
        o[4] += y1.x; o[5] += y1.y; o[6] += y1.z; o[7] += y1.w;
      }
      float4 s0, s1;
      s0.x = o[0]; s0.y = o[1]; s0.z = o[2]; s0.w = o[3];
      s1.x = o[4]; s1.y = o[5]; s1.z = o[6]; s1.w = o[7];
      *(float4*)&yp[0] = s0;
      *(float4*)&yp[4] = s1;
    }
  }
}

// ---------------- fused ELU + LayerNorm (in place), one wave per row ----------------
template <typename T>
__global__ void elu_ln_kernel(T* __restrict__ Hb, const float* __restrict__ g,
                              const float* __restrict__ bias, int M) {
  int w = threadIdx.x >> 6;
  int lane = threadIdx.x & 63;
  int row = blockIdx.x * 4 + w;
  if (row >= M) return;
  T* p = &Hb[(size_t)row * HD + lane * 2];
  float vx = ld1(p), vy = ld1(p + 1);
  vx = (vx > 0.f) ? vx : (expf(vx) - 1.f);
  vy = (vy > 0.f) ? vy : (expf(vy) - 1.f);
  float s = vx + vy;
  float sq = vx * vx + vy * vy;
#pragma unroll
  for (int m = 32; m >= 1; m >>= 1) {
    s += __shfl_xor(s, m, 64);
    sq += __shfl_xor(sq, m, 64);
  }
  float mean = s * (1.0f / HD);
  float var = sq * (1.0f / HD) - mean * mean;
  float rstd = rsqrtf(var + 1e-5f);
  float2 gg = *(const float2*)&g[lane * 2];
  float2 bb = *(const float2*)&bias[lane * 2];
  st1(p, (vx - mean) * rstd * gg.x + bb.x);
  st1(p + 1, (vy - mean) * rstd * gg.y + bb.y);
}

// ---------------- mean-pool operator rows by batch id ----------------
__global__ void pool_kernel(const float* __restrict__ Hb, const int* __restrict__ batch,
                            float* __restrict__ pool, float* __restrict__ pcnt) {
  int tid = blockIdx.x * 256 + threadIdx.x;
  int n = tid >> 7;
  int c = tid & 127;
  if (n >= N_OP) return;
  int b = batch[n];
  atomicAdd(&pool[(size_t)b * HD + c], Hb[(size_t)n * HD + c]);
  if (c == 0) atomicAdd(&pcnt[b], 1.0f);
}

__global__ void final_kernel(const float* __restrict__ pool, const float* __restrict__ pcnt,
                             const float* __restrict__ Wl, const float* __restrict__ bl,
                             float* __restrict__ out) {
  int w = threadIdx.x >> 6;
  int lane = threadIdx.x & 63;
  int b = blockIdx.x * 4 + w;
  if (b >= NB) return;
  float2 p = *(const float2*)&pool[(size_t)b * HD + lane * 2];
  float2 wl = *(const float2*)&Wl[lane * 2];
  float s = p.x * wl.x + p.y * wl.y;
#pragma unroll
  for (int m = 32; m >= 1; m >>= 1) s += __shfl_xor(s, m, 64);
  if (lane == 0) out[b] = s / fmaxf(pcnt[b], 1.0f) + bl[0];
}

// =================== host ===================
template <typename T>
static void run_pipeline(void* const* d_in, void* d_out, void* d_ws, hipStream_t stream) {
  const float* xt[7];
  for (int t = 0; t < 7; ++t) xt[t] = (const float*)d_in[t];
  const int* ei[14];
  for (int r = 0; r < 14; ++r) ei[r] = (const int*)d_in[7 + r];
  const int* batch = (const int*)d_in[21];
  const float* Wt[7]; const float* bt[7];
  for (int t = 0; t < 7; ++t) { Wt[t] = (const float*)d_in[22 + 2 * t]; bt[t] = (const float*)d_in[23 + 2 * t]; }
  const float* c_root[2] = {(const float*)d_in[36], (const float*)d_in[39]};
  const float* c_rel[2]  = {(const float*)d_in[37], (const float*)d_in[40]};
  const float* c_bias[2] = {(const float*)d_in[38], (const float*)d_in[41]};
  const float* ng[2] = {(const float*)d_in[42], (const float*)d_in[44]};
  const float* nbv[2] = {(const float*)d_in[43], (const float*)d_in[45]};
  const float* Wlin = (const float*)d_in[46];
  const float* blin = (const float*)d_in[47];
  float* out = (float*)d_out;

  char* base = (char*)d_ws;
  size_t off = 0;
  auto alloc = [&](size_t bytes) -> void* {
    void* p = base + off;
    off += (bytes + 255) & ~(size_t)255;
    return p;
  };
  T* Hb       = (T*)alloc((size_t)N_L1 * HD * sizeof(T));
  float* OUT2 = (float*)alloc((size_t)N_OP * HD * 4);
  float* AGG  = (float*)alloc((size_t)N_OP * HD * 4);
  float* AGR  = (float*)alloc((size_t)AGR_TOT * 4);
  float* CNT  = (float*)alloc((size_t)CNT_TOT * 4);
  float* WC   = (float*)alloc((size_t)14 * 1280 * 4);
  float* BC   = (float*)alloc((size_t)14 * HD * 4);
  float* WR   = (float*)alloc((size_t)7 * 1280 * 4);
  float* BR   = (float*)alloc((size_t)7 * HD * 4);
  float* POOL = (float*)alloc((size_t)NB * HD * 4);
  float* PCNT = (float*)alloc((size_t)NB * 4);

  static const int l1_rels[12] = {0,1,2,3,4,5,6,7,8,11,12,13};
  static const int l2_rels[5]  = {0,1,2,4,5};

  // precompute combined layer-1 weights: WC[r] = W_srctype @ c1_rel[r]; BC[r] = b_srctype @ c1_rel[r]
  for (int q = 0; q < 12; ++q) {
    int r = l1_rels[q]; int t = SRC_T[r]; int F = TF[t];
    combine_kernel<<<F + 1, 128, 0, stream>>>(Wt[t], bt[t], c_rel[0] + (size_t)r * HD * HD,
                                              nullptr, WC + r * 1280, BC + r * HD, F);
  }
  for (int t = 0; t < 5; ++t) {
    combine_kernel<<<TF[t] + 1, 128, 0, stream>>>(Wt[t], bt[t], c_root[0], c_bias[0],
                                                  WR + t * 1280, BR + t * HD, TF[t]);
  }

  // degree counts (shared by both layers)
  hipMemsetAsync(CNT, 0, (size_t)CNT_TOT * 4, stream);
  for (int q = 0; q < 12; ++q) {
    int r = l1_rels[q];
    count_kernel<<<(REL_E[r] + 255) / 256, 256, 0, stream>>>(ei[r] + REL_E[r], CNT + CNT_OFF[r], REL_E[r]);
  }
  recip_kernel<<<(CNT_TOT + 255) / 256, 256, 0, stream>>>(CNT, CNT_TOT);

  // layer-1 raw-feature aggregation
  hipMemsetAsync(AGR, 0, (size_t)AGR_TOT * 4, stream);
  for (int q = 0; q < 12; ++q) {
    int r = l1_rels[q]; int F = TF[SRC_T[r]]; int E = REL_E[r];
    scatter_raw<<<(E + 255) / 256, 256, 0, stream>>>(xt[SRC_T[r]], ei[r], ei[r] + E,
                                                     AGR + AGR_OFF[r], E, F);
  }

  // layer-1 fused compute per dst type
  auto relterm = [&](int r) {
    Term tm; tm.S = AGR + AGR_OFF[r]; tm.W = WC + r * 1280; tm.B = BC + r * HD;
    tm.recip = CNT + CNT_OFF[r]; tm.F = TF[SRC_T[r]]; return tm;
  };
  auto rootterm = [&](int t) {
    Term tm; tm.S = xt[t]; tm.W = WR + t * 1280; tm.B = BR + t * HD;
    tm.recip = nullptr; tm.F = TF[t]; return tm;
  };
  static const int TOFF5[5] = {0, 100000, 120000, 240000, 300000};
  static const int NREL[5] = {5, 1, 1, 2, 3};
  static const int RELS[5][5] = {{0, 1, 2, 4, 5}, {11, 0, 0, 0, 0}, {12, 0, 0, 0, 0},
                                 {6, 13, 0, 0, 0}, {3, 7, 8, 0, 0}};
  for (int t = 0; t < 5; ++t) {
    TermPack P = {};
    P.n = 1 + NREL[t];
    P.t[0] = rootterm(t);
    for (int j = 0; j < NREL[t]; ++j) P.t[1 + j] = relterm(RELS[t][j]);
    int M = TSZ[t];
    layer1_kernel<T><<<((size_t)M * HD + 255) / 256, 256, 0, stream>>>(P, Hb + (size_t)TOFF5[t] * HD, M);
  }
  elu_ln_kernel<T><<<(N_L1 + 3) / 4, 256, 0, stream>>>(Hb, ng[0], nbv[0], N_L1);

  // layer-2 (only dst=operator relations survive DCE)
  gemm128<T, false, false, true><<<(N_OP + TM - 1) / TM, 256, 0, stream>>>(
      Hb, c_root[1], OUT2, nullptr, c_bias[1], N_OP);
  for (int q = 0; q < 5; ++q) {
    int r = l2_rels[q]; int E = REL_E[r];
    hipMemsetAsync(AGG, 0, (size_t)N_OP * HD * 4, stream);
    scatter_kernel<T><<<((size_t)E * HD + 255) / 256, 256, 0, stream>>>(
        Hb, ei[r], ei[r] + E, AGG, E, REL_SOFF[r]);
    gemm128<float, true, true, false><<<(N_OP + TM - 1) / TM, 256, 0, stream>>>(
        AGG, c_rel[1] + (size_t)r * HD * HD, OUT2, CNT + CNT_OFF[r], nullptr, N_OP);
  }
  elu_ln_kernel<float><<<(N_OP + 3) / 4, 256, 0, stream>>>(OUT2, ng[1], nbv[1], N_OP);

  // pool + final linear
  hipMemsetAsync(POOL, 0, (size_t)NB * HD * 4, stream);
  hipMemsetAsync(PCNT, 0, (size_t)NB * 4, stream);
  pool_kernel<<<((size_t)N_OP * HD + 255) / 256, 256, 0, stream>>>(OUT2, batch, POOL, PCNT);
  final_kernel<<<(NB + 3) / 4, 256, 0, stream>>>(POOL, PCNT, Wlin, blin, out);
}

extern "C" void kernel_launch(void* const* d_in, const int* in_sizes, int n_in,
                              void* d_out, int out_size, void* d_ws, size_t ws_size,
                              hipStream_t stream) {
  auto total_need = [&](size_t esz) -> size_t {
    size_t s = 0;
    auto add = [&](size_t b) { s += (b + 255) & ~(size_t)255; };
    add((size_t)N_L1 * HD * esz);   // Hb
    add((size_t)N_OP * HD * 4);     // OUT2
    add((size_t)N_OP * HD * 4);     // AGG
    add((size_t)AGR_TOT * 4);       // AGR
    add((size_t)CNT_TOT * 4);       // CNT
    add((size_t)14 * 1280 * 4); add((size_t)14 * HD * 4);
    add((size_t)7 * 1280 * 4);  add((size_t)7 * HD * 4);
    add((size_t)NB * HD * 4); add((size_t)NB * 4);
    return s;
  };
  if (ws_size >= total_need(4)) {
    run_pipeline<float>(d_in, d_out, d_ws, stream);
  } else {
    run_pipeline<__hip_bfloat16>(d_in, d_out, d_ws, stream);
  }
}

// Round 3
// 1287.196 us; speedup vs baseline: 1.6634x; 1.6634x over previous
//
#include <hip/hip_runtime.h>
#include <hip/hip_bf16.h>
#include <math.h>

#define HD 128
#define N_OP 100000
#define N_L1 400000
#define NB 2048

typedef short short8 __attribute__((ext_vector_type(8)));
typedef float floatx4 __attribute__((ext_vector_type(4)));

// relation tables (from reference EDGES/OFFS)
static const int REL_E[14]    = {100000,100000,100000,100000,100000,100000,100000,100000,100000,50000,50000,20000,120000,60000};
static const int REL_SOFF_HB[14] = {100000,240000,120000,120000,0,300000,300000,400000,450000,400000,450000,100000,120000,240000};
static const int CNT_OFF[14]  = {0,100000,200000,300000,400000,500000,600000,660000,760000,860000,910000,960000,980000,1100000};
#define CNT_TOT 1160000
static const int SRC_T[14] = {1,3,2,2,0,4,4,5,6,5,6,1,2,3};
static const int TSZ[7] = {100000,20000,120000,60000,100000,50000,50000};
static const int TF[7]  = {4,2,10,4,8,1,1};
static const size_t AGR_OFF[14] = {0,200000,600000,1600000,2600000,3000000,3800000,4280000,4380000,0,0,4480000,4520000,5720000};
#define AGR_TOT 5960000

// ============ prep: degree counts + raw-feature scatter + batch counts (one kernel) ============
struct PrepJob { const int* dst; const int* srcp; const float* x; float* cnt; float* agr; int E; int F; int blk0; };
struct PrepPack { PrepJob j[13]; };

__global__ void prep_kernel(PrepPack P) {
  int b = blockIdx.x;
  int ji = 0;
  for (int i = 1; i < 13; ++i) if (b >= P.j[i].blk0) ji = i;
  PrepJob J = P.j[ji];
  int e = (b - J.blk0) * 256 + threadIdx.x;
  if (e >= J.E) return;
  int d = J.dst[e];
  atomicAdd(&J.cnt[d], 1.0f);
  if (J.F > 0) {
    int s = J.srcp[e];
    for (int f = 0; f < J.F; ++f)
      atomicAdd(&J.agr[(size_t)d * J.F + f], J.x[(size_t)s * J.F + f]);
  }
}

__global__ void recip_kernel(float* __restrict__ c, int n) {
  int i = blockIdx.x * 256 + threadIdx.x;
  if (i < n) {
    float v = c[i];
    c[i] = (v > 0.0f) ? (1.0f / v) : 0.0f;  // 0 marks empty dst
  }
}

// ============ combine weights: Wout = A(F,128)@Mtx ; bout = bin@Mtx + extra ============
struct CombJob { const float* A; const float* bin; const float* Mtx; const float* extra; float* Wout; float* bout; int F; };
struct CombPack { CombJob j[17]; };

__global__ void combine_all(CombPack P) {
  CombJob J = P.j[blockIdx.x];
  int c = threadIdx.x;  // 128 threads
  for (int f = 0; f <= J.F; ++f) {
    const float* arow = (f < J.F) ? &J.A[f * HD] : J.bin;
    float s = (f < J.F) ? 0.f : (J.extra ? J.extra[c] : 0.f);
    for (int k = 0; k < HD; ++k) s = fmaf(arow[k], J.Mtx[k * HD + c], s);
    if (f < J.F) J.Wout[f * HD + c] = s;
    else J.bout[c] = s;
  }
}

// ============ layer-2 weight prep: bf16, transposed [n][k], padded stride 136 ============
__global__ void wprep_kernel(const float* __restrict__ c2root, const float* __restrict__ c2rel,
                             __hip_bfloat16* __restrict__ Wt) {
  const int RID[6] = {-1, 0, 1, 2, 4, 5};
  int j = blockIdx.x;
  const float* W = (j == 0) ? c2root : (c2rel + (size_t)RID[j] * HD * HD);
  __hip_bfloat16* o = Wt + (size_t)j * HD * 136;
  for (int i = threadIdx.x; i < HD * HD; i += 256) {
    int k = i >> 7, n = i & 127;
    o[n * 136 + k] = __float2bfloat16(W[i]);
  }
}

// ============ layer-1 fused (compile-time term widths) + ELU + LayerNorm ============
struct Term { const float* S; const float* W; const float* B; const float* recip; };
template <int NT> struct TPack { Term t[NT]; };

template <int F>
__device__ inline float term_eval(const Term& tm, int row, int c) {
  float scale = 1.f;
  if (tm.recip) {
    scale = tm.recip[row];
    if (scale <= 0.f) return 0.f;   // empty dst: whole term (incl. bias) absent
  }
  float s = 0.f;
#pragma unroll
  for (int f = 0; f < F; ++f)
    s = fmaf(tm.S[(size_t)row * F + f], tm.W[f * HD + c], s);
  return fmaf(s, scale, tm.B[c]);
}

template <int... Fs>
__global__ void layer1_ln(TPack<sizeof...(Fs)> P, const float* __restrict__ g,
                          const float* __restrict__ bb, __hip_bfloat16* __restrict__ out,
                          int base) {
  const int t = threadIdx.x;
  const int rl = t >> 7;          // 0 or 1: local row
  const int c = t & 127;
  const int row = blockIdx.x * 2 + rl;

  float acc = 0.f;
  int qi = 0;
  int dummy[] = { (acc += term_eval<Fs>(P.t[qi], row, c), ++qi, 0)... };
  (void)dummy;

  // ELU
  float e = (acc > 0.f) ? acc : (expf(acc) - 1.f);
  // LN across 128 channels; 2 waves per row
  float s = e, sq = e * e;
#pragma unroll
  for (int m = 32; m >= 1; m >>= 1) {
    s += __shfl_xor(s, m, 64);
    sq += __shfl_xor(sq, m, 64);
  }
  __shared__ float red[8];
  int wv = t >> 6;
  if ((t & 63) == 0) { red[wv] = s; red[wv + 4] = sq; }
  __syncthreads();
  int rb = rl * 2;
  float S = red[rb] + red[rb + 1];
  float Q = red[rb + 4] + red[rb + 5];
  float mean = S * (1.0f / HD);
  float var = Q * (1.0f / HD) - mean * mean;
  float rstd = rsqrtf(var + 1e-5f);
  float v = (e - mean) * rstd * g[c] + bb[c];
  out[(size_t)(base + row) * HD + c] = __float2bfloat16(v);
}

// ============ layer-2: fused gather -> bf16 MFMA -> (atomic-scatter | store) ============
// EDGE:  OUT2[dst[e],:] += recip[dst[e]] * (Hb[src[e]+soff,:] @ W)   per edge block
// !EDGE: OUT2[m,:] = Hb[m,:] @ W + bias
template <bool EDGE>
__global__ __launch_bounds__(256, 2)
void gemm_l2(const unsigned short* __restrict__ Hb, const unsigned short* __restrict__ Wt,
             const int* __restrict__ src, const int* __restrict__ dst,
             const float* __restrict__ recip, const float* __restrict__ bias,
             float* __restrict__ OUT2, int M, int soff) {
  __shared__ unsigned short As[128 * 136];
  __shared__ unsigned short Ws[128 * 136];
  __shared__ int sid[128];
  __shared__ int dstl[128];
  __shared__ float rcl[128];
  const int t = threadIdx.x;
  const int m0 = blockIdx.x * 128;

  if (EDGE && t < 128) {
    int e = m0 + t;
    if (e < M) {
      int d = dst[e];
      sid[t] = src[e] + soff;
      dstl[t] = d;
      rcl[t] = recip[d];
    } else {
      sid[t] = soff; dstl[t] = -1; rcl[t] = 0.f;
    }
  }
  // stage W (pre-padded 128x136 bf16): 2176 uint4
  {
    const uint4* wg = (const uint4*)Wt;
    uint4* ws4 = (uint4*)Ws;
#pragma unroll
    for (int i = 0; i < 9; ++i) {
      int idx = i * 256 + t;
      if (idx < 2176) ws4[idx] = wg[idx];
    }
  }
  __syncthreads();
  // gather A rows: 128 rows x 16 chunks of 8 bf16
#pragma unroll
  for (int i = 0; i < 8; ++i) {
    int idx = i * 256 + t;
    int row = idx >> 4, ch = idx & 15;
    long r = EDGE ? (long)sid[row] : (long)(m0 + row);
    uint4 v = *(const uint4*)&Hb[r * HD + ch * 8];
    *(uint4*)&As[row * 136 + ch * 8] = v;
  }
  __syncthreads();

  const int wv = t >> 6, ln = t & 63;
  const int ln15 = ln & 15;
  const int q8 = (ln >> 4) * 8;

  floatx4 acc[2][8];
#pragma unroll
  for (int a = 0; a < 2; ++a)
#pragma unroll
    for (int b = 0; b < 8; ++b) acc[a][b] = (floatx4){0.f, 0.f, 0.f, 0.f};

  short8 afr[2][4];
#pragma unroll
  for (int mt2 = 0; mt2 < 2; ++mt2) {
    int row = (wv * 2 + mt2) * 16 + ln15;
#pragma unroll
    for (int k4 = 0; k4 < 4; ++k4)
      afr[mt2][k4] = *(const short8*)&As[row * 136 + k4 * 32 + q8];
  }
#pragma unroll
  for (int nt = 0; nt < 8; ++nt) {
    int wrow = nt * 16 + ln15;
    short8 b0 = *(const short8*)&Ws[wrow * 136 + 0 + q8];
    short8 b1 = *(const short8*)&Ws[wrow * 136 + 32 + q8];
    short8 b2 = *(const short8*)&Ws[wrow * 136 + 64 + q8];
    short8 b3 = *(const short8*)&Ws[wrow * 136 + 96 + q8];
#pragma unroll
    for (int mt2 = 0; mt2 < 2; ++mt2) {
      acc[mt2][nt] = __builtin_amdgcn_mfma_f32_16x16x32_bf16(afr[mt2][0], b0, acc[mt2][nt], 0, 0, 0);
      acc[mt2][nt] = __builtin_amdgcn_mfma_f32_16x16x32_bf16(afr[mt2][1], b1, acc[mt2][nt], 0, 0, 0);
      acc[mt2][nt] = __builtin_amdgcn_mfma_f32_16x16x32_bf16(afr[mt2][2], b2, acc[mt2][nt], 0, 0, 0);
      acc[mt2][nt] = __builtin_amdgcn_mfma_f32_16x16x32_bf16(afr[mt2][3], b3, acc[mt2][nt], 0, 0, 0);
    }
  }

  // epilogue: D row = quad*4 + reg, col = nt*16 + ln15
#pragma unroll
  for (int mt2 = 0; mt2 < 2; ++mt2) {
#pragma unroll
    for (int r = 0; r < 4; ++r) {
      int row = (wv * 2 + mt2) * 16 + (ln >> 4) * 4 + r;
      if (EDGE) {
        int d = dstl[row];
        if (d >= 0) {
          float sc = rcl[row];
#pragma unroll
          for (int nt = 0; nt < 8; ++nt)
            atomicAdd(&OUT2[(size_t)d * HD + nt * 16 + ln15], acc[mt2][nt][r] * sc);
        }
      } else {
        int m = m0 + row;
        if (m < M) {
#pragma unroll
          for (int nt = 0; nt < 8; ++nt) {
            int col = nt * 16 + ln15;
            OUT2[(size_t)m * HD + col] = acc[mt2][nt][r] + bias[col];
          }
        }
      }
    }
  }
}

// ============ epilogue: ELU + LN + dot(W_lin) + batch-sum (one wave per row) ============
__global__ void ln2pool(const float* __restrict__ OUT2, const int* __restrict__ batch,
                        const float* __restrict__ g, const float* __restrict__ bb,
                        const float* __restrict__ Wl, float* __restrict__ accb) {
  int wv = threadIdx.x >> 6, ln = threadIdx.x & 63;
  int row = blockIdx.x * 4 + wv;
  if (row >= N_OP) return;
  float2 v = *(const float2*)&OUT2[(size_t)row * HD + ln * 2];
  v.x = (v.x > 0.f) ? v.x : (expf(v.x) - 1.f);
  v.y = (v.y > 0.f) ? v.y : (expf(v.y) - 1.f);
  float s = v.x + v.y, sq = v.x * v.x + v.y * v.y;
#pragma unroll
  for (int m = 32; m >= 1; m >>= 1) {
    s += __shfl_xor(s, m, 64);
    sq += __shfl_xor(sq, m, 64);
  }
  float mean = s * (1.0f / HD);
  float var = sq * (1.0f / HD) - mean * mean;
  float rstd = rsqrtf(var + 1e-5f);
  float2 gg = *(const float2*)&g[ln * 2];
  float2 b2 = *(const float2*)&bb[ln * 2];
  float2 wl = *(const float2*)&Wl[ln * 2];
  float o = ((v.x - mean) * rstd * gg.x + b2.x) * wl.x +
            ((v.y - mean) * rstd * gg.y + b2.y) * wl.y;
#pragma unroll
  for (int m = 32; m >= 1; m >>= 1) o += __shfl_xor(o, m, 64);
  if (ln == 0) atomicAdd(&accb[batch[row]], o);
}

__global__ void final_kernel(const float* __restrict__ accb, const float* __restrict__ pcnt,
                             const float* __restrict__ bl, float* __restrict__ out) {
  int b = blockIdx.x * 256 + threadIdx.x;
  if (b < NB) out[b] = accb[b] / fmaxf(pcnt[b], 1.0f) + bl[0];
}

// =================== host ===================
extern "C" void kernel_launch(void* const* d_in, const int* in_sizes, int n_in,
                              void* d_out, int out_size, void* d_ws, size_t ws_size,
                              hipStream_t stream) {
  const float* xt[7];
  for (int t = 0; t < 7; ++t) xt[t] = (const float*)d_in[t];
  const int* ei[14];
  for (int r = 0; r < 14; ++r) ei[r] = (const int*)d_in[7 + r];
  const int* batch = (const int*)d_in[21];
  const float* Wemb[7]; const float* bemb[7];
  for (int t = 0; t < 7; ++t) { Wemb[t] = (const float*)d_in[22 + 2 * t]; bemb[t] = (const float*)d_in[23 + 2 * t]; }
  const float* c_root[2] = {(const float*)d_in[36], (const float*)d_in[39]};
  const float* c_rel[2]  = {(const float*)d_in[37], (const float*)d_in[40]};
  const float* c_bias[2] = {(const float*)d_in[38], (const float*)d_in[41]};
  const float* ng[2] = {(const float*)d_in[42], (const float*)d_in[44]};
  const float* nbv[2] = {(const float*)d_in[43], (const float*)d_in[45]};
  const float* Wlin = (const float*)d_in[46];
  const float* blin = (const float*)d_in[47];
  float* out = (float*)d_out;

  char* base = (char*)d_ws;
  size_t off = 0;
  auto alloc = [&](size_t bytes) -> void* {
    void* p = base + off;
    off += (bytes + 255) & ~(size_t)255;
    return p;
  };
  __hip_bfloat16* Hb = (__hip_bfloat16*)alloc((size_t)N_L1 * HD * 2);
  float* OUT2 = (float*)alloc((size_t)N_OP * HD * 4);
  float* AGR  = (float*)alloc((size_t)AGR_TOT * 4);
  float* CNT  = (float*)alloc((size_t)CNT_TOT * 4);
  float* WC   = (float*)alloc((size_t)14 * 1280 * 4);
  float* BC   = (float*)alloc((size_t)14 * HD * 4);
  float* WR   = (float*)alloc((size_t)7 * 1280 * 4);
  float* BR   = (float*)alloc((size_t)7 * HD * 4);
  __hip_bfloat16* WT2 = (__hip_bfloat16*)alloc((size_t)6 * HD * 136 * 2);
  float* ACC  = (float*)alloc((size_t)NB * 4);
  float* PCNT = (float*)alloc((size_t)NB * 4);

  static const int l1_rels[12] = {0,1,2,3,4,5,6,7,8,11,12,13};

  // ---- memsets ----
  hipMemsetAsync(CNT, 0, (size_t)CNT_TOT * 4, stream);
  hipMemsetAsync(AGR, 0, (size_t)AGR_TOT * 4, stream);
  hipMemsetAsync(ACC, 0, (size_t)NB * 4, stream);
  hipMemsetAsync(PCNT, 0, (size_t)NB * 4, stream);

  // ---- prep: counts + raw scatter + batch counts ----
  PrepPack PP;
  int blk = 0;
  for (int q = 0; q < 12; ++q) {
    int r = l1_rels[q]; int t = SRC_T[r];
    PrepJob& J = PP.j[q];
    J.dst = ei[r] + REL_E[r]; J.srcp = ei[r]; J.x = xt[t];
    J.cnt = CNT + CNT_OFF[r]; J.agr = AGR + AGR_OFF[r];
    J.E = REL_E[r]; J.F = TF[t]; J.blk0 = blk;
    blk += (REL_E[r] + 255) / 256;
  }
  {
    PrepJob& J = PP.j[12];
    J.dst = batch; J.srcp = nullptr; J.x = nullptr;
    J.cnt = PCNT; J.agr = nullptr; J.E = N_OP; J.F = 0; J.blk0 = blk;
    blk += (N_OP + 255) / 256;
  }
  prep_kernel<<<blk, 256, 0, stream>>>(PP);
  recip_kernel<<<(CNT_TOT + 255) / 256, 256, 0, stream>>>(CNT, CNT_TOT);

  // ---- combined weights ----
  CombPack CP;
  for (int q = 0; q < 12; ++q) {
    int r = l1_rels[q]; int t = SRC_T[r];
    CombJob& J = CP.j[q];
    J.A = Wemb[t]; J.bin = bemb[t]; J.Mtx = c_rel[0] + (size_t)r * HD * HD;
    J.extra = nullptr; J.Wout = WC + r * 1280; J.bout = BC + r * HD; J.F = TF[t];
  }
  for (int t = 0; t < 5; ++t) {
    CombJob& J = CP.j[12 + t];
    J.A = Wemb[t]; J.bin = bemb[t]; J.Mtx = c_root[0];
    J.extra = c_bias[0]; J.Wout = WR + t * 1280; J.bout = BR + t * HD; J.F = TF[t];
  }
  combine_all<<<17, 128, 0, stream>>>(CP);
  wprep_kernel<<<6, 256, 0, stream>>>(c_root[1], c_rel[1], WT2);

  // ---- layer 1 (fused matmul + ELU + LN), per dst type ----
  auto RT = [&](int r) {
    Term tm; tm.S = AGR + AGR_OFF[r]; tm.W = WC + r * 1280; tm.B = BC + r * HD;
    tm.recip = CNT + CNT_OFF[r]; return tm;
  };
  auto RO = [&](int t) {
    Term tm; tm.S = xt[t]; tm.W = WR + t * 1280; tm.B = BR + t * HD;
    tm.recip = nullptr; return tm;
  };
  static const int TOFF5[5] = {0, 100000, 120000, 240000, 300000};
  {
    TPack<6> P = {{RO(0), RT(0), RT(1), RT(2), RT(4), RT(5)}};
    layer1_ln<4,2,4,10,4,8><<<TSZ[0] / 2, 256, 0, stream>>>(P, ng[0], nbv[0], Hb, TOFF5[0]);
  }
  {
    TPack<2> P = {{RO(1), RT(11)}};
    layer1_ln<2,2><<<TSZ[1] / 2, 256, 0, stream>>>(P, ng[0], nbv[0], Hb, TOFF5[1]);
  }
  {
    TPack<2> P = {{RO(2), RT(12)}};
    layer1_ln<10,10><<<TSZ[2] / 2, 256, 0, stream>>>(P, ng[0], nbv[0], Hb, TOFF5[2]);
  }
  {
    TPack<3> P = {{RO(3), RT(6), RT(13)}};
    layer1_ln<4,8,4><<<TSZ[3] / 2, 256, 0, stream>>>(P, ng[0], nbv[0], Hb, TOFF5[3]);
  }
  {
    TPack<4> P = {{RO(4), RT(3), RT(7), RT(8)}};
    layer1_ln<8,10,1,1><<<TSZ[4] / 2, 256, 0, stream>>>(P, ng[0], nbv[0], Hb, TOFF5[4]);
  }

  // ---- layer 2: root (direct) + 5 edge-fused MFMA kernels ----
  const unsigned short* Hbu = (const unsigned short*)Hb;
  const unsigned short* WT2u = (const unsigned short*)WT2;
  int gl2 = (N_OP + 127) / 128;
  gemm_l2<false><<<gl2, 256, 0, stream>>>(Hbu, WT2u, nullptr, nullptr, nullptr,
                                          c_bias[1], OUT2, N_OP, 0);
  static const int l2_rels[5] = {0, 1, 2, 4, 5};
  for (int q = 0; q < 5; ++q) {
    int r = l2_rels[q]; int E = REL_E[r];
    gemm_l2<true><<<(E + 127) / 128, 256, 0, stream>>>(
        Hbu, WT2u + (size_t)(q + 1) * HD * 136, ei[r], ei[r] + E,
        CNT + CNT_OFF[r], nullptr, OUT2, E, REL_SOFF_HB[r]);
  }

  // ---- epilogue: ELU+LN+dot+pool, then final scale ----
  ln2pool<<<(N_OP + 3) / 4, 256, 0, stream>>>(OUT2, batch, ng[1], nbv[1], Wlin, ACC);
  final_kernel<<<(NB + 255) / 256, 256, 0, stream>>>(ACC, PCNT, blin, out);
}

// Round 4
// 966.416 us; speedup vs baseline: 2.2156x; 1.3319x over previous
//
#include <hip/hip_runtime.h>
#include <hip/hip_bf16.h>
#include <math.h>

#define HD 128
#define N_OP 100000
#define N_L1 400000
#define NB 2048
#define CNT_TOT 1160000
#define EDG_TOT 1100000

typedef short short8 __attribute__((ext_vector_type(8)));
typedef float floatx4 __attribute__((ext_vector_type(4)));

// relation tables (from reference EDGES/OFFS)
static const int REL_E[14]    = {100000,100000,100000,100000,100000,100000,100000,100000,100000,50000,50000,20000,120000,60000};
static const int REL_DSZ[14]  = {100000,100000,100000,100000,100000,100000,60000,100000,100000,50000,50000,20000,120000,60000};
static const int CNT_OFF[14]  = {0,100000,200000,300000,400000,500000,600000,660000,760000,860000,910000,960000,980000,1100000};
static const int SRC_T[14] = {1,3,2,2,0,4,4,5,6,5,6,1,2,3};
static const int TSZ[7] = {100000,20000,120000,60000,100000,50000,50000};
static const int TF[7]  = {4,2,10,4,8,1,1};
static const size_t AGR_OFF[14] = {0,200000,600000,1600000,2600000,3000000,3800000,4280000,4380000,0,0,4480000,4520000,5720000};
#define AGR_TOT 5960000

// ---------------- bf16 helpers ----------------
__device__ inline float bfu2f(unsigned short u) {
  union { unsigned int i; float f; } v; v.i = ((unsigned int)u) << 16; return v.f;
}
__device__ inline unsigned short f2bf(float f) {
  union { float f; unsigned int u; } v; v.f = f;
  unsigned int r = v.u + 0x7FFF + ((v.u >> 16) & 1);
  return (unsigned short)(r >> 16);
}

// ============ count: int degree counts per (rel,dst) + float batch counts ============
struct CJob { const int* dst; int coff; int E; int blk0; };
struct CPackK { CJob j[12]; int bblk0; const int* batch; float* pcnt; int nop; };

__global__ void count_k(CPackK P, int* __restrict__ ICNT) {
  int b = blockIdx.x;
  if (b >= P.bblk0) {
    int i = (b - P.bblk0) * 256 + threadIdx.x;
    if (i < P.nop) atomicAdd(&P.pcnt[P.batch[i]], 1.0f);
    return;
  }
  int ji = 0;
#pragma unroll
  for (int i = 1; i < 12; ++i) if (b >= P.j[i].blk0) ji = i;
  CJob J = P.j[ji];
  int e = (b - J.blk0) * 256 + threadIdx.x;
  if (e < J.E) atomicAdd(&ICNT[J.coff + J.dst[e]], 1);
}

// ============ scans: exclusive prefix over ICNT -> OFF ============
#define SCAN_BLK 1024
__global__ void scan1(const int* __restrict__ in, int* __restrict__ out,
                      int* __restrict__ bsum, int n) {
  __shared__ int sh[256];
  int t = threadIdx.x;
  int base = blockIdx.x * SCAN_BLK + t * 4;
  int v0 = 0, v1 = 0, v2 = 0, v3 = 0;
  if (base + 3 < n) { int4 q = *(const int4*)&in[base]; v0 = q.x; v1 = q.y; v2 = q.z; v3 = q.w; }
  else {
    if (base < n) v0 = in[base];
    if (base + 1 < n) v1 = in[base + 1];
    if (base + 2 < n) v2 = in[base + 2];
    if (base + 3 < n) v3 = in[base + 3];
  }
  int ts = v0 + v1 + v2 + v3;
  sh[t] = ts; __syncthreads();
  for (int o = 1; o < 256; o <<= 1) {
    int x = (t >= o) ? sh[t - o] : 0;
    __syncthreads();
    sh[t] += x;
    __syncthreads();
  }
  int excl = sh[t] - ts;
  if (base < n) out[base] = excl;
  if (base + 1 < n) out[base + 1] = excl + v0;
  if (base + 2 < n) out[base + 2] = excl + v0 + v1;
  if (base + 3 < n) out[base + 3] = excl + v0 + v1 + v2;
  if (t == 255) bsum[blockIdx.x] = sh[255];
}

__global__ void scan2(int* __restrict__ bs, int nb) {
  __shared__ int sh[256];
  int t = threadIdx.x;
  const int C = 5;
  int v[C]; int ts = 0;
#pragma unroll
  for (int i = 0; i < C; ++i) { int idx = t * C + i; v[i] = (idx < nb) ? bs[idx] : 0; ts += v[i]; }
  sh[t] = ts; __syncthreads();
  for (int o = 1; o < 256; o <<= 1) {
    int x = (t >= o) ? sh[t - o] : 0;
    __syncthreads();
    sh[t] += x;
    __syncthreads();
  }
  int run = sh[t] - ts;
#pragma unroll
  for (int i = 0; i < C; ++i) { int idx = t * C + i; if (idx < nb) bs[idx] = run; run += v[i]; }
}

__global__ void scan3(int* __restrict__ OFF, int* __restrict__ CUR, float* __restrict__ CNTf,
                      const int* __restrict__ ICNT, const int* __restrict__ bs, int n) {
  int i = blockIdx.x * 256 + threadIdx.x;
  if (i < n) {
    int o = OFF[i] + bs[i >> 10];
    OFF[i] = o; CUR[i] = o;
    int c = ICNT[i];
    CNTf[i] = (c > 0) ? (1.0f / (float)c) : 0.0f;
  }
}

// ============ fill: EDG[pos] = src, grouped by (rel,dst) ============
struct FJob { const int* src; const int* dst; int coff; int E; int blk0; };
struct FPackK { FJob j[12]; };

__global__ void fill_k(FPackK P, int* __restrict__ CUR, int* __restrict__ EDG) {
  int b = blockIdx.x;
  int ji = 0;
#pragma unroll
  for (int i = 1; i < 12; ++i) if (b >= P.j[i].blk0) ji = i;
  FJob J = P.j[ji];
  int e = (b - J.blk0) * 256 + threadIdx.x;
  if (e < J.E) {
    int pos = atomicAdd(&CUR[J.coff + J.dst[e]], 1);
    EDG[pos] = J.src[e];
  }
}

// ============ gather raw-feature sums per (rel,dst): AGR[d,:F] = sum x[src,:F] ============
template <int F>
__global__ void gather_agr(const float* __restrict__ x, float* __restrict__ agr,
                           const int* __restrict__ OFF, const int* __restrict__ ICNT,
                           const int* __restrict__ EDG, int coff, int D) {
  int d = blockIdx.x * 256 + threadIdx.x;
  if (d >= D) return;
  int cb = coff + d;
  int o = OFF[cb], n = ICNT[cb];
  float acc[F];
#pragma unroll
  for (int f = 0; f < F; ++f) acc[f] = 0.f;
  for (int e = 0; e < n; ++e) {
    int s = EDG[o + e];
#pragma unroll
    for (int f = 0; f < F; ++f) acc[f] += x[(size_t)s * F + f];
  }
#pragma unroll
  for (int f = 0; f < F; ++f) agr[(size_t)d * F + f] = acc[f];
}

// ============ combine weights: Wout = A(F,128)@Mtx ; bout = bin@Mtx + extra ============
struct CombJob { const float* A; const float* bin; const float* Mtx; const float* extra; float* Wout; float* bout; int F; };
struct CombPack { CombJob j[17]; };

__global__ void combine_all(CombPack P) {
  CombJob J = P.j[blockIdx.x];
  int c = threadIdx.x;  // 128 threads
  for (int f = 0; f <= J.F; ++f) {
    const float* arow = (f < J.F) ? &J.A[f * HD] : J.bin;
    float s = (f < J.F) ? 0.f : (J.extra ? J.extra[c] : 0.f);
    for (int k = 0; k < HD; ++k) s = fmaf(arow[k], J.Mtx[k * HD + c], s);
    if (f < J.F) J.Wout[f * HD + c] = s;
    else J.bout[c] = s;
  }
}

// ============ layer-2 weight prep: bf16, transposed [n][k], padded stride 136 ============
__global__ void wprep_kernel(const float* __restrict__ c2root, const float* __restrict__ c2rel,
                             __hip_bfloat16* __restrict__ Wt) {
  const int RID[6] = {-1, 0, 1, 2, 4, 5};
  int j = blockIdx.x;
  const float* W = (j == 0) ? c2root : (c2rel + (size_t)RID[j] * HD * HD);
  __hip_bfloat16* o = Wt + (size_t)j * HD * 136;
  for (int i = threadIdx.x; i < HD * HD; i += 256) {
    int k = i >> 7, n = i & 127;
    o[n * 136 + k] = __float2bfloat16(W[i]);
  }
}

// ============ layer-1 fused (compile-time term widths) + ELU + LayerNorm ============
struct Term { const float* S; const float* W; const float* B; const float* recip; };
template <int NT> struct TPack { Term t[NT]; };

template <int F>
__device__ inline float term_eval(const Term& tm, int row, int c) {
  float scale = 1.f;
  if (tm.recip) {
    scale = tm.recip[row];
    if (scale <= 0.f) return 0.f;   // empty dst: whole term absent
  }
  float s = 0.f;
#pragma unroll
  for (int f = 0; f < F; ++f)
    s = fmaf(tm.S[(size_t)row * F + f], tm.W[f * HD + c], s);
  return fmaf(s, scale, tm.B[c]);
}

template <int... Fs>
__global__ void layer1_ln(TPack<sizeof...(Fs)> P, const float* __restrict__ g,
                          const float* __restrict__ bb, __hip_bfloat16* __restrict__ out,
                          int base) {
  const int t = threadIdx.x;
  const int rl = t >> 7;
  const int c = t & 127;
  const int row = blockIdx.x * 2 + rl;

  float acc = 0.f;
  int qi = 0;
  int dummy[] = { (acc += term_eval<Fs>(P.t[qi], row, c), ++qi, 0)... };
  (void)dummy;

  float e = (acc > 0.f) ? acc : (expf(acc) - 1.f);
  float s = e, sq = e * e;
#pragma unroll
  for (int m = 32; m >= 1; m >>= 1) {
    s += __shfl_xor(s, m, 64);
    sq += __shfl_xor(sq, m, 64);
  }
  __shared__ float red[8];
  int wv = t >> 6;
  if ((t & 63) == 0) { red[wv] = s; red[wv + 4] = sq; }
  __syncthreads();
  int rb = rl * 2;
  float S = red[rb] + red[rb + 1];
  float Q = red[rb + 4] + red[rb + 5];
  float mean = S * (1.0f / HD);
  float var = Q * (1.0f / HD) - mean * mean;
  float rstd = rsqrtf(var + 1e-5f);
  float v = (e - mean) * rstd * g[c] + bb[c];
  out[(size_t)(base + row) * HD + c] = __float2bfloat16(v);
}

// ============ layer-2: fully fused root + 5 relations, CSR gather -> MFMA -> store ============
// OUT2[m,:] = Hb[m,:]@Wroot + bias + sum_r recip_r[m] * (sum_{e in CSR_r[m]} Hb[src_e+soff,:]) @ W_r
__global__ __launch_bounds__(256, 2)
void l2_fused(const unsigned short* __restrict__ Hb, const unsigned short* __restrict__ Wall,
              const int* __restrict__ OFF, const int* __restrict__ ICNT,
              const float* __restrict__ RECIP, const int* __restrict__ EDG,
              const float* __restrict__ bias, float* __restrict__ OUT2, int M) {
  const int CSR_OFF[5] = {0, 100000, 200000, 400000, 500000};   // CNT_OFF of rels 0,1,2,4,5
  const int SOFF[5]    = {100000, 240000, 120000, 0, 300000};   // Hb row offset of src type
  __shared__ unsigned short Ws[128 * 136];
  const int t = threadIdx.x, wv = t >> 6, ln = t & 63;
  const int ln15 = ln & 15, q8 = (ln >> 4) * 8;
  const int m0 = blockIdx.x * 128;

  floatx4 acc[2][8];
#pragma unroll
  for (int a = 0; a < 2; ++a)
#pragma unroll
    for (int b = 0; b < 8; ++b) acc[a][b] = (floatx4){0.f, 0.f, 0.f, 0.f};

  for (int term = 0; term < 6; ++term) {
    __syncthreads();   // protect previous term's Ws readers
    {
      const uint4* wg = (const uint4*)(Wall + (size_t)term * 128 * 136);
      uint4* ws4 = (uint4*)Ws;
#pragma unroll
      for (int i = 0; i < 9; ++i) {
        int idx = i * 256 + t;
        if (idx < 2176) ws4[idx] = wg[idx];
      }
    }
    __syncthreads();

    short8 afr[2][4];
#pragma unroll
    for (int mt2 = 0; mt2 < 2; ++mt2) {
      int row = m0 + (wv * 2 + mt2) * 16 + ln15;
      if (term == 0) {
        if (row < M) {
#pragma unroll
          for (int k4 = 0; k4 < 4; ++k4)
            afr[mt2][k4] = *(const short8*)&Hb[(size_t)row * HD + k4 * 32 + q8];
        } else {
#pragma unroll
          for (int k4 = 0; k4 < 4; ++k4)
#pragma unroll
            for (int j = 0; j < 8; ++j) afr[mt2][k4][j] = 0;
        }
      } else {
        float sum[4][8];
#pragma unroll
        for (int k4 = 0; k4 < 4; ++k4)
#pragma unroll
          for (int j = 0; j < 8; ++j) sum[k4][j] = 0.f;
        if (row < M) {
          int cb = CSR_OFF[term - 1] + row;
          int o = OFF[cb], n = ICNT[cb];
          float rc = RECIP[cb];
          int so = SOFF[term - 1];
          for (int e = 0; e < n; ++e) {
            size_t s = (size_t)(EDG[o + e] + so);
#pragma unroll
            for (int k4 = 0; k4 < 4; ++k4) {
              short8 h = *(const short8*)&Hb[s * HD + k4 * 32 + q8];
#pragma unroll
              for (int j = 0; j < 8; ++j) sum[k4][j] += bfu2f((unsigned short)h[j]);
            }
          }
#pragma unroll
          for (int k4 = 0; k4 < 4; ++k4)
#pragma unroll
            for (int j = 0; j < 8; ++j) sum[k4][j] *= rc;
        }
#pragma unroll
        for (int k4 = 0; k4 < 4; ++k4)
#pragma unroll
          for (int j = 0; j < 8; ++j) afr[mt2][k4][j] = (short)f2bf(sum[k4][j]);
      }
    }

#pragma unroll
    for (int nt = 0; nt < 8; ++nt) {
      int wrow = nt * 16 + ln15;
      short8 b0 = *(const short8*)&Ws[wrow * 136 + 0 + q8];
      short8 b1 = *(const short8*)&Ws[wrow * 136 + 32 + q8];
      short8 b2 = *(const short8*)&Ws[wrow * 136 + 64 + q8];
      short8 b3 = *(const short8*)&Ws[wrow * 136 + 96 + q8];
#pragma unroll
      for (int mt2 = 0; mt2 < 2; ++mt2) {
        acc[mt2][nt] = __builtin_amdgcn_mfma_f32_16x16x32_bf16(afr[mt2][0], b0, acc[mt2][nt], 0, 0, 0);
        acc[mt2][nt] = __builtin_amdgcn_mfma_f32_16x16x32_bf16(afr[mt2][1], b1, acc[mt2][nt], 0, 0, 0);
        acc[mt2][nt] = __builtin_amdgcn_mfma_f32_16x16x32_bf16(afr[mt2][2], b2, acc[mt2][nt], 0, 0, 0);
        acc[mt2][nt] = __builtin_amdgcn_mfma_f32_16x16x32_bf16(afr[mt2][3], b3, acc[mt2][nt], 0, 0, 0);
      }
    }
  }

  // epilogue: D row = quad*4 + reg, col = nt*16 + ln15
#pragma unroll
  for (int mt2 = 0; mt2 < 2; ++mt2) {
#pragma unroll
    for (int r = 0; r < 4; ++r) {
      int m = m0 + (wv * 2 + mt2) * 16 + (ln >> 4) * 4 + r;
      if (m < M) {
#pragma unroll
        for (int nt = 0; nt < 8; ++nt) {
          int col = nt * 16 + ln15;
          OUT2[(size_t)m * HD + col] = acc[mt2][nt][r] + bias[col];
        }
      }
    }
  }
}

// ============ epilogue: ELU + LN + dot(W_lin) + batch-sum (one wave per row) ============
__global__ void ln2pool(const float* __restrict__ OUT2, const int* __restrict__ batch,
                        const float* __restrict__ g, const float* __restrict__ bb,
                        const float* __restrict__ Wl, float* __restrict__ accb) {
  int wv = threadIdx.x >> 6, ln = threadIdx.x & 63;
  int row = blockIdx.x * 4 + wv;
  if (row >= N_OP) return;
  float2 v = *(const float2*)&OUT2[(size_t)row * HD + ln * 2];
  v.x = (v.x > 0.f) ? v.x : (expf(v.x) - 1.f);
  v.y = (v.y > 0.f) ? v.y : (expf(v.y) - 1.f);
  float s = v.x + v.y, sq = v.x * v.x + v.y * v.y;
#pragma unroll
  for (int m = 32; m >= 1; m >>= 1) {
    s += __shfl_xor(s, m, 64);
    sq += __shfl_xor(sq, m, 64);
  }
  float mean = s * (1.0f / HD);
  float var = sq * (1.0f / HD) - mean * mean;
  float rstd = rsqrtf(var + 1e-5f);
  float2 gg = *(const float2*)&g[ln * 2];
  float2 b2 = *(const float2*)&bb[ln * 2];
  float2 wl = *(const float2*)&Wl[ln * 2];
  float o = ((v.x - mean) * rstd * gg.x + b2.x) * wl.x +
            ((v.y - mean) * rstd * gg.y + b2.y) * wl.y;
#pragma unroll
  for (int m = 32; m >= 1; m >>= 1) o += __shfl_xor(o, m, 64);
  if (ln == 0) atomicAdd(&accb[batch[row]], o);
}

__global__ void final_kernel(const float* __restrict__ accb, const float* __restrict__ pcnt,
                             const float* __restrict__ bl, float* __restrict__ out) {
  int b = blockIdx.x * 256 + threadIdx.x;
  if (b < NB) out[b] = accb[b] / fmaxf(pcnt[b], 1.0f) + bl[0];
}

// =================== host ===================
extern "C" void kernel_launch(void* const* d_in, const int* in_sizes, int n_in,
                              void* d_out, int out_size, void* d_ws, size_t ws_size,
                              hipStream_t stream) {
  const float* xt[7];
  for (int t = 0; t < 7; ++t) xt[t] = (const float*)d_in[t];
  const int* ei[14];
  for (int r = 0; r < 14; ++r) ei[r] = (const int*)d_in[7 + r];
  const int* batch = (const int*)d_in[21];
  const float* Wemb[7]; const float* bemb[7];
  for (int t = 0; t < 7; ++t) { Wemb[t] = (const float*)d_in[22 + 2 * t]; bemb[t] = (const float*)d_in[23 + 2 * t]; }
  const float* c_root[2] = {(const float*)d_in[36], (const float*)d_in[39]};
  const float* c_rel[2]  = {(const float*)d_in[37], (const float*)d_in[40]};
  const float* c_bias[2] = {(const float*)d_in[38], (const float*)d_in[41]};
  const float* ng[2] = {(const float*)d_in[42], (const float*)d_in[44]};
  const float* nbv[2] = {(const float*)d_in[43], (const float*)d_in[45]};
  const float* Wlin = (const float*)d_in[46];
  const float* blin = (const float*)d_in[47];
  float* out = (float*)d_out;

  char* base = (char*)d_ws;
  size_t off = 0;
  auto alloc = [&](size_t bytes) -> void* {
    void* p = base + off;
    off += (bytes + 255) & ~(size_t)255;
    return p;
  };
  __hip_bfloat16* Hb = (__hip_bfloat16*)alloc((size_t)N_L1 * HD * 2);
  float* OUT2 = (float*)alloc((size_t)N_OP * HD * 4);
  float* AGR  = (float*)alloc((size_t)AGR_TOT * 4);
  int*   ICNT = (int*)alloc((size_t)CNT_TOT * 4);
  int*   OFFS = (int*)alloc((size_t)CNT_TOT * 4);
  int*   CUR  = (int*)alloc((size_t)CNT_TOT * 4);
  float* CNTf = (float*)alloc((size_t)CNT_TOT * 4);
  int*   EDG  = (int*)alloc((size_t)EDG_TOT * 4);
  int*   BS   = (int*)alloc((size_t)1152 * 4);
  float* WC   = (float*)alloc((size_t)14 * 1280 * 4);
  float* BC   = (float*)alloc((size_t)14 * HD * 4);
  float* WR   = (float*)alloc((size_t)7 * 1280 * 4);
  float* BR   = (float*)alloc((size_t)7 * HD * 4);
  __hip_bfloat16* WT2 = (__hip_bfloat16*)alloc((size_t)6 * HD * 136 * 2);
  float* ACC  = (float*)alloc((size_t)NB * 4);
  float* PCNT = (float*)alloc((size_t)NB * 4);

  static const int l1_rels[12] = {0,1,2,3,4,5,6,7,8,11,12,13};

  // ---- memsets ----
  hipMemsetAsync(ICNT, 0, (size_t)CNT_TOT * 4, stream);
  hipMemsetAsync(ACC, 0, (size_t)NB * 4, stream);
  hipMemsetAsync(PCNT, 0, (size_t)NB * 4, stream);

  // ---- count pass (int atomics, 4.6 MB footprint) + batch counts ----
  CPackK CP1;
  int blk = 0;
  for (int q = 0; q < 12; ++q) {
    int r = l1_rels[q];
    CP1.j[q].dst = ei[r] + REL_E[r];
    CP1.j[q].coff = CNT_OFF[r];
    CP1.j[q].E = REL_E[r];
    CP1.j[q].blk0 = blk;
    blk += (REL_E[r] + 255) / 256;
  }
  CP1.bblk0 = blk; CP1.batch = batch; CP1.pcnt = PCNT; CP1.nop = N_OP;
  blk += (N_OP + 255) / 256;
  count_k<<<blk, 256, 0, stream>>>(CP1, ICNT);

  // ---- scan -> OFF, CUR, recip ----
  int nb1 = (CNT_TOT + SCAN_BLK - 1) / SCAN_BLK;   // 1133
  scan1<<<nb1, 256, 0, stream>>>(ICNT, OFFS, BS, CNT_TOT);
  scan2<<<1, 256, 0, stream>>>(BS, nb1);
  scan3<<<(CNT_TOT + 255) / 256, 256, 0, stream>>>(OFFS, CUR, CNTf, ICNT, BS, CNT_TOT);

  // ---- fill CSR ----
  FPackK FP;
  blk = 0;
  for (int q = 0; q < 12; ++q) {
    int r = l1_rels[q];
    FP.j[q].src = ei[r];
    FP.j[q].dst = ei[r] + REL_E[r];
    FP.j[q].coff = CNT_OFF[r];
    FP.j[q].E = REL_E[r];
    FP.j[q].blk0 = blk;
    blk += (REL_E[r] + 255) / 256;
  }
  fill_k<<<blk, 256, 0, stream>>>(FP, CUR, EDG);

  // ---- gather raw-feature sums (no atomics) ----
  {
    auto G = [&](auto Ftag, int r) {
      constexpr int F = decltype(Ftag)::value;
      int D = REL_DSZ[r];
      gather_agr<F><<<(D + 255) / 256, 256, 0, stream>>>(
          xt[SRC_T[r]], AGR + AGR_OFF[r], OFFS, ICNT, EDG, CNT_OFF[r], D);
    };
    G(std::integral_constant<int,2>{}, 0);
    G(std::integral_constant<int,4>{}, 1);
    G(std::integral_constant<int,10>{}, 2);
    G(std::integral_constant<int,10>{}, 3);
    G(std::integral_constant<int,4>{}, 4);
    G(std::integral_constant<int,8>{}, 5);
    G(std::integral_constant<int,8>{}, 6);
    G(std::integral_constant<int,1>{}, 7);
    G(std::integral_constant<int,1>{}, 8);
    G(std::integral_constant<int,2>{}, 11);
    G(std::integral_constant<int,10>{}, 12);
    G(std::integral_constant<int,4>{}, 13);
  }

  // ---- combined layer-1 weights + layer-2 bf16 weights ----
  CombPack CP;
  for (int q = 0; q < 12; ++q) {
    int r = l1_rels[q]; int t = SRC_T[r];
    CombJob& J = CP.j[q];
    J.A = Wemb[t]; J.bin = bemb[t]; J.Mtx = c_rel[0] + (size_t)r * HD * HD;
    J.extra = nullptr; J.Wout = WC + r * 1280; J.bout = BC + r * HD; J.F = TF[t];
  }
  for (int t = 0; t < 5; ++t) {
    CombJob& J = CP.j[12 + t];
    J.A = Wemb[t]; J.bin = bemb[t]; J.Mtx = c_root[0];
    J.extra = c_bias[0]; J.Wout = WR + t * 1280; J.bout = BR + t * HD; J.F = TF[t];
  }
  combine_all<<<17, 128, 0, stream>>>(CP);
  wprep_kernel<<<6, 256, 0, stream>>>(c_root[1], c_rel[1], WT2);

  // ---- layer 1 (fused matmul + ELU + LN), per dst type ----
  auto RT = [&](int r) {
    Term tm; tm.S = AGR + AGR_OFF[r]; tm.W = WC + r * 1280; tm.B = BC + r * HD;
    tm.recip = CNTf + CNT_OFF[r]; return tm;
  };
  auto RO = [&](int t) {
    Term tm; tm.S = xt[t]; tm.W = WR + t * 1280; tm.B = BR + t * HD;
    tm.recip = nullptr; return tm;
  };
  static const int TOFF5[5] = {0, 100000, 120000, 240000, 300000};
  {
    TPack<6> P = {{RO(0), RT(0), RT(1), RT(2), RT(4), RT(5)}};
    layer1_ln<4,2,4,10,4,8><<<TSZ[0] / 2, 256, 0, stream>>>(P, ng[0], nbv[0], Hb, TOFF5[0]);
  }
  {
    TPack<2> P = {{RO(1), RT(11)}};
    layer1_ln<2,2><<<TSZ[1] / 2, 256, 0, stream>>>(P, ng[0], nbv[0], Hb, TOFF5[1]);
  }
  {
    TPack<2> P = {{RO(2), RT(12)}};
    layer1_ln<10,10><<<TSZ[2] / 2, 256, 0, stream>>>(P, ng[0], nbv[0], Hb, TOFF5[2]);
  }
  {
    TPack<3> P = {{RO(3), RT(6), RT(13)}};
    layer1_ln<4,8,4><<<TSZ[3] / 2, 256, 0, stream>>>(P, ng[0], nbv[0], Hb, TOFF5[3]);
  }
  {
    TPack<4> P = {{RO(4), RT(3), RT(7), RT(8)}};
    layer1_ln<8,10,1,1><<<TSZ[4] / 2, 256, 0, stream>>>(P, ng[0], nbv[0], Hb, TOFF5[4]);
  }

  // ---- layer 2: fully fused, atomic-free ----
  l2_fused<<<(N_OP + 127) / 128, 256, 0, stream>>>(
      (const unsigned short*)Hb, (const unsigned short*)WT2,
      OFFS, ICNT, CNTf, EDG, c_bias[1], OUT2, N_OP);

  // ---- epilogue ----
  ln2pool<<<(N_OP + 3) / 4, 256, 0, stream>>>(OUT2, batch, ng[1], nbv[1], Wlin, ACC);
  final_kernel<<<(NB + 255) / 256, 256, 0, stream>>>(ACC, PCNT, blin, out);
}

// Round 5
// 820.500 us; speedup vs baseline: 2.6096x; 1.1778x over previous
//
#include <hip/hip_runtime.h>
#include <hip/hip_bf16.h>
#include <math.h>

#define HD 128
#define N_OP 100000
#define N_L1 400000
#define NB 2048
#define CNT_TOT 1160000
#define EDG_TOT 1100000

typedef short short8 __attribute__((ext_vector_type(8)));
typedef float floatx4 __attribute__((ext_vector_type(4)));

// relation tables (from reference EDGES/OFFS)
static const int REL_E[14]    = {100000,100000,100000,100000,100000,100000,100000,100000,100000,50000,50000,20000,120000,60000};
static const int CNT_OFF[14]  = {0,100000,200000,300000,400000,500000,600000,660000,760000,860000,910000,960000,980000,1100000};
static const int SRC_T[14] = {1,3,2,2,0,4,4,5,6,5,6,1,2,3};
static const int TF[7]  = {4,2,10,4,8,1,1};

// ---------------- bf16 helpers ----------------
__device__ inline unsigned short f2bf(float f) {
  union { float f; unsigned int u; } v; v.f = f;
  unsigned int r = v.u + 0x7FFF + ((v.u >> 16) & 1);
  return (unsigned short)(r >> 16);
}
__device__ inline float bfu2f(unsigned short u) {
  union { unsigned int i; float f; } v; v.i = ((unsigned int)u) << 16; return v.f;
}

// ============ count: int degree counts per (rel,dst) + float batch counts ============
struct CJob { const int* dst; int coff; int E; int blk0; };
struct CPackK { CJob j[12]; int bblk0; const int* batch; float* pcnt; int nop; };

__global__ void count_k(CPackK P, int* __restrict__ ICNT) {
  int b = blockIdx.x;
  if (b >= P.bblk0) {
    int i = (b - P.bblk0) * 256 + threadIdx.x;
    if (i < P.nop) atomicAdd(&P.pcnt[P.batch[i]], 1.0f);
    return;
  }
  int ji = 0;
#pragma unroll
  for (int i = 1; i < 12; ++i) if (b >= P.j[i].blk0) ji = i;
  CJob J = P.j[ji];
  int e = (b - J.blk0) * 256 + threadIdx.x;
  if (e < J.E) atomicAdd(&ICNT[J.coff + J.dst[e]], 1);
}

// ============ scans: exclusive prefix over ICNT ============
#define SCAN_BLK 1024
__global__ void scan1(const int* __restrict__ in, int* __restrict__ out,
                      int* __restrict__ bsum, int n) {
  __shared__ int sh[256];
  int t = threadIdx.x;
  int base = blockIdx.x * SCAN_BLK + t * 4;
  int v0 = 0, v1 = 0, v2 = 0, v3 = 0;
  if (base + 3 < n) { int4 q = *(const int4*)&in[base]; v0 = q.x; v1 = q.y; v2 = q.z; v3 = q.w; }
  else {
    if (base < n) v0 = in[base];
    if (base + 1 < n) v1 = in[base + 1];
    if (base + 2 < n) v2 = in[base + 2];
    if (base + 3 < n) v3 = in[base + 3];
  }
  int ts = v0 + v1 + v2 + v3;
  sh[t] = ts; __syncthreads();
  for (int o = 1; o < 256; o <<= 1) {
    int x = (t >= o) ? sh[t - o] : 0;
    __syncthreads();
    sh[t] += x;
    __syncthreads();
  }
  int excl = sh[t] - ts;
  if (base < n) out[base] = excl;
  if (base + 1 < n) out[base + 1] = excl + v0;
  if (base + 2 < n) out[base + 2] = excl + v0 + v1;
  if (base + 3 < n) out[base + 3] = excl + v0 + v1 + v2;
  if (t == 255) bsum[blockIdx.x] = sh[255];
}

__global__ void scan2(int* __restrict__ bs, int nb) {
  __shared__ int sh[256];
  int t = threadIdx.x;
  const int C = 5;
  int v[C]; int ts = 0;
#pragma unroll
  for (int i = 0; i < C; ++i) { int idx = t * C + i; v[i] = (idx < nb) ? bs[idx] : 0; ts += v[i]; }
  sh[t] = ts; __syncthreads();
  for (int o = 1; o < 256; o <<= 1) {
    int x = (t >= o) ? sh[t - o] : 0;
    __syncthreads();
    sh[t] += x;
    __syncthreads();
  }
  int run = sh[t] - ts;
#pragma unroll
  for (int i = 0; i < C; ++i) { int idx = t * C + i; if (idx < nb) bs[idx] = run; run += v[i]; }
}

__global__ void scan3(int* __restrict__ CUR, int2* __restrict__ OFF2,
                      const int* __restrict__ ICNT, const int* __restrict__ bs, int n) {
  int i = blockIdx.x * 256 + threadIdx.x;
  if (i < n) {
    int o = CUR[i] + bs[i >> 10];
    CUR[i] = o;
    OFF2[i] = make_int2(o, ICNT[i]);
  }
}

// ============ fill: EDG[pos] = src, grouped by (rel,dst) ============
struct FJob { const int* src; const int* dst; int coff; int E; int blk0; };
struct FPackK { FJob j[12]; };

__global__ void fill_k(FPackK P, int* __restrict__ CUR, int* __restrict__ EDG) {
  int b = blockIdx.x;
  int ji = 0;
#pragma unroll
  for (int i = 1; i < 12; ++i) if (b >= P.j[i].blk0) ji = i;
  FJob J = P.j[ji];
  int e = (b - J.blk0) * 256 + threadIdx.x;
  if (e < J.E) {
    int pos = atomicAdd(&CUR[J.coff + J.dst[e]], 1);
    EDG[pos] = J.src[e];
  }
}

// ============ weight prep: 17 combine jobs + 6 bf16-transpose jobs in one kernel ============
struct CombJob { const float* A; const float* bin; const float* Mtx; const float* extra; float* Wout; float* bout; int F; };
struct CombPack { CombJob j[17]; };

__global__ void weights_prep(CombPack P, const float* __restrict__ c2root,
                             const float* __restrict__ c2rel, __hip_bfloat16* __restrict__ Wt) {
  int b = blockIdx.x;
  if (b < 17) {
    if (threadIdx.x >= 128) return;
    CombJob J = P.j[b];
    int c = threadIdx.x;
    for (int f = 0; f <= J.F; ++f) {
      const float* arow = (f < J.F) ? &J.A[f * HD] : J.bin;
      float s = (f < J.F) ? 0.f : (J.extra ? J.extra[c] : 0.f);
      for (int k = 0; k < HD; ++k) s = fmaf(arow[k], J.Mtx[k * HD + c], s);
      if (f < J.F) J.Wout[f * HD + c] = s;
      else J.bout[c] = s;
    }
  } else {
    const int RID[6] = {-1, 0, 1, 2, 4, 5};
    int j = b - 17;
    const float* W = (j == 0) ? c2root : (c2rel + (size_t)RID[j] * HD * HD);
    __hip_bfloat16* o = Wt + (size_t)j * HD * 136;
    for (int i = threadIdx.x; i < HD * HD; i += 256) {
      int k = i >> 7, n = i & 127;
      o[n * 136 + k] = __float2bfloat16(W[i]);
    }
  }
}

// ============ layer-1: fused CSR-gather + matmul + ELU + LN, all 5 types, one kernel ============
struct L1Args {
  const float* x[7];
  const float* WC; const float* BC; const float* WR; const float* BR;
  const int2* OFF2; const int* EDG;
  const float* g; const float* b;
  __hip_bfloat16* Hb;
};

template <int F>
__device__ inline void t_root(float2& a, const float* __restrict__ x,
                              const float* __restrict__ W, const float* __restrict__ B,
                              int row, int c2) {
  float s[F];
#pragma unroll
  for (int f = 0; f < F; ++f) s[f] = x[(size_t)row * F + f];
  float dx = B[c2], dy = B[c2 + 1];
#pragma unroll
  for (int f = 0; f < F; ++f) {
    dx = fmaf(s[f], W[f * HD + c2], dx);
    dy = fmaf(s[f], W[f * HD + c2 + 1], dy);
  }
  a.x += dx; a.y += dy;
}

template <int F>
__device__ inline void t_rel(float2& a, const float* __restrict__ x,
                             const float* __restrict__ W, const float* __restrict__ B,
                             const int2* __restrict__ OFF2, const int* __restrict__ EDG,
                             int cb, int row, int c2) {
  int2 oc = OFF2[cb + row];
  if (oc.y == 0) return;   // empty dst: whole term absent
  float s[F];
#pragma unroll
  for (int f = 0; f < F; ++f) s[f] = 0.f;
  for (int e = 0; e < oc.y; ++e) {
    int si = EDG[oc.x + e];
#pragma unroll
    for (int f = 0; f < F; ++f) s[f] += x[(size_t)si * F + f];
  }
  float rc = 1.0f / (float)oc.y;
  float dx = 0.f, dy = 0.f;
#pragma unroll
  for (int f = 0; f < F; ++f) {
    dx = fmaf(s[f], W[f * HD + c2], dx);
    dy = fmaf(s[f], W[f * HD + c2 + 1], dy);
  }
  a.x += fmaf(dx, rc, B[c2]);
  a.y += fmaf(dy, rc, B[c2 + 1]);
}

__global__ void layer1_all(L1Args A) {
  const int b = blockIdx.x;
  const int wv = threadIdx.x >> 6, lane = threadIdx.x & 63;
  const int c2 = lane * 2;
  float2 a = {0.f, 0.f};
  int orow;
  if (b < 25000) {                       // operator, 100000 rows
    int row = b * 4 + wv;
    t_root<4>(a, A.x[0], A.WR + 0 * 1280, A.BR + 0 * HD, row, c2);
    t_rel<2>(a, A.x[1], A.WC + 0 * 1280, A.BC + 0 * HD, A.OFF2, A.EDG, 0, row, c2);
    t_rel<4>(a, A.x[3], A.WC + 1 * 1280, A.BC + 1 * HD, A.OFF2, A.EDG, 100000, row, c2);
    t_rel<10>(a, A.x[2], A.WC + 2 * 1280, A.BC + 2 * HD, A.OFF2, A.EDG, 200000, row, c2);
    t_rel<4>(a, A.x[0], A.WC + 4 * 1280, A.BC + 4 * HD, A.OFF2, A.EDG, 400000, row, c2);
    t_rel<8>(a, A.x[4], A.WC + 5 * 1280, A.BC + 5 * HD, A.OFF2, A.EDG, 500000, row, c2);
    orow = row;
  } else if (b < 30000) {                // table, 20000 rows
    int row = (b - 25000) * 4 + wv;
    t_root<2>(a, A.x[1], A.WR + 1 * 1280, A.BR + 1 * HD, row, c2);
    t_rel<2>(a, A.x[1], A.WC + 11 * 1280, A.BC + 11 * HD, A.OFF2, A.EDG, 960000, row, c2);
    orow = 100000 + row;
  } else if (b < 60000) {                // column, 120000 rows
    int row = (b - 30000) * 4 + wv;
    t_root<10>(a, A.x[2], A.WR + 2 * 1280, A.BR + 2 * HD, row, c2);
    t_rel<10>(a, A.x[2], A.WC + 12 * 1280, A.BC + 12 * HD, A.OFF2, A.EDG, 980000, row, c2);
    orow = 120000 + row;
  } else if (b < 75000) {                // predicate, 60000 rows
    int row = (b - 60000) * 4 + wv;
    t_root<4>(a, A.x[3], A.WR + 3 * 1280, A.BR + 3 * HD, row, c2);
    t_rel<8>(a, A.x[4], A.WC + 6 * 1280, A.BC + 6 * HD, A.OFF2, A.EDG, 600000, row, c2);
    t_rel<4>(a, A.x[3], A.WC + 13 * 1280, A.BC + 13 * HD, A.OFF2, A.EDG, 1100000, row, c2);
    orow = 240000 + row;
  } else {                               // operation, 100000 rows
    int row = (b - 75000) * 4 + wv;
    t_root<8>(a, A.x[4], A.WR + 4 * 1280, A.BR + 4 * HD, row, c2);
    t_rel<10>(a, A.x[2], A.WC + 3 * 1280, A.BC + 3 * HD, A.OFF2, A.EDG, 300000, row, c2);
    t_rel<1>(a, A.x[5], A.WC + 7 * 1280, A.BC + 7 * HD, A.OFF2, A.EDG, 660000, row, c2);
    t_rel<1>(a, A.x[6], A.WC + 8 * 1280, A.BC + 8 * HD, A.OFF2, A.EDG, 760000, row, c2);
    orow = 300000 + row;
  }

  // ELU + LN (row fully within one wave; 2 cols/lane)
  a.x = (a.x > 0.f) ? a.x : (expf(a.x) - 1.f);
  a.y = (a.y > 0.f) ? a.y : (expf(a.y) - 1.f);
  float s = a.x + a.y, sq = a.x * a.x + a.y * a.y;
#pragma unroll
  for (int m = 32; m >= 1; m >>= 1) {
    s += __shfl_xor(s, m, 64);
    sq += __shfl_xor(sq, m, 64);
  }
  float mean = s * (1.0f / HD);
  float var = sq * (1.0f / HD) - mean * mean;
  float rstd = rsqrtf(var + 1e-5f);
  float2 gg = *(const float2*)&A.g[c2];
  float2 bb = *(const float2*)&A.b[c2];
  float ox = (a.x - mean) * rstd * gg.x + bb.x;
  float oy = (a.y - mean) * rstd * gg.y + bb.y;
  unsigned int pack = (unsigned int)f2bf(ox) | ((unsigned int)f2bf(oy) << 16);
  *(unsigned int*)((unsigned short*)A.Hb + (size_t)orow * HD + c2) = pack;
}

// ============ layer-2: CSR gather -> MFMA (root + 5 rels) -> fused ELU+LN+dot+pool ============
__global__ __launch_bounds__(256, 4)
void l2_fused(const unsigned short* __restrict__ Hb, const unsigned short* __restrict__ Wall,
              const int2* __restrict__ OFF2, const int* __restrict__ EDG,
              const float* __restrict__ c2bias, const float* __restrict__ n2g,
              const float* __restrict__ n2b, const float* __restrict__ Wl,
              const int* __restrict__ batch, float* __restrict__ accb, int M) {
  const int CSR_OFF[5] = {0, 100000, 200000, 400000, 500000};   // rels 0,1,2,4,5
  const int SOFF[5]    = {100000, 240000, 120000, 0, 300000};   // Hb row offset of src type
  __shared__ unsigned short Ws[128 * 136];
  const int t = threadIdx.x, wv = t >> 6, ln = t & 63;
  const int quad = ln >> 4, ln15 = ln & 15, q8 = quad * 8;
  const int m0 = blockIdx.x * 64;
  const int rowA = m0 + wv * 16 + ln15;

  // per-lane column constants (cols nt*16 + ln15)
  float bias_c[8], gw[8];
  float pg = 0.f, pb = 0.f;
#pragma unroll
  for (int nt = 0; nt < 8; ++nt) {
    int col = nt * 16 + ln15;
    float wl = Wl[col], gc = n2g[col], bc = n2b[col];
    bias_c[nt] = c2bias[col];
    gw[nt] = gc * wl;
    pg += gc * wl;
    pb += bc * wl;
  }
#pragma unroll
  for (int m = 8; m >= 1; m >>= 1) {
    pg += __shfl_xor(pg, m, 64);
    pb += __shfl_xor(pb, m, 64);
  }

  floatx4 acc[8];
#pragma unroll
  for (int b = 0; b < 8; ++b) acc[b] = (floatx4){0.f, 0.f, 0.f, 0.f};

  for (int term = 0; term < 6; ++term) {
    __syncthreads();
    {
      const uint4* wg = (const uint4*)(Wall + (size_t)term * 128 * 136);
      uint4* ws4 = (uint4*)Ws;
#pragma unroll
      for (int i = 0; i < 9; ++i) {
        int idx = i * 256 + t;
        if (idx < 2176) ws4[idx] = wg[idx];
      }
    }
    __syncthreads();

    short8 afr[4];
    if (term == 0) {
      if (rowA < M) {
#pragma unroll
        for (int k4 = 0; k4 < 4; ++k4)
          afr[k4] = *(const short8*)&Hb[(size_t)rowA * HD + k4 * 32 + q8];
      } else {
#pragma unroll
        for (int k4 = 0; k4 < 4; ++k4)
#pragma unroll
          for (int j = 0; j < 8; ++j) afr[k4][j] = 0;
      }
    } else {
      float sum[4][8];
#pragma unroll
      for (int k4 = 0; k4 < 4; ++k4)
#pragma unroll
        for (int j = 0; j < 8; ++j) sum[k4][j] = 0.f;
      if (rowA < M) {
        int2 oc = OFF2[CSR_OFF[term - 1] + rowA];
        if (oc.y > 0) {
          int so = SOFF[term - 1];
          for (int e = 0; e < oc.y; ++e) {
            size_t s = (size_t)(EDG[oc.x + e] + so);
#pragma unroll
            for (int k4 = 0; k4 < 4; ++k4) {
              short8 h = *(const short8*)&Hb[s * HD + k4 * 32 + q8];
#pragma unroll
              for (int j = 0; j < 8; ++j) sum[k4][j] += bfu2f((unsigned short)h[j]);
            }
          }
          float rc = 1.0f / (float)oc.y;
#pragma unroll
          for (int k4 = 0; k4 < 4; ++k4)
#pragma unroll
            for (int j = 0; j < 8; ++j) sum[k4][j] *= rc;
        }
      }
#pragma unroll
      for (int k4 = 0; k4 < 4; ++k4)
#pragma unroll
        for (int j = 0; j < 8; ++j) afr[k4][j] = (short)f2bf(sum[k4][j]);
    }

#pragma unroll
    for (int nt = 0; nt < 8; ++nt) {
      int wrow = nt * 16 + ln15;
      short8 b0 = *(const short8*)&Ws[wrow * 136 + 0 + q8];
      short8 b1 = *(const short8*)&Ws[wrow * 136 + 32 + q8];
      short8 b2 = *(const short8*)&Ws[wrow * 136 + 64 + q8];
      short8 b3 = *(const short8*)&Ws[wrow * 136 + 96 + q8];
      acc[nt] = __builtin_amdgcn_mfma_f32_16x16x32_bf16(afr[0], b0, acc[nt], 0, 0, 0);
      acc[nt] = __builtin_amdgcn_mfma_f32_16x16x32_bf16(afr[1], b1, acc[nt], 0, 0, 0);
      acc[nt] = __builtin_amdgcn_mfma_f32_16x16x32_bf16(afr[2], b2, acc[nt], 0, 0, 0);
      acc[nt] = __builtin_amdgcn_mfma_f32_16x16x32_bf16(afr[3], b3, acc[nt], 0, 0, 0);
    }
  }

  // fused epilogue: ELU + LN + dot(Wl) + batch pool.
  // D row = quad*4 + r, col = nt*16 + ln15; dot = rstd*(S1 - mean*sgw) + sbw
#pragma unroll
  for (int r = 0; r < 4; ++r) {
    int rowD = m0 + wv * 16 + quad * 4 + r;
    float p = 0.f, q = 0.f, s1 = 0.f;
#pragma unroll
    for (int nt = 0; nt < 8; ++nt) {
      float v = acc[nt][r] + bias_c[nt];
      float e = (v > 0.f) ? v : (expf(v) - 1.f);
      p += e; q += e * e; s1 += e * gw[nt];
    }
#pragma unroll
    for (int m = 8; m >= 1; m >>= 1) {
      p += __shfl_xor(p, m, 64);
      q += __shfl_xor(q, m, 64);
      s1 += __shfl_xor(s1, m, 64);
    }
    if (ln15 == 0 && rowD < M) {
      float mean = p * (1.0f / HD);
      float var = q * (1.0f / HD) - mean * mean;
      float rstd = rsqrtf(var + 1e-5f);
      float o = rstd * (s1 - mean * pg) + pb;
      atomicAdd(&accb[batch[rowD]], o);
    }
  }
}

__global__ void final_kernel(const float* __restrict__ accb, const float* __restrict__ pcnt,
                             const float* __restrict__ bl, float* __restrict__ out) {
  int b = blockIdx.x * 256 + threadIdx.x;
  if (b < NB) out[b] = accb[b] / fmaxf(pcnt[b], 1.0f) + bl[0];
}

// =================== host ===================
extern "C" void kernel_launch(void* const* d_in, const int* in_sizes, int n_in,
                              void* d_out, int out_size, void* d_ws, size_t ws_size,
                              hipStream_t stream) {
  const float* xt[7];
  for (int t = 0; t < 7; ++t) xt[t] = (const float*)d_in[t];
  const int* ei[14];
  for (int r = 0; r < 14; ++r) ei[r] = (const int*)d_in[7 + r];
  const int* batch = (const int*)d_in[21];
  const float* Wemb[7]; const float* bemb[7];
  for (int t = 0; t < 7; ++t) { Wemb[t] = (const float*)d_in[22 + 2 * t]; bemb[t] = (const float*)d_in[23 + 2 * t]; }
  const float* c_root[2] = {(const float*)d_in[36], (const float*)d_in[39]};
  const float* c_rel[2]  = {(const float*)d_in[37], (const float*)d_in[40]};
  const float* c_bias[2] = {(const float*)d_in[38], (const float*)d_in[41]};
  const float* ng[2] = {(const float*)d_in[42], (const float*)d_in[44]};
  const float* nbv[2] = {(const float*)d_in[43], (const float*)d_in[45]};
  const float* Wlin = (const float*)d_in[46];
  const float* blin = (const float*)d_in[47];
  float* out = (float*)d_out;

  char* base = (char*)d_ws;
  size_t off = 0;
  auto alloc = [&](size_t bytes) -> void* {
    void* p = base + off;
    off += (bytes + 255) & ~(size_t)255;
    return p;
  };
  __hip_bfloat16* Hb = (__hip_bfloat16*)alloc((size_t)N_L1 * HD * 2);
  int*   ICNT = (int*)alloc((size_t)CNT_TOT * 4);
  int*   CUR  = (int*)alloc((size_t)CNT_TOT * 4);
  int2*  OFF2 = (int2*)alloc((size_t)CNT_TOT * 8);
  int*   EDG  = (int*)alloc((size_t)EDG_TOT * 4);
  int*   BS   = (int*)alloc((size_t)1152 * 4);
  float* WC   = (float*)alloc((size_t)14 * 1280 * 4);
  float* BC   = (float*)alloc((size_t)14 * HD * 4);
  float* WR   = (float*)alloc((size_t)7 * 1280 * 4);
  float* BR   = (float*)alloc((size_t)7 * HD * 4);
  __hip_bfloat16* WT2 = (__hip_bfloat16*)alloc((size_t)6 * HD * 136 * 2);
  float* ACC  = (float*)alloc((size_t)NB * 4);      // ACC and PCNT adjacent:
  float* PCNT = (float*)alloc((size_t)NB * 4);      // one memset covers both

  static const int l1_rels[12] = {0,1,2,3,4,5,6,7,8,11,12,13};

  // ---- memsets (2) ----
  hipMemsetAsync(ICNT, 0, (size_t)CNT_TOT * 4, stream);
  hipMemsetAsync(ACC, 0, (size_t)2 * NB * 4, stream);

  // ---- count (incl. batch counts) ----
  CPackK CP1;
  int blk = 0;
  for (int q = 0; q < 12; ++q) {
    int r = l1_rels[q];
    CP1.j[q].dst = ei[r] + REL_E[r];
    CP1.j[q].coff = CNT_OFF[r];
    CP1.j[q].E = REL_E[r];
    CP1.j[q].blk0 = blk;
    blk += (REL_E[r] + 255) / 256;
  }
  CP1.bblk0 = blk; CP1.batch = batch; CP1.pcnt = PCNT; CP1.nop = N_OP;
  blk += (N_OP + 255) / 256;
  count_k<<<blk, 256, 0, stream>>>(CP1, ICNT);

  // ---- scan -> CUR (running offsets), OFF2 (off,cnt) ----
  int nb1 = (CNT_TOT + SCAN_BLK - 1) / SCAN_BLK;   // 1133
  scan1<<<nb1, 256, 0, stream>>>(ICNT, CUR, BS, CNT_TOT);
  scan2<<<1, 256, 0, stream>>>(BS, nb1);
  scan3<<<(CNT_TOT + 255) / 256, 256, 0, stream>>>(CUR, OFF2, ICNT, BS, CNT_TOT);

  // ---- fill CSR ----
  FPackK FP;
  blk = 0;
  for (int q = 0; q < 12; ++q) {
    int r = l1_rels[q];
    FP.j[q].src = ei[r];
    FP.j[q].dst = ei[r] + REL_E[r];
    FP.j[q].coff = CNT_OFF[r];
    FP.j[q].E = REL_E[r];
    FP.j[q].blk0 = blk;
    blk += (REL_E[r] + 255) / 256;
  }
  fill_k<<<blk, 256, 0, stream>>>(FP, CUR, EDG);

  // ---- weights: 12 rel-combine + 5 root-combine + 6 bf16-transpose ----
  CombPack CP;
  for (int q = 0; q < 12; ++q) {
    int r = l1_rels[q]; int t = SRC_T[r];
    CombJob& J = CP.j[q];
    J.A = Wemb[t]; J.bin = bemb[t]; J.Mtx = c_rel[0] + (size_t)r * HD * HD;
    J.extra = nullptr; J.Wout = WC + r * 1280; J.bout = BC + r * HD; J.F = TF[t];
  }
  for (int t = 0; t < 5; ++t) {
    CombJob& J = CP.j[12 + t];
    J.A = Wemb[t]; J.bin = bemb[t]; J.Mtx = c_root[0];
    J.extra = c_bias[0]; J.Wout = WR + t * 1280; J.bout = BR + t * HD; J.F = TF[t];
  }
  weights_prep<<<23, 256, 0, stream>>>(CP, c_root[1], c_rel[1], WT2);

  // ---- layer 1: one kernel, all types, in-kernel CSR gather ----
  L1Args A;
  for (int t = 0; t < 7; ++t) A.x[t] = xt[t];
  A.WC = WC; A.BC = BC; A.WR = WR; A.BR = BR;
  A.OFF2 = OFF2; A.EDG = EDG; A.g = ng[0]; A.b = nbv[0]; A.Hb = Hb;
  layer1_all<<<100000, 256, 0, stream>>>(A);

  // ---- layer 2: fused MFMA + ELU + LN + dot + pool ----
  l2_fused<<<(N_OP + 63) / 64, 256, 0, stream>>>(
      (const unsigned short*)Hb, (const unsigned short*)WT2,
      OFF2, EDG, c_bias[1], ng[1], nbv[1], Wlin, batch, ACC, N_OP);

  // ---- final scale ----
  final_kernel<<<(NB + 255) / 256, 256, 0, stream>>>(ACC, PCNT, blin, out);
}

// Round 6
// 779.626 us; speedup vs baseline: 2.7464x; 1.0524x over previous
//
#include <hip/hip_runtime.h>
#include <hip/hip_bf16.h>
#include <math.h>

#define HD 128
#define N_OP 100000
#define N_L1 400000
#define NB 2048
#define CNT_TOT 1160000
#define EDG_TOT 1100000

typedef short short8 __attribute__((ext_vector_type(8)));
typedef float floatx4 __attribute__((ext_vector_type(4)));

// relation tables (from reference EDGES/OFFS)
static const int REL_E[14]    = {100000,100000,100000,100000,100000,100000,100000,100000,100000,50000,50000,20000,120000,60000};
static const int REL_DSZ[14]  = {100000,100000,100000,100000,100000,100000,60000,100000,100000,50000,50000,20000,120000,60000};
static const int CNT_OFF[14]  = {0,100000,200000,300000,400000,500000,600000,660000,760000,860000,910000,960000,980000,1100000};
static const int SRC_T[14] = {1,3,2,2,0,4,4,5,6,5,6,1,2,3};
static const int TF[7]  = {4,2,10,4,8,1,1};
static const size_t AGR_OFF[14] = {0,200000,600000,1600000,2600000,3000000,3800000,4280000,4380000,0,0,4480000,4520000,5720000};
#define AGR_TOT 5960000

// ---------------- bf16 helpers ----------------
__device__ inline unsigned short f2bf(float f) {
  union { float f; unsigned int u; } v; v.f = f;
  unsigned int r = v.u + 0x7FFF + ((v.u >> 16) & 1);
  return (unsigned short)(r >> 16);
}
__device__ inline float bfu2f(unsigned short u) {
  union { unsigned int i; float f; } v; v.i = ((unsigned int)u) << 16; return v.f;
}

// ============ count: int degree counts per (rel,dst) + float batch counts ============
struct CJob { const int* dst; int coff; int E; int blk0; };
struct CPackK { CJob j[12]; int bblk0; const int* batch; float* pcnt; int nop; };

__global__ void count_k(CPackK P, int* __restrict__ ICNT) {
  int b = blockIdx.x;
  if (b >= P.bblk0) {
    int i = (b - P.bblk0) * 256 + threadIdx.x;
    if (i < P.nop) atomicAdd(&P.pcnt[P.batch[i]], 1.0f);
    return;
  }
  int ji = 0;
#pragma unroll
  for (int i = 1; i < 12; ++i) if (b >= P.j[i].blk0) ji = i;
  CJob J = P.j[ji];
  int e = (b - J.blk0) * 256 + threadIdx.x;
  if (e < J.E) atomicAdd(&ICNT[J.coff + J.dst[e]], 1);
}

// ============ scans: exclusive prefix over ICNT ============
#define SCAN_BLK 1024
__global__ void scan1(const int* __restrict__ in, int* __restrict__ out,
                      int* __restrict__ bsum, int n) {
  __shared__ int sh[256];
  int t = threadIdx.x;
  int base = blockIdx.x * SCAN_BLK + t * 4;
  int v0 = 0, v1 = 0, v2 = 0, v3 = 0;
  if (base + 3 < n) { int4 q = *(const int4*)&in[base]; v0 = q.x; v1 = q.y; v2 = q.z; v3 = q.w; }
  else {
    if (base < n) v0 = in[base];
    if (base + 1 < n) v1 = in[base + 1];
    if (base + 2 < n) v2 = in[base + 2];
    if (base + 3 < n) v3 = in[base + 3];
  }
  int ts = v0 + v1 + v2 + v3;
  sh[t] = ts; __syncthreads();
  for (int o = 1; o < 256; o <<= 1) {
    int x = (t >= o) ? sh[t - o] : 0;
    __syncthreads();
    sh[t] += x;
    __syncthreads();
  }
  int excl = sh[t] - ts;
  if (base < n) out[base] = excl;
  if (base + 1 < n) out[base + 1] = excl + v0;
  if (base + 2 < n) out[base + 2] = excl + v0 + v1;
  if (base + 3 < n) out[base + 3] = excl + v0 + v1 + v2;
  if (t == 255) bsum[blockIdx.x] = sh[255];
}

__global__ void scan2(int* __restrict__ bs, int nb) {
  __shared__ int sh[256];
  int t = threadIdx.x;
  const int C = 5;
  int v[C]; int ts = 0;
#pragma unroll
  for (int i = 0; i < C; ++i) { int idx = t * C + i; v[i] = (idx < nb) ? bs[idx] : 0; ts += v[i]; }
  sh[t] = ts; __syncthreads();
  for (int o = 1; o < 256; o <<= 1) {
    int x = (t >= o) ? sh[t - o] : 0;
    __syncthreads();
    sh[t] += x;
    __syncthreads();
  }
  int run = sh[t] - ts;
#pragma unroll
  for (int i = 0; i < C; ++i) { int idx = t * C + i; if (idx < nb) bs[idx] = run; run += v[i]; }
}

__global__ void scan3(int* __restrict__ CUR, int2* __restrict__ OFF2,
                      const int* __restrict__ ICNT, const int* __restrict__ bs, int n) {
  int i = blockIdx.x * 256 + threadIdx.x;
  if (i < n) {
    int o = CUR[i] + bs[i >> 10];
    CUR[i] = o;
    OFF2[i] = make_int2(o, ICNT[i]);
  }
}

// ============ fill: EDG[pos] = src, grouped by (rel,dst) ============
struct FJob { const int* src; const int* dst; int coff; int E; int blk0; };
struct FPackK { FJob j[12]; };

__global__ void fill_k(FPackK P, int* __restrict__ CUR, int* __restrict__ EDG) {
  int b = blockIdx.x;
  int ji = 0;
#pragma unroll
  for (int i = 1; i < 12; ++i) if (b >= P.j[i].blk0) ji = i;
  FJob J = P.j[ji];
  int e = (b - J.blk0) * 256 + threadIdx.x;
  if (e < J.E) {
    int pos = atomicAdd(&CUR[J.coff + J.dst[e]], 1);
    EDG[pos] = J.src[e];
  }
}

// ============ gather_all: one thread per (rel,dst), AGR[d,:F] = mean(x[src,:F]) ============
struct GJob { const float* x; float* agr; int coff; int D; int F; int blk0; };
struct GPack { GJob j[12]; };

template <int F>
__device__ inline void gathF(const float* __restrict__ x, float* __restrict__ agr,
                             const int* __restrict__ EDG, int2 oc, int d) {
  if (oc.y == 0) return;
  float s[F];
#pragma unroll
  for (int f = 0; f < F; ++f) s[f] = 0.f;
  for (int e = 0; e < oc.y; ++e) {
    int si = EDG[oc.x + e];
    const float* xp = &x[(size_t)si * F];
#pragma unroll
    for (int f = 0; f < F; ++f) s[f] += xp[f];
  }
  float rc = 1.0f / (float)oc.y;
  float* ap = &agr[(size_t)d * F];
#pragma unroll
  for (int f = 0; f < F; ++f) ap[f] = s[f] * rc;
}

__global__ void gather_all(GPack P, const int2* __restrict__ OFF2, const int* __restrict__ EDG) {
  int b = blockIdx.x;
  int ji = 0;
#pragma unroll
  for (int i = 1; i < 12; ++i) if (b >= P.j[i].blk0) ji = i;
  GJob J = P.j[ji];
  int d = (b - J.blk0) * 256 + threadIdx.x;
  if (d >= J.D) return;
  int2 oc = OFF2[J.coff + d];
  switch (J.F) {
    case 1:  gathF<1>(J.x, J.agr, EDG, oc, d); break;
    case 2:  gathF<2>(J.x, J.agr, EDG, oc, d); break;
    case 4:  gathF<4>(J.x, J.agr, EDG, oc, d); break;
    case 8:  gathF<8>(J.x, J.agr, EDG, oc, d); break;
    default: gathF<10>(J.x, J.agr, EDG, oc, d); break;
  }
}

// ============ weight prep: 17 combine jobs + 6 bf16-transpose jobs ============
struct CombJob { const float* A; const float* bin; const float* Mtx; const float* extra; float* Wout; float* bout; int F; };
struct CombPack { CombJob j[17]; };

__global__ void weights_prep(CombPack P, const float* __restrict__ c2root,
                             const float* __restrict__ c2rel, __hip_bfloat16* __restrict__ Wt) {
  int b = blockIdx.x;
  if (b < 17) {
    if (threadIdx.x >= 128) return;
    CombJob J = P.j[b];
    int c = threadIdx.x;
    for (int f = 0; f <= J.F; ++f) {
      const float* arow = (f < J.F) ? &J.A[f * HD] : J.bin;
      float s = (f < J.F) ? 0.f : (J.extra ? J.extra[c] : 0.f);
      for (int k = 0; k < HD; ++k) s = fmaf(arow[k], J.Mtx[k * HD + c], s);
      if (f < J.F) J.Wout[f * HD + c] = s;
      else J.bout[c] = s;
    }
  } else {
    const int RID[6] = {-1, 0, 1, 2, 4, 5};
    int j = b - 17;
    const float* W = (j == 0) ? c2root : (c2rel + (size_t)RID[j] * HD * HD);
    __hip_bfloat16* o = Wt + (size_t)j * HD * 136;
    for (int i = threadIdx.x; i < HD * HD; i += 256) {
      int k = i >> 7, n = i & 127;
      o[n * 136 + k] = __float2bfloat16(W[i]);
    }
  }
}

// ============ layer-1 matmul + ELU + LN (reads pre-averaged AGR) ============
struct L1Args {
  const float* x[7];
  const float* AGR;
  const float* WC; const float* BC; const float* WR; const float* BR;
  const int2* OFF2;
  const float* g; const float* b;
  __hip_bfloat16* Hb;
};

template <int F>
__device__ inline void t_root(float2& a, const float* __restrict__ x,
                              const float* __restrict__ W, const float* __restrict__ B,
                              int row, int c2) {
  float s[F];
#pragma unroll
  for (int f = 0; f < F; ++f) s[f] = x[(size_t)row * F + f];
  float dx = B[c2], dy = B[c2 + 1];
#pragma unroll
  for (int f = 0; f < F; ++f) {
    dx = fmaf(s[f], W[f * HD + c2], dx);
    dy = fmaf(s[f], W[f * HD + c2 + 1], dy);
  }
  a.x += dx; a.y += dy;
}

template <int F>
__device__ inline void t_rel(float2& a, const float* __restrict__ agr,
                             const float* __restrict__ W, const float* __restrict__ B,
                             const int2* __restrict__ OFF2, int cb, int row, int c2) {
  if (OFF2[cb + row].y == 0) return;   // empty dst: whole term absent
  const float* sp = &agr[(size_t)row * F];
  float dx = B[c2], dy = B[c2 + 1];
#pragma unroll
  for (int f = 0; f < F; ++f) {
    float sv = sp[f];
    dx = fmaf(sv, W[f * HD + c2], dx);
    dy = fmaf(sv, W[f * HD + c2 + 1], dy);
  }
  a.x += dx; a.y += dy;
}

__global__ void layer1_mm(L1Args A) {
  const int b = blockIdx.x;
  const int wv = threadIdx.x >> 6, lane = threadIdx.x & 63;
  const int c2 = lane * 2;
  float2 a = {0.f, 0.f};
  int orow;
  if (b < 25000) {                       // operator, 100000 rows
    int row = b * 4 + wv;
    t_root<4>(a, A.x[0], A.WR + 0 * 1280, A.BR + 0 * HD, row, c2);
    t_rel<2>(a, A.AGR + AGR_OFF[0], A.WC + 0 * 1280, A.BC + 0 * HD, A.OFF2, 0, row, c2);
    t_rel<4>(a, A.AGR + AGR_OFF[1], A.WC + 1 * 1280, A.BC + 1 * HD, A.OFF2, 100000, row, c2);
    t_rel<10>(a, A.AGR + AGR_OFF[2], A.WC + 2 * 1280, A.BC + 2 * HD, A.OFF2, 200000, row, c2);
    t_rel<4>(a, A.AGR + AGR_OFF[4], A.WC + 4 * 1280, A.BC + 4 * HD, A.OFF2, 400000, row, c2);
    t_rel<8>(a, A.AGR + AGR_OFF[5], A.WC + 5 * 1280, A.BC + 5 * HD, A.OFF2, 500000, row, c2);
    orow = row;
  } else if (b < 30000) {                // table, 20000 rows
    int row = (b - 25000) * 4 + wv;
    t_root<2>(a, A.x[1], A.WR + 1 * 1280, A.BR + 1 * HD, row, c2);
    t_rel<2>(a, A.AGR + AGR_OFF[11], A.WC + 11 * 1280, A.BC + 11 * HD, A.OFF2, 960000, row, c2);
    orow = 100000 + row;
  } else if (b < 60000) {                // column, 120000 rows
    int row = (b - 30000) * 4 + wv;
    t_root<10>(a, A.x[2], A.WR + 2 * 1280, A.BR + 2 * HD, row, c2);
    t_rel<10>(a, A.AGR + AGR_OFF[12], A.WC + 12 * 1280, A.BC + 12 * HD, A.OFF2, 980000, row, c2);
    orow = 120000 + row;
  } else if (b < 75000) {                // predicate, 60000 rows
    int row = (b - 60000) * 4 + wv;
    t_root<4>(a, A.x[3], A.WR + 3 * 1280, A.BR + 3 * HD, row, c2);
    t_rel<8>(a, A.AGR + AGR_OFF[6], A.WC + 6 * 1280, A.BC + 6 * HD, A.OFF2, 600000, row, c2);
    t_rel<4>(a, A.AGR + AGR_OFF[13], A.WC + 13 * 1280, A.BC + 13 * HD, A.OFF2, 1100000, row, c2);
    orow = 240000 + row;
  } else {                               // operation, 100000 rows
    int row = (b - 75000) * 4 + wv;
    t_root<8>(a, A.x[4], A.WR + 4 * 1280, A.BR + 4 * HD, row, c2);
    t_rel<10>(a, A.AGR + AGR_OFF[3], A.WC + 3 * 1280, A.BC + 3 * HD, A.OFF2, 300000, row, c2);
    t_rel<1>(a, A.AGR + AGR_OFF[7], A.WC + 7 * 1280, A.BC + 7 * HD, A.OFF2, 660000, row, c2);
    t_rel<1>(a, A.AGR + AGR_OFF[8], A.WC + 8 * 1280, A.BC + 8 * HD, A.OFF2, 760000, row, c2);
    orow = 300000 + row;
  }

  // ELU + LN (row fully within one wave; 2 cols/lane)
  a.x = (a.x > 0.f) ? a.x : (expf(a.x) - 1.f);
  a.y = (a.y > 0.f) ? a.y : (expf(a.y) - 1.f);
  float s = a.x + a.y, sq = a.x * a.x + a.y * a.y;
#pragma unroll
  for (int m = 32; m >= 1; m >>= 1) {
    s += __shfl_xor(s, m, 64);
    sq += __shfl_xor(sq, m, 64);
  }
  float mean = s * (1.0f / HD);
  float var = sq * (1.0f / HD) - mean * mean;
  float rstd = rsqrtf(var + 1e-5f);
  float2 gg = *(const float2*)&A.g[c2];
  float2 bb = *(const float2*)&A.b[c2];
  float ox = (a.x - mean) * rstd * gg.x + bb.x;
  float oy = (a.y - mean) * rstd * gg.y + bb.y;
  unsigned int pack = (unsigned int)f2bf(ox) | ((unsigned int)f2bf(oy) << 16);
  *(unsigned int*)((unsigned short*)A.Hb + (size_t)orow * HD + c2) = pack;
}

// ============ layer-2: CSR gather -> MFMA (root + 5 rels) -> fused ELU+LN+dot+pool ============
__global__ __launch_bounds__(256, 4)
void l2_fused(const unsigned short* __restrict__ Hb, const unsigned short* __restrict__ Wall,
              const int2* __restrict__ OFF2, const int* __restrict__ EDG,
              const float* __restrict__ c2bias, const float* __restrict__ n2g,
              const float* __restrict__ n2b, const float* __restrict__ Wl,
              const int* __restrict__ batch, float* __restrict__ accb, int M) {
  const int CSR_OFF[5] = {0, 100000, 200000, 400000, 500000};   // rels 0,1,2,4,5
  const int SOFF[5]    = {100000, 240000, 120000, 0, 300000};   // Hb row offset of src type
  __shared__ unsigned short Ws[128 * 136];
  const int t = threadIdx.x, wv = t >> 6, ln = t & 63;
  const int quad = ln >> 4, ln15 = ln & 15, q8 = quad * 8;
  const int m0 = blockIdx.x * 64;
  const int rowA = m0 + wv * 16 + ln15;

  float bias_c[8], gw[8];
  float pg = 0.f, pb = 0.f;
#pragma unroll
  for (int nt = 0; nt < 8; ++nt) {
    int col = nt * 16 + ln15;
    float wl = Wl[col], gc = n2g[col], bc = n2b[col];
    bias_c[nt] = c2bias[col];
    gw[nt] = gc * wl;
    pg += gc * wl;
    pb += bc * wl;
  }
#pragma unroll
  for (int m = 8; m >= 1; m >>= 1) {
    pg += __shfl_xor(pg, m, 64);
    pb += __shfl_xor(pb, m, 64);
  }

  floatx4 acc[8];
#pragma unroll
  for (int b = 0; b < 8; ++b) acc[b] = (floatx4){0.f, 0.f, 0.f, 0.f};

  for (int term = 0; term < 6; ++term) {
    __syncthreads();
    {
      const uint4* wg = (const uint4*)(Wall + (size_t)term * 128 * 136);
      uint4* ws4 = (uint4*)Ws;
#pragma unroll
      for (int i = 0; i < 9; ++i) {
        int idx = i * 256 + t;
        if (idx < 2176) ws4[idx] = wg[idx];
      }
    }
    __syncthreads();

    short8 afr[4];
    if (term == 0) {
      if (rowA < M) {
#pragma unroll
        for (int k4 = 0; k4 < 4; ++k4)
          afr[k4] = *(const short8*)&Hb[(size_t)rowA * HD + k4 * 32 + q8];
      } else {
#pragma unroll
        for (int k4 = 0; k4 < 4; ++k4)
#pragma unroll
          for (int j = 0; j < 8; ++j) afr[k4][j] = 0;
      }
    } else {
      float sum[4][8];
#pragma unroll
      for (int k4 = 0; k4 < 4; ++k4)
#pragma unroll
        for (int j = 0; j < 8; ++j) sum[k4][j] = 0.f;
      if (rowA < M) {
        int2 oc = OFF2[CSR_OFF[term - 1] + rowA];
        if (oc.y > 0) {
          int so = SOFF[term - 1];
          for (int e = 0; e < oc.y; ++e) {
            size_t s = (size_t)(EDG[oc.x + e] + so);
#pragma unroll
            for (int k4 = 0; k4 < 4; ++k4) {
              short8 h = *(const short8*)&Hb[s * HD + k4 * 32 + q8];
#pragma unroll
              for (int j = 0; j < 8; ++j) sum[k4][j] += bfu2f((unsigned short)h[j]);
            }
          }
          float rc = 1.0f / (float)oc.y;
#pragma unroll
          for (int k4 = 0; k4 < 4; ++k4)
#pragma unroll
            for (int j = 0; j < 8; ++j) sum[k4][j] *= rc;
        }
      }
#pragma unroll
      for (int k4 = 0; k4 < 4; ++k4)
#pragma unroll
        for (int j = 0; j < 8; ++j) afr[k4][j] = (short)f2bf(sum[k4][j]);
    }

#pragma unroll
    for (int nt = 0; nt < 8; ++nt) {
      int wrow = nt * 16 + ln15;
      short8 b0 = *(const short8*)&Ws[wrow * 136 + 0 + q8];
      short8 b1 = *(const short8*)&Ws[wrow * 136 + 32 + q8];
      short8 b2 = *(const short8*)&Ws[wrow * 136 + 64 + q8];
      short8 b3 = *(const short8*)&Ws[wrow * 136 + 96 + q8];
      acc[nt] = __builtin_amdgcn_mfma_f32_16x16x32_bf16(afr[0], b0, acc[nt], 0, 0, 0);
      acc[nt] = __builtin_amdgcn_mfma_f32_16x16x32_bf16(afr[1], b1, acc[nt], 0, 0, 0);
      acc[nt] = __builtin_amdgcn_mfma_f32_16x16x32_bf16(afr[2], b2, acc[nt], 0, 0, 0);
      acc[nt] = __builtin_amdgcn_mfma_f32_16x16x32_bf16(afr[3], b3, acc[nt], 0, 0, 0);
    }
  }

  // fused epilogue: ELU + LN + dot(Wl) + batch pool
#pragma unroll
  for (int r = 0; r < 4; ++r) {
    int rowD = m0 + wv * 16 + quad * 4 + r;
    float p = 0.f, q = 0.f, s1 = 0.f;
#pragma unroll
    for (int nt = 0; nt < 8; ++nt) {
      float v = acc[nt][r] + bias_c[nt];
      float e = (v > 0.f) ? v : (expf(v) - 1.f);
      p += e; q += e * e; s1 += e * gw[nt];
    }
#pragma unroll
    for (int m = 8; m >= 1; m >>= 1) {
      p += __shfl_xor(p, m, 64);
      q += __shfl_xor(q, m, 64);
      s1 += __shfl_xor(s1, m, 64);
    }
    if (ln15 == 0 && rowD < M) {
      float mean = p * (1.0f / HD);
      float var = q * (1.0f / HD) - mean * mean;
      float rstd = rsqrtf(var + 1e-5f);
      float o = rstd * (s1 - mean * pg) + pb;
      atomicAdd(&accb[batch[rowD]], o);
    }
  }
}

__global__ void final_kernel(const float* __restrict__ accb, const float* __restrict__ pcnt,
                             const float* __restrict__ bl, float* __restrict__ out) {
  int b = blockIdx.x * 256 + threadIdx.x;
  if (b < NB) out[b] = accb[b] / fmaxf(pcnt[b], 1.0f) + bl[0];
}

// =================== host ===================
extern "C" void kernel_launch(void* const* d_in, const int* in_sizes, int n_in,
                              void* d_out, int out_size, void* d_ws, size_t ws_size,
                              hipStream_t stream) {
  const float* xt[7];
  for (int t = 0; t < 7; ++t) xt[t] = (const float*)d_in[t];
  const int* ei[14];
  for (int r = 0; r < 14; ++r) ei[r] = (const int*)d_in[7 + r];
  const int* batch = (const int*)d_in[21];
  const float* Wemb[7]; const float* bemb[7];
  for (int t = 0; t < 7; ++t) { Wemb[t] = (const float*)d_in[22 + 2 * t]; bemb[t] = (const float*)d_in[23 + 2 * t]; }
  const float* c_root[2] = {(const float*)d_in[36], (const float*)d_in[39]};
  const float* c_rel[2]  = {(const float*)d_in[37], (const float*)d_in[40]};
  const float* c_bias[2] = {(const float*)d_in[38], (const float*)d_in[41]};
  const float* ng[2] = {(const float*)d_in[42], (const float*)d_in[44]};
  const float* nbv[2] = {(const float*)d_in[43], (const float*)d_in[45]};
  const float* Wlin = (const float*)d_in[46];
  const float* blin = (const float*)d_in[47];
  float* out = (float*)d_out;

  char* base = (char*)d_ws;
  size_t off = 0;
  auto alloc = [&](size_t bytes) -> void* {
    void* p = base + off;
    off += (bytes + 255) & ~(size_t)255;
    return p;
  };
  __hip_bfloat16* Hb = (__hip_bfloat16*)alloc((size_t)N_L1 * HD * 2);
  float* AGR  = (float*)alloc((size_t)AGR_TOT * 4);
  int*   ICNT = (int*)alloc((size_t)CNT_TOT * 4);
  int*   CUR  = (int*)alloc((size_t)CNT_TOT * 4);
  int2*  OFF2 = (int2*)alloc((size_t)CNT_TOT * 8);
  int*   EDG  = (int*)alloc((size_t)EDG_TOT * 4);
  int*   BS   = (int*)alloc((size_t)1152 * 4);
  float* WC   = (float*)alloc((size_t)14 * 1280 * 4);
  float* BC   = (float*)alloc((size_t)14 * HD * 4);
  float* WR   = (float*)alloc((size_t)7 * 1280 * 4);
  float* BR   = (float*)alloc((size_t)7 * HD * 4);
  __hip_bfloat16* WT2 = (__hip_bfloat16*)alloc((size_t)6 * HD * 136 * 2);
  float* ACC  = (float*)alloc((size_t)NB * 4);      // ACC and PCNT adjacent:
  float* PCNT = (float*)alloc((size_t)NB * 4);      // one memset covers both

  static const int l1_rels[12] = {0,1,2,3,4,5,6,7,8,11,12,13};

  // ---- memsets (2) ----
  hipMemsetAsync(ICNT, 0, (size_t)CNT_TOT * 4, stream);
  hipMemsetAsync(ACC, 0, (size_t)2 * NB * 4, stream);

  // ---- count (incl. batch counts) ----
  CPackK CP1;
  int blk = 0;
  for (int q = 0; q < 12; ++q) {
    int r = l1_rels[q];
    CP1.j[q].dst = ei[r] + REL_E[r];
    CP1.j[q].coff = CNT_OFF[r];
    CP1.j[q].E = REL_E[r];
    CP1.j[q].blk0 = blk;
    blk += (REL_E[r] + 255) / 256;
  }
  CP1.bblk0 = blk; CP1.batch = batch; CP1.pcnt = PCNT; CP1.nop = N_OP;
  blk += (N_OP + 255) / 256;
  count_k<<<blk, 256, 0, stream>>>(CP1, ICNT);

  // ---- scan -> CUR (running offsets), OFF2 (off,cnt) ----
  int nb1 = (CNT_TOT + SCAN_BLK - 1) / SCAN_BLK;   // 1133
  scan1<<<nb1, 256, 0, stream>>>(ICNT, CUR, BS, CNT_TOT);
  scan2<<<1, 256, 0, stream>>>(BS, nb1);
  scan3<<<(CNT_TOT + 255) / 256, 256, 0, stream>>>(CUR, OFF2, ICNT, BS, CNT_TOT);

  // ---- fill CSR ----
  FPackK FP;
  blk = 0;
  for (int q = 0; q < 12; ++q) {
    int r = l1_rels[q];
    FP.j[q].src = ei[r];
    FP.j[q].dst = ei[r] + REL_E[r];
    FP.j[q].coff = CNT_OFF[r];
    FP.j[q].E = REL_E[r];
    FP.j[q].blk0 = blk;
    blk += (REL_E[r] + 255) / 256;
  }
  fill_k<<<blk, 256, 0, stream>>>(FP, CUR, EDG);

  // ---- weights: 12 rel-combine + 5 root-combine + 6 bf16-transpose ----
  CombPack CP;
  for (int q = 0; q < 12; ++q) {
    int r = l1_rels[q]; int t = SRC_T[r];
    CombJob& J = CP.j[q];
    J.A = Wemb[t]; J.bin = bemb[t]; J.Mtx = c_rel[0] + (size_t)r * HD * HD;
    J.extra = nullptr; J.Wout = WC + r * 1280; J.bout = BC + r * HD; J.F = TF[t];
  }
  for (int t = 0; t < 5; ++t) {
    CombJob& J = CP.j[12 + t];
    J.A = Wemb[t]; J.bin = bemb[t]; J.Mtx = c_root[0];
    J.extra = c_bias[0]; J.Wout = WR + t * 1280; J.bout = BR + t * HD; J.F = TF[t];
  }
  weights_prep<<<23, 256, 0, stream>>>(CP, c_root[1], c_rel[1], WT2);

  // ---- gather: one thread per (rel,dst), writes pre-averaged AGR ----
  GPack GP;
  blk = 0;
  for (int q = 0; q < 12; ++q) {
    int r = l1_rels[q]; int t = SRC_T[r];
    GP.j[q].x = xt[t];
    GP.j[q].agr = AGR + AGR_OFF[r];
    GP.j[q].coff = CNT_OFF[r];
    GP.j[q].D = REL_DSZ[r];
    GP.j[q].F = TF[t];
    GP.j[q].blk0 = blk;
    blk += (REL_DSZ[r] + 255) / 256;
  }
  gather_all<<<blk, 256, 0, stream>>>(GP, OFF2, EDG);

  // ---- layer 1: matmul + ELU + LN ----
  L1Args A;
  for (int t = 0; t < 7; ++t) A.x[t] = xt[t];
  A.AGR = AGR;
  A.WC = WC; A.BC = BC; A.WR = WR; A.BR = BR;
  A.OFF2 = OFF2; A.g = ng[0]; A.b = nbv[0]; A.Hb = Hb;
  layer1_mm<<<100000, 256, 0, stream>>>(A);

  // ---- layer 2: fused MFMA + ELU + LN + dot + pool ----
  l2_fused<<<(N_OP + 63) / 64, 256, 0, stream>>>(
      (const unsigned short*)Hb, (const unsigned short*)WT2,
      OFF2, EDG, c_bias[1], ng[1], nbv[1], Wlin, batch, ACC, N_OP);

  // ---- final scale ----
  final_kernel<<<(NB + 255) / 256, 256, 0, stream>>>(ACC, PCNT, blin, out);
}

// Round 7
// 677.553 us; speedup vs baseline: 3.1601x; 1.1506x over previous
//
#include <hip/hip_runtime.h>
#include <hip/hip_bf16.h>
#include <math.h>

#define HD 128
#define N_OP 100000
#define N_L1 400000
#define NB 2048
#define CNT_TOT 1160000
#define EDG_TOT 1100000

typedef short short8 __attribute__((ext_vector_type(8)));
typedef float floatx4 __attribute__((ext_vector_type(4)));

// relation tables (from reference EDGES/OFFS)
static const int REL_E[14]    = {100000,100000,100000,100000,100000,100000,100000,100000,100000,50000,50000,20000,120000,60000};
static const int REL_DSZ[14]  = {100000,100000,100000,100000,100000,100000,60000,100000,100000,50000,50000,20000,120000,60000};
static const int CNT_OFF[14]  = {0,100000,200000,300000,400000,500000,600000,660000,760000,860000,910000,960000,980000,1100000};
static const int SRC_T[14] = {1,3,2,2,0,4,4,5,6,5,6,1,2,3};
static const int TF[7]  = {4,2,10,4,8,1,1};
static const size_t AGR_OFF[14] = {0,200000,600000,1600000,2600000,3000000,3800000,4280000,4380000,0,0,4480000,4520000,5720000};
#define AGR_TOT 5960000
// WL1 packed blob row offsets (rows of 128 floats); bias row last per type
static const int RELW[14] = {4,7,12,93,23,28,70,104,106,-1,-1,40,54,79};
static const int RELI[14] = {6,11,22,103,27,36,78,105,107,-1,-1,42,64,83};
static const int ROOTW[5] = {0,38,44,66,85};
static const int ROOTB[5] = {37,43,65,84,108};
#define WL1_ROWS 109

// ---------------- bf16 helpers ----------------
__device__ inline unsigned short f2bf(float f) {
  union { float f; unsigned int u; } v; v.f = f;
  unsigned int r = v.u + 0x7FFF + ((v.u >> 16) & 1);
  return (unsigned short)(r >> 16);
}
__device__ inline float bfu2f(unsigned short u) {
  union { unsigned int i; float f; } v; v.i = ((unsigned int)u) << 16; return v.f;
}

// ============ count: int degree counts per (rel,dst) + float batch counts ============
struct CJob { const int* dst; int coff; int E; int blk0; };
struct CPackK { CJob j[12]; int bblk0; const int* batch; float* pcnt; int nop; };

__global__ void count_k(CPackK P, int* __restrict__ ICNT) {
  int b = blockIdx.x;
  if (b >= P.bblk0) {
    int i = (b - P.bblk0) * 256 + threadIdx.x;
    if (i < P.nop) atomicAdd(&P.pcnt[P.batch[i]], 1.0f);
    return;
  }
  int ji = 0;
#pragma unroll
  for (int i = 1; i < 12; ++i) if (b >= P.j[i].blk0) ji = i;
  CJob J = P.j[ji];
  int e = (b - J.blk0) * 256 + threadIdx.x;
  if (e < J.E) atomicAdd(&ICNT[J.coff + J.dst[e]], 1);
}

// ============ scans: exclusive prefix over ICNT ============
#define SCAN_BLK 1024
__global__ void scan1(const int* __restrict__ in, int* __restrict__ out,
                      int* __restrict__ bsum, int n) {
  __shared__ int sh[256];
  int t = threadIdx.x;
  int base = blockIdx.x * SCAN_BLK + t * 4;
  int v0 = 0, v1 = 0, v2 = 0, v3 = 0;
  if (base + 3 < n) { int4 q = *(const int4*)&in[base]; v0 = q.x; v1 = q.y; v2 = q.z; v3 = q.w; }
  else {
    if (base < n) v0 = in[base];
    if (base + 1 < n) v1 = in[base + 1];
    if (base + 2 < n) v2 = in[base + 2];
    if (base + 3 < n) v3 = in[base + 3];
  }
  int ts = v0 + v1 + v2 + v3;
  sh[t] = ts; __syncthreads();
  for (int o = 1; o < 256; o <<= 1) {
    int x = (t >= o) ? sh[t - o] : 0;
    __syncthreads();
    sh[t] += x;
    __syncthreads();
  }
  int excl = sh[t] - ts;
  if (base < n) out[base] = excl;
  if (base + 1 < n) out[base + 1] = excl + v0;
  if (base + 2 < n) out[base + 2] = excl + v0 + v1;
  if (base + 3 < n) out[base + 3] = excl + v0 + v1 + v2;
  if (t == 255) bsum[blockIdx.x] = sh[255];
}

__global__ void scan2(int* __restrict__ bs, int nb) {
  __shared__ int sh[256];
  int t = threadIdx.x;
  const int C = 5;
  int v[C]; int ts = 0;
#pragma unroll
  for (int i = 0; i < C; ++i) { int idx = t * C + i; v[i] = (idx < nb) ? bs[idx] : 0; ts += v[i]; }
  sh[t] = ts; __syncthreads();
  for (int o = 1; o < 256; o <<= 1) {
    int x = (t >= o) ? sh[t - o] : 0;
    __syncthreads();
    sh[t] += x;
    __syncthreads();
  }
  int run = sh[t] - ts;
#pragma unroll
  for (int i = 0; i < C; ++i) { int idx = t * C + i; if (idx < nb) bs[idx] = run; run += v[i]; }
}

__global__ void scan3(int* __restrict__ CUR, int2* __restrict__ OFF2,
                      const int* __restrict__ ICNT, const int* __restrict__ bs, int n) {
  int i = blockIdx.x * 256 + threadIdx.x;
  if (i < n) {
    int o = CUR[i] + bs[i >> 10];
    CUR[i] = o;
    OFF2[i] = make_int2(o, ICNT[i]);
  }
}

// ============ fill: EDG[pos] = src, grouped by (rel,dst) ============
struct FJob { const int* src; const int* dst; int coff; int E; int blk0; };
struct FPackK { FJob j[12]; };

__global__ void fill_k(FPackK P, int* __restrict__ CUR, int* __restrict__ EDG) {
  int b = blockIdx.x;
  int ji = 0;
#pragma unroll
  for (int i = 1; i < 12; ++i) if (b >= P.j[i].blk0) ji = i;
  FJob J = P.j[ji];
  int e = (b - J.blk0) * 256 + threadIdx.x;
  if (e < J.E) {
    int pos = atomicAdd(&CUR[J.coff + J.dst[e]], 1);
    EDG[pos] = J.src[e];
  }
}

// ============ gather_all: one thread per (rel,dst), AGR[d,:F] = mean(x[src,:F]) ============
struct GJob { const float* x; float* agr; int coff; int D; int F; int blk0; };
struct GPack { GJob j[12]; };

template <int F>
__device__ inline void gathF(const float* __restrict__ x, float* __restrict__ agr,
                             const int* __restrict__ EDG, int2 oc, int d) {
  if (oc.y == 0) return;
  float s[F];
#pragma unroll
  for (int f = 0; f < F; ++f) s[f] = 0.f;
  for (int e = 0; e < oc.y; ++e) {
    int si = EDG[oc.x + e];
    const float* xp = &x[(size_t)si * F];
#pragma unroll
    for (int f = 0; f < F; ++f) s[f] += xp[f];
  }
  float rc = 1.0f / (float)oc.y;
  float* ap = &agr[(size_t)d * F];
#pragma unroll
  for (int f = 0; f < F; ++f) ap[f] = s[f] * rc;
}

__global__ void gather_all(GPack P, const int2* __restrict__ OFF2, const int* __restrict__ EDG) {
  int b = blockIdx.x;
  int ji = 0;
#pragma unroll
  for (int i = 1; i < 12; ++i) if (b >= P.j[i].blk0) ji = i;
  GJob J = P.j[ji];
  int d = (b - J.blk0) * 256 + threadIdx.x;
  if (d >= J.D) return;
  int2 oc = OFF2[J.coff + d];
  switch (J.F) {
    case 1:  gathF<1>(J.x, J.agr, EDG, oc, d); break;
    case 2:  gathF<2>(J.x, J.agr, EDG, oc, d); break;
    case 4:  gathF<4>(J.x, J.agr, EDG, oc, d); break;
    case 8:  gathF<8>(J.x, J.agr, EDG, oc, d); break;
    default: gathF<10>(J.x, J.agr, EDG, oc, d); break;
  }
}

// ============ weight prep: 17 combine jobs (into packed WL1) + 6 bf16-transpose jobs ============
struct CombJob { const float* A; const float* bin; const float* Mtx; const float* extra; float* Wout; float* bout; int F; };
struct CombPack { CombJob j[17]; };

__global__ void weights_prep(CombPack P, const float* __restrict__ c2root,
                             const float* __restrict__ c2rel, __hip_bfloat16* __restrict__ Wt) {
  int b = blockIdx.x;
  if (b < 17) {
    if (threadIdx.x >= 128) return;
    CombJob J = P.j[b];
    int c = threadIdx.x;
    for (int f = 0; f <= J.F; ++f) {
      const float* arow = (f < J.F) ? &J.A[f * HD] : J.bin;
      float s = (f < J.F) ? 0.f : (J.extra ? J.extra[c] : 0.f);
      for (int k = 0; k < HD; ++k) s = fmaf(arow[k], J.Mtx[k * HD + c], s);
      if (f < J.F) J.Wout[f * HD + c] = s;
      else J.bout[c] = s;
    }
  } else {
    const int RID[6] = {-1, 0, 1, 2, 4, 5};
    int j = b - 17;
    const float* W = (j == 0) ? c2root : (c2rel + (size_t)RID[j] * HD * HD);
    __hip_bfloat16* o = Wt + (size_t)j * HD * 136;
    for (int i = threadIdx.x; i < HD * HD; i += 256) {
      int k = i >> 7, n = i & 127;
      o[n * 136 + k] = __float2bfloat16(W[i]);
    }
  }
}

// ============ layer-1 v2: LDS-staged packed weights, 256 rows/block ============
struct L1v2 {
  const float* x0; const float* x1; const float* x2; const float* x3; const float* x4;
  const float* AGR; const float* WL1; const int2* OFF2;
  const float* g; const float* b;
  unsigned short* Hb;
};

template <int F>
__device__ inline void ld_rel(float* s, const float* __restrict__ agr,
                              const int2* __restrict__ OFF2, int cb, int row) {
  int cnt = OFF2[cb + row].y;
  if (cnt > 0) {
    const float* ap = &agr[(size_t)row * F];
#pragma unroll
    for (int f = 0; f < F; ++f) s[f] = ap[f];
    s[F] = 1.f;
  } else {
#pragma unroll
    for (int f = 0; f <= F; ++f) s[f] = 0.f;
  }
}

template <int KT>
__device__ inline float2 l1_dot(const float* __restrict__ Ls, const float (&s)[KT], int c2) {
  float2 a;
  a.x = Ls[KT * 128 + c2];        // bias row (last)
  a.y = Ls[KT * 128 + c2 + 1];
#pragma unroll
  for (int k = 0; k < KT; ++k) {
    a.x = fmaf(s[k], Ls[k * 128 + c2], a.x);
    a.y = fmaf(s[k], Ls[k * 128 + c2 + 1], a.y);
  }
  return a;
}

__device__ inline void l1_fin(float2 a, int c2, const float* __restrict__ g,
                              const float* __restrict__ bb,
                              unsigned short* __restrict__ Hb, int orow) {
  a.x = (a.x > 0.f) ? a.x : (expf(a.x) - 1.f);
  a.y = (a.y > 0.f) ? a.y : (expf(a.y) - 1.f);
  float s = a.x + a.y, sq = a.x * a.x + a.y * a.y;
#pragma unroll
  for (int m = 32; m >= 1; m >>= 1) {
    s += __shfl_xor(s, m, 64);
    sq += __shfl_xor(sq, m, 64);
  }
  float mean = s * (1.0f / HD);
  float var = sq * (1.0f / HD) - mean * mean;
  float rstd = rsqrtf(var + 1e-5f);
  float2 gg = *(const float2*)&g[c2];
  float2 b2 = *(const float2*)&bb[c2];
  float ox = (a.x - mean) * rstd * gg.x + b2.x;
  float oy = (a.y - mean) * rstd * gg.y + b2.y;
  unsigned int pack = (unsigned int)f2bf(ox) | ((unsigned int)f2bf(oy) << 16);
  *(unsigned int*)&Hb[(size_t)orow * HD + c2] = pack;
}

__global__ __launch_bounds__(256) void layer1_v2(L1v2 A) {
  __shared__ float Ls[38 * 128];
  const int b = blockIdx.x, t = threadIdx.x;
  const int wv = t >> 6, lane = t & 63, c2 = lane * 2;
  int type, seg;
  if (b < 391) { type = 0; seg = b; }
  else if (b < 470) { type = 1; seg = b - 391; }
  else if (b < 939) { type = 2; seg = b - 470; }
  else if (b < 1174) { type = 3; seg = b - 939; }
  else { type = 4; seg = b - 1174; }
  const int NR[5] = {38, 6, 22, 19, 24};
  const int RB[5] = {0, 38, 44, 66, 85};
  const int TR[5] = {100000, 20000, 120000, 60000, 100000};
  const int OB[5] = {0, 100000, 120000, 240000, 300000};
  {
    const float4* src = (const float4*)(A.WL1 + RB[type] * 128);
    float4* dst = (float4*)Ls;
    int n4 = NR[type] * 32;
    for (int i = t; i < n4; i += 256) dst[i] = src[i];
  }
  __syncthreads();
  const int row0 = seg * 256, M = TR[type], ob = OB[type];

  if (type == 0) {
    for (int it = 0; it < 64; ++it) {
      int row = row0 + it * 4 + wv;
      if (row >= M) break;
      float s[37];
      const float* xp = &A.x0[(size_t)row * 4];
#pragma unroll
      for (int f = 0; f < 4; ++f) s[f] = xp[f];
      ld_rel<2>(s + 4, A.AGR + 0, A.OFF2, 0, row);
      ld_rel<4>(s + 7, A.AGR + 200000, A.OFF2, 100000, row);
      ld_rel<10>(s + 12, A.AGR + 600000, A.OFF2, 200000, row);
      ld_rel<4>(s + 23, A.AGR + 2600000, A.OFF2, 400000, row);
      ld_rel<8>(s + 28, A.AGR + 3000000, A.OFF2, 500000, row);
      l1_fin(l1_dot<37>(Ls, s, c2), c2, A.g, A.b, A.Hb, ob + row);
    }
  } else if (type == 1) {
    for (int it = 0; it < 64; ++it) {
      int row = row0 + it * 4 + wv;
      if (row >= M) break;
      float s[5];
      const float* xp = &A.x1[(size_t)row * 2];
#pragma unroll
      for (int f = 0; f < 2; ++f) s[f] = xp[f];
      ld_rel<2>(s + 2, A.AGR + 4480000, A.OFF2, 960000, row);
      l1_fin(l1_dot<5>(Ls, s, c2), c2, A.g, A.b, A.Hb, ob + row);
    }
  } else if (type == 2) {
    for (int it = 0; it < 64; ++it) {
      int row = row0 + it * 4 + wv;
      if (row >= M) break;
      float s[21];
      const float* xp = &A.x2[(size_t)row * 10];
#pragma unroll
      for (int f = 0; f < 10; ++f) s[f] = xp[f];
      ld_rel<10>(s + 10, A.AGR + 4520000, A.OFF2, 980000, row);
      l1_fin(l1_dot<21>(Ls, s, c2), c2, A.g, A.b, A.Hb, ob + row);
    }
  } else if (type == 3) {
    for (int it = 0; it < 64; ++it) {
      int row = row0 + it * 4 + wv;
      if (row >= M) break;
      float s[18];
      const float* xp = &A.x3[(size_t)row * 4];
#pragma unroll
      for (int f = 0; f < 4; ++f) s[f] = xp[f];
      ld_rel<8>(s + 4, A.AGR + 3800000, A.OFF2, 600000, row);
      ld_rel<4>(s + 13, A.AGR + 5720000, A.OFF2, 1100000, row);
      l1_fin(l1_dot<18>(Ls, s, c2), c2, A.g, A.b, A.Hb, ob + row);
    }
  } else {
    for (int it = 0; it < 64; ++it) {
      int row = row0 + it * 4 + wv;
      if (row >= M) break;
      float s[23];
      const float* xp = &A.x4[(size_t)row * 8];
#pragma unroll
      for (int f = 0; f < 8; ++f) s[f] = xp[f];
      ld_rel<10>(s + 8, A.AGR + 1600000, A.OFF2, 300000, row);
      ld_rel<1>(s + 19, A.AGR + 4280000, A.OFF2, 660000, row);
      ld_rel<1>(s + 21, A.AGR + 4380000, A.OFF2, 760000, row);
      l1_fin(l1_dot<23>(Ls, s, c2), c2, A.g, A.b, A.Hb, ob + row);
    }
  }
}

// ============ layer-2: CSR gather -> MFMA (root + 5 rels) -> fused ELU+LN+dot+pool ============
__global__ __launch_bounds__(256, 4)
void l2_fused(const unsigned short* __restrict__ Hb, const unsigned short* __restrict__ Wall,
              const int2* __restrict__ OFF2, const int* __restrict__ EDG,
              const float* __restrict__ c2bias, const float* __restrict__ n2g,
              const float* __restrict__ n2b, const float* __restrict__ Wl,
              const int* __restrict__ batch, float* __restrict__ accb, int M) {
  const int CSR_OFF[5] = {0, 100000, 200000, 400000, 500000};   // rels 0,1,2,4,5
  const int SOFF[5]    = {100000, 240000, 120000, 0, 300000};   // Hb row offset of src type
  __shared__ unsigned short Ws[128 * 136];
  const int t = threadIdx.x, wv = t >> 6, ln = t & 63;
  const int quad = ln >> 4, ln15 = ln & 15, q8 = quad * 8;
  const int m0 = blockIdx.x * 64;
  const int rowA = m0 + wv * 16 + ln15;

  float bias_c[8], gw[8];
  float pg = 0.f, pb = 0.f;
#pragma unroll
  for (int nt = 0; nt < 8; ++nt) {
    int col = nt * 16 + ln15;
    float wl = Wl[col], gc = n2g[col], bc = n2b[col];
    bias_c[nt] = c2bias[col];
    gw[nt] = gc * wl;
    pg += gc * wl;
    pb += bc * wl;
  }
#pragma unroll
  for (int m = 8; m >= 1; m >>= 1) {
    pg += __shfl_xor(pg, m, 64);
    pb += __shfl_xor(pb, m, 64);
  }

  floatx4 acc[8];
#pragma unroll
  for (int b = 0; b < 8; ++b) acc[b] = (floatx4){0.f, 0.f, 0.f, 0.f};

  for (int term = 0; term < 6; ++term) {
    __syncthreads();
    {
      const uint4* wg = (const uint4*)(Wall + (size_t)term * 128 * 136);
      uint4* ws4 = (uint4*)Ws;
#pragma unroll
      for (int i = 0; i < 9; ++i) {
        int idx = i * 256 + t;
        if (idx < 2176) ws4[idx] = wg[idx];
      }
    }
    __syncthreads();

    short8 afr[4];
    if (term == 0) {
      if (rowA < M) {
#pragma unroll
        for (int k4 = 0; k4 < 4; ++k4)
          afr[k4] = *(const short8*)&Hb[(size_t)rowA * HD + k4 * 32 + q8];
      } else {
#pragma unroll
        for (int k4 = 0; k4 < 4; ++k4)
#pragma unroll
          for (int j = 0; j < 8; ++j) afr[k4][j] = 0;
      }
    } else {
      float sum[4][8];
#pragma unroll
      for (int k4 = 0; k4 < 4; ++k4)
#pragma unroll
        for (int j = 0; j < 8; ++j) sum[k4][j] = 0.f;
      if (rowA < M) {
        int2 oc = OFF2[CSR_OFF[term - 1] + rowA];
        if (oc.y > 0) {
          int so = SOFF[term - 1];
          for (int e = 0; e < oc.y; ++e) {
            size_t s = (size_t)(EDG[oc.x + e] + so);
#pragma unroll
            for (int k4 = 0; k4 < 4; ++k4) {
              short8 h = *(const short8*)&Hb[s * HD + k4 * 32 + q8];
#pragma unroll
              for (int j = 0; j < 8; ++j) sum[k4][j] += bfu2f((unsigned short)h[j]);
            }
          }
          float rc = 1.0f / (float)oc.y;
#pragma unroll
          for (int k4 = 0; k4 < 4; ++k4)
#pragma unroll
            for (int j = 0; j < 8; ++j) sum[k4][j] *= rc;
        }
      }
#pragma unroll
      for (int k4 = 0; k4 < 4; ++k4)
#pragma unroll
        for (int j = 0; j < 8; ++j) afr[k4][j] = (short)f2bf(sum[k4][j]);
    }

#pragma unroll
    for (int nt = 0; nt < 8; ++nt) {
      int wrow = nt * 16 + ln15;
      short8 b0 = *(const short8*)&Ws[wrow * 136 + 0 + q8];
      short8 b1 = *(const short8*)&Ws[wrow * 136 + 32 + q8];
      short8 b2 = *(const short8*)&Ws[wrow * 136 + 64 + q8];
      short8 b3 = *(const short8*)&Ws[wrow * 136 + 96 + q8];
      acc[nt] = __builtin_amdgcn_mfma_f32_16x16x32_bf16(afr[0], b0, acc[nt], 0, 0, 0);
      acc[nt] = __builtin_amdgcn_mfma_f32_16x16x32_bf16(afr[1], b1, acc[nt], 0, 0, 0);
      acc[nt] = __builtin_amdgcn_mfma_f32_16x16x32_bf16(afr[2], b2, acc[nt], 0, 0, 0);
      acc[nt] = __builtin_amdgcn_mfma_f32_16x16x32_bf16(afr[3], b3, acc[nt], 0, 0, 0);
    }
  }

  // fused epilogue: ELU + LN + dot(Wl) + batch pool
#pragma unroll
  for (int r = 0; r < 4; ++r) {
    int rowD = m0 + wv * 16 + quad * 4 + r;
    float p = 0.f, q = 0.f, s1 = 0.f;
#pragma unroll
    for (int nt = 0; nt < 8; ++nt) {
      float v = acc[nt][r] + bias_c[nt];
      float e = (v > 0.f) ? v : (expf(v) - 1.f);
      p += e; q += e * e; s1 += e * gw[nt];
    }
#pragma unroll
    for (int m = 8; m >= 1; m >>= 1) {
      p += __shfl_xor(p, m, 64);
      q += __shfl_xor(q, m, 64);
      s1 += __shfl_xor(s1, m, 64);
    }
    if (ln15 == 0 && rowD < M) {
      float mean = p * (1.0f / HD);
      float var = q * (1.0f / HD) - mean * mean;
      float rstd = rsqrtf(var + 1e-5f);
      float o = rstd * (s1 - mean * pg) + pb;
      atomicAdd(&accb[batch[rowD]], o);
    }
  }
}

__global__ void final_kernel(const float* __restrict__ accb, const float* __restrict__ pcnt,
                             const float* __restrict__ bl, float* __restrict__ out) {
  int b = blockIdx.x * 256 + threadIdx.x;
  if (b < NB) out[b] = accb[b] / fmaxf(pcnt[b], 1.0f) + bl[0];
}

// =================== host ===================
extern "C" void kernel_launch(void* const* d_in, const int* in_sizes, int n_in,
                              void* d_out, int out_size, void* d_ws, size_t ws_size,
                              hipStream_t stream) {
  const float* xt[7];
  for (int t = 0; t < 7; ++t) xt[t] = (const float*)d_in[t];
  const int* ei[14];
  for (int r = 0; r < 14; ++r) ei[r] = (const int*)d_in[7 + r];
  const int* batch = (const int*)d_in[21];
  const float* Wemb[7]; const float* bemb[7];
  for (int t = 0; t < 7; ++t) { Wemb[t] = (const float*)d_in[22 + 2 * t]; bemb[t] = (const float*)d_in[23 + 2 * t]; }
  const float* c_root[2] = {(const float*)d_in[36], (const float*)d_in[39]};
  const float* c_rel[2]  = {(const float*)d_in[37], (const float*)d_in[40]};
  const float* c_bias[2] = {(const float*)d_in[38], (const float*)d_in[41]};
  const float* ng[2] = {(const float*)d_in[42], (const float*)d_in[44]};
  const float* nbv[2] = {(const float*)d_in[43], (const float*)d_in[45]};
  const float* Wlin = (const float*)d_in[46];
  const float* blin = (const float*)d_in[47];
  float* out = (float*)d_out;

  char* base = (char*)d_ws;
  size_t off = 0;
  auto alloc = [&](size_t bytes) -> void* {
    void* p = base + off;
    off += (bytes + 255) & ~(size_t)255;
    return p;
  };
  __hip_bfloat16* Hb = (__hip_bfloat16*)alloc((size_t)N_L1 * HD * 2);
  float* AGR  = (float*)alloc((size_t)AGR_TOT * 4);
  int*   ICNT = (int*)alloc((size_t)CNT_TOT * 4);
  int*   CUR  = (int*)alloc((size_t)CNT_TOT * 4);
  int2*  OFF2 = (int2*)alloc((size_t)CNT_TOT * 8);
  int*   EDG  = (int*)alloc((size_t)EDG_TOT * 4);
  int*   BS   = (int*)alloc((size_t)1152 * 4);
  float* WL1  = (float*)alloc((size_t)WL1_ROWS * 128 * 4);
  __hip_bfloat16* WT2 = (__hip_bfloat16*)alloc((size_t)6 * HD * 136 * 2);
  float* ACC  = (float*)alloc((size_t)NB * 4);      // ACC and PCNT adjacent:
  float* PCNT = (float*)alloc((size_t)NB * 4);      // one memset covers both

  static const int l1_rels[12] = {0,1,2,3,4,5,6,7,8,11,12,13};

  // ---- memsets (2) ----
  hipMemsetAsync(ICNT, 0, (size_t)CNT_TOT * 4, stream);
  hipMemsetAsync(ACC, 0, (size_t)2 * NB * 4, stream);

  // ---- count (incl. batch counts) ----
  CPackK CP1;
  int blk = 0;
  for (int q = 0; q < 12; ++q) {
    int r = l1_rels[q];
    CP1.j[q].dst = ei[r] + REL_E[r];
    CP1.j[q].coff = CNT_OFF[r];
    CP1.j[q].E = REL_E[r];
    CP1.j[q].blk0 = blk;
    blk += (REL_E[r] + 255) / 256;
  }
  CP1.bblk0 = blk; CP1.batch = batch; CP1.pcnt = PCNT; CP1.nop = N_OP;
  blk += (N_OP + 255) / 256;
  count_k<<<blk, 256, 0, stream>>>(CP1, ICNT);

  // ---- scan -> CUR (running offsets), OFF2 (off,cnt) ----
  int nb1 = (CNT_TOT + SCAN_BLK - 1) / SCAN_BLK;   // 1133
  scan1<<<nb1, 256, 0, stream>>>(ICNT, CUR, BS, CNT_TOT);
  scan2<<<1, 256, 0, stream>>>(BS, nb1);
  scan3<<<(CNT_TOT + 255) / 256, 256, 0, stream>>>(CUR, OFF2, ICNT, BS, CNT_TOT);

  // ---- fill CSR ----
  FPackK FP;
  blk = 0;
  for (int q = 0; q < 12; ++q) {
    int r = l1_rels[q];
    FP.j[q].src = ei[r];
    FP.j[q].dst = ei[r] + REL_E[r];
    FP.j[q].coff = CNT_OFF[r];
    FP.j[q].E = REL_E[r];
    FP.j[q].blk0 = blk;
    blk += (REL_E[r] + 255) / 256;
  }
  fill_k<<<blk, 256, 0, stream>>>(FP, CUR, EDG);

  // ---- weights: 12 rel-combine + 5 root-combine (into packed WL1) + 6 bf16-transpose ----
  CombPack CP;
  for (int q = 0; q < 12; ++q) {
    int r = l1_rels[q]; int t = SRC_T[r];
    CombJob& J = CP.j[q];
    J.A = Wemb[t]; J.bin = bemb[t]; J.Mtx = c_rel[0] + (size_t)r * HD * HD;
    J.extra = nullptr;
    J.Wout = WL1 + (size_t)RELW[r] * 128;
    J.bout = WL1 + (size_t)RELI[r] * 128;
    J.F = TF[t];
  }
  for (int t = 0; t < 5; ++t) {
    CombJob& J = CP.j[12 + t];
    J.A = Wemb[t]; J.bin = bemb[t]; J.Mtx = c_root[0];
    J.extra = c_bias[0];
    J.Wout = WL1 + (size_t)ROOTW[t] * 128;
    J.bout = WL1 + (size_t)ROOTB[t] * 128;
    J.F = TF[t];
  }
  weights_prep<<<23, 256, 0, stream>>>(CP, c_root[1], c_rel[1], WT2);

  // ---- gather: one thread per (rel,dst), writes pre-averaged AGR ----
  GPack GP;
  blk = 0;
  for (int q = 0; q < 12; ++q) {
    int r = l1_rels[q]; int t = SRC_T[r];
    GP.j[q].x = xt[t];
    GP.j[q].agr = AGR + AGR_OFF[r];
    GP.j[q].coff = CNT_OFF[r];
    GP.j[q].D = REL_DSZ[r];
    GP.j[q].F = TF[t];
    GP.j[q].blk0 = blk;
    blk += (REL_DSZ[r] + 255) / 256;
  }
  gather_all<<<blk, 256, 0, stream>>>(GP, OFF2, EDG);

  // ---- layer 1: LDS-staged weights, 256 rows/block ----
  L1v2 A;
  A.x0 = xt[0]; A.x1 = xt[1]; A.x2 = xt[2]; A.x3 = xt[3]; A.x4 = xt[4];
  A.AGR = AGR; A.WL1 = WL1; A.OFF2 = OFF2;
  A.g = ng[0]; A.b = nbv[0]; A.Hb = (unsigned short*)Hb;
  layer1_v2<<<1565, 256, 0, stream>>>(A);

  // ---- layer 2: fused MFMA + ELU + LN + dot + pool ----
  l2_fused<<<(N_OP + 63) / 64, 256, 0, stream>>>(
      (const unsigned short*)Hb, (const unsigned short*)WT2,
      OFF2, EDG, c_bias[1], ng[1], nbv[1], Wlin, batch, ACC, N_OP);

  // ---- final scale ----
  final_kernel<<<(NB + 255) / 256, 256, 0, stream>>>(ACC, PCNT, blin, out);
}

// Round 8
// 612.909 us; speedup vs baseline: 3.4934x; 1.1055x over previous
//
#include <hip/hip_runtime.h>
#include <hip/hip_bf16.h>
#include <math.h>

#define HD 128
#define N_OP 100000
#define N_L1 400000
#define NB 2048
#define CNT_TOT 1160000
#define EDG_TOT 1100000

typedef short short8 __attribute__((ext_vector_type(8)));
typedef float floatx4 __attribute__((ext_vector_type(4)));

// relation tables (from reference EDGES/OFFS)
static const int REL_E[14]    = {100000,100000,100000,100000,100000,100000,100000,100000,100000,50000,50000,20000,120000,60000};
static const int REL_DSZ[14]  = {100000,100000,100000,100000,100000,100000,60000,100000,100000,50000,50000,20000,120000,60000};
static const int CNT_OFF[14]  = {0,100000,200000,300000,400000,500000,600000,660000,760000,860000,910000,960000,980000,1100000};
static const int SRC_T[14] = {1,3,2,2,0,4,4,5,6,5,6,1,2,3};
static const int TF[7]  = {4,2,10,4,8,1,1};
static const size_t AGR_OFF[14] = {0,200000,600000,1600000,2600000,3000000,3800000,4280000,4380000,0,0,4480000,4520000,5720000};
#define AGR_TOT 5960000
// WL1 packed blob row offsets (rows of 128 floats); bias row last per type
static const int RELW[14] = {4,7,12,93,23,28,70,104,106,-1,-1,40,54,79};
static const int RELI[14] = {6,11,22,103,27,36,78,105,107,-1,-1,42,64,83};
static const int ROOTW[5] = {0,38,44,66,85};
static const int ROOTB[5] = {37,43,65,84,108};
#define WL1_ROWS 109

// ---------------- bf16 helpers ----------------
__device__ inline unsigned short f2bf(float f) {
  union { float f; unsigned int u; } v; v.f = f;
  unsigned int r = v.u + 0x7FFF + ((v.u >> 16) & 1);
  return (unsigned short)(r >> 16);
}
__device__ inline float bfu2f(unsigned short u) {
  union { unsigned int i; float f; } v; v.i = ((unsigned int)u) << 16; return v.f;
}

// ============ count: int degree counts per (rel,dst) + float batch counts ============
struct CJob { const int* dst; int coff; int E; int blk0; };
struct CPackK { CJob j[12]; int bblk0; const int* batch; float* pcnt; int nop; };

__global__ void count_k(CPackK P, int* __restrict__ ICNT) {
  int b = blockIdx.x;
  if (b >= P.bblk0) {
    int i = (b - P.bblk0) * 256 + threadIdx.x;
    if (i < P.nop) atomicAdd(&P.pcnt[P.batch[i]], 1.0f);
    return;
  }
  int ji = 0;
#pragma unroll
  for (int i = 1; i < 12; ++i) if (b >= P.j[i].blk0) ji = i;
  CJob J = P.j[ji];
  int e = (b - J.blk0) * 256 + threadIdx.x;
  if (e < J.E) atomicAdd(&ICNT[J.coff + J.dst[e]], 1);
}

// ============ scans: exclusive prefix over ICNT ============
#define SCAN_BLK 1024
__global__ void scan1(const int* __restrict__ in, int* __restrict__ out,
                      int* __restrict__ bsum, int n) {
  __shared__ int sh[256];
  int t = threadIdx.x;
  int base = blockIdx.x * SCAN_BLK + t * 4;
  int v0 = 0, v1 = 0, v2 = 0, v3 = 0;
  if (base + 3 < n) { int4 q = *(const int4*)&in[base]; v0 = q.x; v1 = q.y; v2 = q.z; v3 = q.w; }
  else {
    if (base < n) v0 = in[base];
    if (base + 1 < n) v1 = in[base + 1];
    if (base + 2 < n) v2 = in[base + 2];
    if (base + 3 < n) v3 = in[base + 3];
  }
  int ts = v0 + v1 + v2 + v3;
  sh[t] = ts; __syncthreads();
  for (int o = 1; o < 256; o <<= 1) {
    int x = (t >= o) ? sh[t - o] : 0;
    __syncthreads();
    sh[t] += x;
    __syncthreads();
  }
  int excl = sh[t] - ts;
  if (base < n) out[base] = excl;
  if (base + 1 < n) out[base + 1] = excl + v0;
  if (base + 2 < n) out[base + 2] = excl + v0 + v1;
  if (base + 3 < n) out[base + 3] = excl + v0 + v1 + v2;
  if (t == 255) bsum[blockIdx.x] = sh[255];
}

__global__ void scan2(int* __restrict__ bs, int nb) {
  __shared__ int sh[256];
  int t = threadIdx.x;
  const int C = 5;
  int v[C]; int ts = 0;
#pragma unroll
  for (int i = 0; i < C; ++i) { int idx = t * C + i; v[i] = (idx < nb) ? bs[idx] : 0; ts += v[i]; }
  sh[t] = ts; __syncthreads();
  for (int o = 1; o < 256; o <<= 1) {
    int x = (t >= o) ? sh[t - o] : 0;
    __syncthreads();
    sh[t] += x;
    __syncthreads();
  }
  int run = sh[t] - ts;
#pragma unroll
  for (int i = 0; i < C; ++i) { int idx = t * C + i; if (idx < nb) bs[idx] = run; run += v[i]; }
}

__global__ void scan3(int* __restrict__ CUR, int2* __restrict__ OFF2,
                      const int* __restrict__ ICNT, const int* __restrict__ bs, int n) {
  int i = blockIdx.x * 256 + threadIdx.x;
  if (i < n) {
    int o = CUR[i] + bs[i >> 10];
    CUR[i] = o;
    OFF2[i] = make_int2(o, ICNT[i]);
  }
}

// ============ fill: EDG[pos] = src, grouped by (rel,dst) ============
struct FJob { const int* src; const int* dst; int coff; int E; int blk0; };
struct FPackK { FJob j[12]; };

__global__ void fill_k(FPackK P, int* __restrict__ CUR, int* __restrict__ EDG) {
  int b = blockIdx.x;
  int ji = 0;
#pragma unroll
  for (int i = 1; i < 12; ++i) if (b >= P.j[i].blk0) ji = i;
  FJob J = P.j[ji];
  int e = (b - J.blk0) * 256 + threadIdx.x;
  if (e < J.E) {
    int pos = atomicAdd(&CUR[J.coff + J.dst[e]], 1);
    EDG[pos] = J.src[e];
  }
}

// ============ gather_all: one thread per (rel,dst), AGR[d,:F] = mean(x[src,:F]) ============
struct GJob { const float* x; float* agr; int coff; int D; int F; int blk0; };
struct GPack { GJob j[12]; };

template <int F>
__device__ inline void gathF(const float* __restrict__ x, float* __restrict__ agr,
                             const int* __restrict__ EDG, int2 oc, int d) {
  if (oc.y == 0) return;
  float s[F];
#pragma unroll
  for (int f = 0; f < F; ++f) s[f] = 0.f;
  for (int e = 0; e < oc.y; ++e) {
    int si = EDG[oc.x + e];
    const float* xp = &x[(size_t)si * F];
#pragma unroll
    for (int f = 0; f < F; ++f) s[f] += xp[f];
  }
  float rc = 1.0f / (float)oc.y;
  float* ap = &agr[(size_t)d * F];
#pragma unroll
  for (int f = 0; f < F; ++f) ap[f] = s[f] * rc;
}

__global__ void gather_all(GPack P, const int2* __restrict__ OFF2, const int* __restrict__ EDG) {
  int b = blockIdx.x;
  int ji = 0;
#pragma unroll
  for (int i = 1; i < 12; ++i) if (b >= P.j[i].blk0) ji = i;
  GJob J = P.j[ji];
  int d = (b - J.blk0) * 256 + threadIdx.x;
  if (d >= J.D) return;
  int2 oc = OFF2[J.coff + d];
  switch (J.F) {
    case 1:  gathF<1>(J.x, J.agr, EDG, oc, d); break;
    case 2:  gathF<2>(J.x, J.agr, EDG, oc, d); break;
    case 4:  gathF<4>(J.x, J.agr, EDG, oc, d); break;
    case 8:  gathF<8>(J.x, J.agr, EDG, oc, d); break;
    default: gathF<10>(J.x, J.agr, EDG, oc, d); break;
  }
}

// ============ weight prep: 17 combine jobs (into packed WL1) + 6 bf16-transpose jobs ============
struct CombJob { const float* A; const float* bin; const float* Mtx; const float* extra; float* Wout; float* bout; int F; };
struct CombPack { CombJob j[17]; };

__global__ void weights_prep(CombPack P, const float* __restrict__ c2root,
                             const float* __restrict__ c2rel, __hip_bfloat16* __restrict__ Wt) {
  int b = blockIdx.x;
  if (b < 17) {
    if (threadIdx.x >= 128) return;
    CombJob J = P.j[b];
    int c = threadIdx.x;
    for (int f = 0; f <= J.F; ++f) {
      const float* arow = (f < J.F) ? &J.A[f * HD] : J.bin;
      float s = (f < J.F) ? 0.f : (J.extra ? J.extra[c] : 0.f);
      for (int k = 0; k < HD; ++k) s = fmaf(arow[k], J.Mtx[k * HD + c], s);
      if (f < J.F) J.Wout[f * HD + c] = s;
      else J.bout[c] = s;
    }
  } else {
    const int RID[6] = {-1, 0, 1, 2, 4, 5};
    int j = b - 17;
    const float* W = (j == 0) ? c2root : (c2rel + (size_t)RID[j] * HD * HD);
    __hip_bfloat16* o = Wt + (size_t)j * HD * 136;
    for (int i = threadIdx.x; i < HD * HD; i += 256) {
      int k = i >> 7, n = i & 127;
      o[n * 136 + k] = __float2bfloat16(W[i]);
    }
  }
}

// ============ layer-1 v3: LDS weights, 4 rows/wave (16 lanes/row, 8 cols/lane) ============
struct L1v2 {
  const float* x0; const float* x1; const float* x2; const float* x3; const float* x4;
  const float* AGR; const float* WL1; const int2* OFF2;
  const float* g; const float* b;
  unsigned short* Hb;
};

template <int F>
__device__ inline void ld_rel(float* s, const float* __restrict__ agr,
                              const int2* __restrict__ OFF2, int cb, int row) {
  int cnt = OFF2[cb + row].y;
  if (cnt > 0) {
    const float* ap = &agr[(size_t)row * F];
#pragma unroll
    for (int f = 0; f < F; ++f) s[f] = ap[f];
    s[F] = 1.f;
  } else {
#pragma unroll
    for (int f = 0; f <= F; ++f) s[f] = 0.f;
  }
}

template <int KT>
__device__ inline void l1_dot8(const float* __restrict__ Ls, const float (&s)[KT],
                               int c8, float (&a)[8]) {
  {
    float4 w0 = *(const float4*)&Ls[KT * 128 + c8];
    float4 w1 = *(const float4*)&Ls[KT * 128 + c8 + 4];
    a[0] = w0.x; a[1] = w0.y; a[2] = w0.z; a[3] = w0.w;
    a[4] = w1.x; a[5] = w1.y; a[6] = w1.z; a[7] = w1.w;
  }
#pragma unroll
  for (int k = 0; k < KT; ++k) {
    float4 w0 = *(const float4*)&Ls[k * 128 + c8];
    float4 w1 = *(const float4*)&Ls[k * 128 + c8 + 4];
    a[0] = fmaf(s[k], w0.x, a[0]); a[1] = fmaf(s[k], w0.y, a[1]);
    a[2] = fmaf(s[k], w0.z, a[2]); a[3] = fmaf(s[k], w0.w, a[3]);
    a[4] = fmaf(s[k], w1.x, a[4]); a[5] = fmaf(s[k], w1.y, a[5]);
    a[6] = fmaf(s[k], w1.z, a[6]); a[7] = fmaf(s[k], w1.w, a[7]);
  }
}

__device__ inline void l1_fin8(float (&a)[8], int c8, const float* __restrict__ g,
                               const float* __restrict__ bb,
                               unsigned short* __restrict__ Hb, int orow) {
  float p = 0.f, q = 0.f;
#pragma unroll
  for (int j = 0; j < 8; ++j) {
    a[j] = (a[j] > 0.f) ? a[j] : (expf(a[j]) - 1.f);
    p += a[j]; q += a[j] * a[j];
  }
#pragma unroll
  for (int m = 8; m >= 1; m >>= 1) {
    p += __shfl_xor(p, m, 64);
    q += __shfl_xor(q, m, 64);
  }
  float mean = p * (1.0f / HD);
  float var = q * (1.0f / HD) - mean * mean;
  float rstd = rsqrtf(var + 1e-5f);
  float4 g0 = *(const float4*)&g[c8], g1 = *(const float4*)&g[c8 + 4];
  float4 b0 = *(const float4*)&bb[c8], b1 = *(const float4*)&bb[c8 + 4];
  float gg[8] = {g0.x, g0.y, g0.z, g0.w, g1.x, g1.y, g1.z, g1.w};
  float bv[8] = {b0.x, b0.y, b0.z, b0.w, b1.x, b1.y, b1.z, b1.w};
  unsigned int pk[4];
#pragma unroll
  for (int j = 0; j < 4; ++j) {
    float o0 = (a[2 * j] - mean) * rstd * gg[2 * j] + bv[2 * j];
    float o1 = (a[2 * j + 1] - mean) * rstd * gg[2 * j + 1] + bv[2 * j + 1];
    pk[j] = (unsigned int)f2bf(o0) | ((unsigned int)f2bf(o1) << 16);
  }
  uint4 st; st.x = pk[0]; st.y = pk[1]; st.z = pk[2]; st.w = pk[3];
  *(uint4*)&Hb[(size_t)orow * HD + c8] = st;
}

__global__ __launch_bounds__(256) void layer1_v3(L1v2 A) {
  __shared__ float Ls[38 * 128];
  const int b = blockIdx.x, t = threadIdx.x;
  const int wv = t >> 6, ln = t & 63;
  const int sub = ln >> 4, c8 = (ln & 15) * 8;
  int type, seg;
  if (b < 1563) { type = 0; seg = b; }
  else if (b < 1876) { type = 1; seg = b - 1563; }
  else if (b < 3751) { type = 2; seg = b - 1876; }
  else if (b < 4689) { type = 3; seg = b - 3751; }
  else { type = 4; seg = b - 4689; }
  const int NR[5] = {38, 6, 22, 19, 24};
  const int RB[5] = {0, 38, 44, 66, 85};
  const int TR[5] = {100000, 20000, 120000, 60000, 100000};
  const int OB[5] = {0, 100000, 120000, 240000, 300000};
  {
    const float4* src = (const float4*)(A.WL1 + RB[type] * 128);
    float4* dst = (float4*)Ls;
    int n4 = NR[type] * 32;
    for (int i = t; i < n4; i += 256) dst[i] = src[i];
  }
  __syncthreads();
  const int row0 = seg * 64, M = TR[type], ob = OB[type];

  if (type == 0) {
#pragma unroll
    for (int it = 0; it < 4; ++it) {
      int row = row0 + it * 16 + wv * 4 + sub;
      if (row >= M) continue;       // uniform per 16-lane subgroup
      float s[37];
      const float* xp = &A.x0[(size_t)row * 4];
#pragma unroll
      for (int f = 0; f < 4; ++f) s[f] = xp[f];
      ld_rel<2>(s + 4, A.AGR + 0, A.OFF2, 0, row);
      ld_rel<4>(s + 7, A.AGR + 200000, A.OFF2, 100000, row);
      ld_rel<10>(s + 12, A.AGR + 600000, A.OFF2, 200000, row);
      ld_rel<4>(s + 23, A.AGR + 2600000, A.OFF2, 400000, row);
      ld_rel<8>(s + 28, A.AGR + 3000000, A.OFF2, 500000, row);
      float a[8];
      l1_dot8<37>(Ls, s, c8, a);
      l1_fin8(a, c8, A.g, A.b, A.Hb, ob + row);
    }
  } else if (type == 1) {
#pragma unroll
    for (int it = 0; it < 4; ++it) {
      int row = row0 + it * 16 + wv * 4 + sub;
      if (row >= M) continue;
      float s[5];
      const float* xp = &A.x1[(size_t)row * 2];
#pragma unroll
      for (int f = 0; f < 2; ++f) s[f] = xp[f];
      ld_rel<2>(s + 2, A.AGR + 4480000, A.OFF2, 960000, row);
      float a[8];
      l1_dot8<5>(Ls, s, c8, a);
      l1_fin8(a, c8, A.g, A.b, A.Hb, ob + row);
    }
  } else if (type == 2) {
#pragma unroll
    for (int it = 0; it < 4; ++it) {
      int row = row0 + it * 16 + wv * 4 + sub;
      if (row >= M) continue;
      float s[21];
      const float* xp = &A.x2[(size_t)row * 10];
#pragma unroll
      for (int f = 0; f < 10; ++f) s[f] = xp[f];
      ld_rel<10>(s + 10, A.AGR + 4520000, A.OFF2, 980000, row);
      float a[8];
      l1_dot8<21>(Ls, s, c8, a);
      l1_fin8(a, c8, A.g, A.b, A.Hb, ob + row);
    }
  } else if (type == 3) {
#pragma unroll
    for (int it = 0; it < 4; ++it) {
      int row = row0 + it * 16 + wv * 4 + sub;
      if (row >= M) continue;
      float s[18];
      const float* xp = &A.x3[(size_t)row * 4];
#pragma unroll
      for (int f = 0; f < 4; ++f) s[f] = xp[f];
      ld_rel<8>(s + 4, A.AGR + 3800000, A.OFF2, 600000, row);
      ld_rel<4>(s + 13, A.AGR + 5720000, A.OFF2, 1100000, row);
      float a[8];
      l1_dot8<18>(Ls, s, c8, a);
      l1_fin8(a, c8, A.g, A.b, A.Hb, ob + row);
    }
  } else {
#pragma unroll
    for (int it = 0; it < 4; ++it) {
      int row = row0 + it * 16 + wv * 4 + sub;
      if (row >= M) continue;
      float s[23];
      const float* xp = &A.x4[(size_t)row * 8];
#pragma unroll
      for (int f = 0; f < 8; ++f) s[f] = xp[f];
      ld_rel<10>(s + 8, A.AGR + 1600000, A.OFF2, 300000, row);
      ld_rel<1>(s + 19, A.AGR + 4280000, A.OFF2, 660000, row);
      ld_rel<1>(s + 21, A.AGR + 4380000, A.OFF2, 760000, row);
      float a[8];
      l1_dot8<23>(Ls, s, c8, a);
      l1_fin8(a, c8, A.g, A.b, A.Hb, ob + row);
    }
  }
}

// ============ layer-2: CSR gather -> MFMA (root + 5 rels) -> fused ELU+LN+dot+pool ============
__global__ __launch_bounds__(256, 4)
void l2_fused(const unsigned short* __restrict__ Hb, const unsigned short* __restrict__ Wall,
              const int2* __restrict__ OFF2, const int* __restrict__ EDG,
              const float* __restrict__ c2bias, const float* __restrict__ n2g,
              const float* __restrict__ n2b, const float* __restrict__ Wl,
              const int* __restrict__ batch, float* __restrict__ accb, int M) {
  const int CSR_OFF[5] = {0, 100000, 200000, 400000, 500000};   // rels 0,1,2,4,5
  const int SOFF[5]    = {100000, 240000, 120000, 0, 300000};   // Hb row offset of src type
  __shared__ unsigned short Ws[128 * 136];
  const int t = threadIdx.x, wv = t >> 6, ln = t & 63;
  const int quad = ln >> 4, ln15 = ln & 15, q8 = quad * 8;
  const int m0 = blockIdx.x * 64;
  const int rowA = m0 + wv * 16 + ln15;

  float bias_c[8], gw[8];
  float pg = 0.f, pb = 0.f;
#pragma unroll
  for (int nt = 0; nt < 8; ++nt) {
    int col = nt * 16 + ln15;
    float wl = Wl[col], gc = n2g[col], bc = n2b[col];
    bias_c[nt] = c2bias[col];
    gw[nt] = gc * wl;
    pg += gc * wl;
    pb += bc * wl;
  }
#pragma unroll
  for (int m = 8; m >= 1; m >>= 1) {
    pg += __shfl_xor(pg, m, 64);
    pb += __shfl_xor(pb, m, 64);
  }

  floatx4 acc[8];
#pragma unroll
  for (int b = 0; b < 8; ++b) acc[b] = (floatx4){0.f, 0.f, 0.f, 0.f};

  for (int term = 0; term < 6; ++term) {
    __syncthreads();
    {
      const uint4* wg = (const uint4*)(Wall + (size_t)term * 128 * 136);
      uint4* ws4 = (uint4*)Ws;
#pragma unroll
      for (int i = 0; i < 9; ++i) {
        int idx = i * 256 + t;
        if (idx < 2176) ws4[idx] = wg[idx];
      }
    }
    __syncthreads();

    short8 afr[4];
    if (term == 0) {
      if (rowA < M) {
#pragma unroll
        for (int k4 = 0; k4 < 4; ++k4)
          afr[k4] = *(const short8*)&Hb[(size_t)rowA * HD + k4 * 32 + q8];
      } else {
#pragma unroll
        for (int k4 = 0; k4 < 4; ++k4)
#pragma unroll
          for (int j = 0; j < 8; ++j) afr[k4][j] = 0;
      }
    } else {
      float sum[4][8];
#pragma unroll
      for (int k4 = 0; k4 < 4; ++k4)
#pragma unroll
        for (int j = 0; j < 8; ++j) sum[k4][j] = 0.f;
      if (rowA < M) {
        int2 oc = OFF2[CSR_OFF[term - 1] + rowA];
        if (oc.y > 0) {
          int so = SOFF[term - 1];
          for (int e = 0; e < oc.y; ++e) {
            size_t s = (size_t)(EDG[oc.x + e] + so);
#pragma unroll
            for (int k4 = 0; k4 < 4; ++k4) {
              short8 h = *(const short8*)&Hb[s * HD + k4 * 32 + q8];
#pragma unroll
              for (int j = 0; j < 8; ++j) sum[k4][j] += bfu2f((unsigned short)h[j]);
            }
          }
          float rc = 1.0f / (float)oc.y;
#pragma unroll
          for (int k4 = 0; k4 < 4; ++k4)
#pragma unroll
            for (int j = 0; j < 8; ++j) sum[k4][j] *= rc;
        }
      }
#pragma unroll
      for (int k4 = 0; k4 < 4; ++k4)
#pragma unroll
        for (int j = 0; j < 8; ++j) afr[k4][j] = (short)f2bf(sum[k4][j]);
    }

#pragma unroll
    for (int nt = 0; nt < 8; ++nt) {
      int wrow = nt * 16 + ln15;
      short8 b0 = *(const short8*)&Ws[wrow * 136 + 0 + q8];
      short8 b1 = *(const short8*)&Ws[wrow * 136 + 32 + q8];
      short8 b2 = *(const short8*)&Ws[wrow * 136 + 64 + q8];
      short8 b3 = *(const short8*)&Ws[wrow * 136 + 96 + q8];
      acc[nt] = __builtin_amdgcn_mfma_f32_16x16x32_bf16(afr[0], b0, acc[nt], 0, 0, 0);
      acc[nt] = __builtin_amdgcn_mfma_f32_16x16x32_bf16(afr[1], b1, acc[nt], 0, 0, 0);
      acc[nt] = __builtin_amdgcn_mfma_f32_16x16x32_bf16(afr[2], b2, acc[nt], 0, 0, 0);
      acc[nt] = __builtin_amdgcn_mfma_f32_16x16x32_bf16(afr[3], b3, acc[nt], 0, 0, 0);
    }
  }

  // fused epilogue: ELU + LN + dot(Wl) + batch pool
#pragma unroll
  for (int r = 0; r < 4; ++r) {
    int rowD = m0 + wv * 16 + quad * 4 + r;
    float p = 0.f, q = 0.f, s1 = 0.f;
#pragma unroll
    for (int nt = 0; nt < 8; ++nt) {
      float v = acc[nt][r] + bias_c[nt];
      float e = (v > 0.f) ? v : (expf(v) - 1.f);
      p += e; q += e * e; s1 += e * gw[nt];
    }
#pragma unroll
    for (int m = 8; m >= 1; m >>= 1) {
      p += __shfl_xor(p, m, 64);
      q += __shfl_xor(q, m, 64);
      s1 += __shfl_xor(s1, m, 64);
    }
    if (ln15 == 0 && rowD < M) {
      float mean = p * (1.0f / HD);
      float var = q * (1.0f / HD) - mean * mean;
      float rstd = rsqrtf(var + 1e-5f);
      float o = rstd * (s1 - mean * pg) + pb;
      atomicAdd(&accb[batch[rowD]], o);
    }
  }
}

__global__ void final_kernel(const float* __restrict__ accb, const float* __restrict__ pcnt,
                             const float* __restrict__ bl, float* __restrict__ out) {
  int b = blockIdx.x * 256 + threadIdx.x;
  if (b < NB) out[b] = accb[b] / fmaxf(pcnt[b], 1.0f) + bl[0];
}

// =================== host ===================
extern "C" void kernel_launch(void* const* d_in, const int* in_sizes, int n_in,
                              void* d_out, int out_size, void* d_ws, size_t ws_size,
                              hipStream_t stream) {
  const float* xt[7];
  for (int t = 0; t < 7; ++t) xt[t] = (const float*)d_in[t];
  const int* ei[14];
  for (int r = 0; r < 14; ++r) ei[r] = (const int*)d_in[7 + r];
  const int* batch = (const int*)d_in[21];
  const float* Wemb[7]; const float* bemb[7];
  for (int t = 0; t < 7; ++t) { Wemb[t] = (const float*)d_in[22 + 2 * t]; bemb[t] = (const float*)d_in[23 + 2 * t]; }
  const float* c_root[2] = {(const float*)d_in[36], (const float*)d_in[39]};
  const float* c_rel[2]  = {(const float*)d_in[37], (const float*)d_in[40]};
  const float* c_bias[2] = {(const float*)d_in[38], (const float*)d_in[41]};
  const float* ng[2] = {(const float*)d_in[42], (const float*)d_in[44]};
  const float* nbv[2] = {(const float*)d_in[43], (const float*)d_in[45]};
  const float* Wlin = (const float*)d_in[46];
  const float* blin = (const float*)d_in[47];
  float* out = (float*)d_out;

  char* base = (char*)d_ws;
  size_t off = 0;
  auto alloc = [&](size_t bytes) -> void* {
    void* p = base + off;
    off += (bytes + 255) & ~(size_t)255;
    return p;
  };
  __hip_bfloat16* Hb = (__hip_bfloat16*)alloc((size_t)N_L1 * HD * 2);
  float* AGR  = (float*)alloc((size_t)AGR_TOT * 4);
  int*   ICNT = (int*)alloc((size_t)CNT_TOT * 4);
  int*   CUR  = (int*)alloc((size_t)CNT_TOT * 4);
  int2*  OFF2 = (int2*)alloc((size_t)CNT_TOT * 8);
  int*   EDG  = (int*)alloc((size_t)EDG_TOT * 4);
  int*   BS   = (int*)alloc((size_t)1152 * 4);
  float* WL1  = (float*)alloc((size_t)WL1_ROWS * 128 * 4);
  __hip_bfloat16* WT2 = (__hip_bfloat16*)alloc((size_t)6 * HD * 136 * 2);
  float* ACC  = (float*)alloc((size_t)NB * 4);      // ACC and PCNT adjacent:
  float* PCNT = (float*)alloc((size_t)NB * 4);      // one memset covers both

  static const int l1_rels[12] = {0,1,2,3,4,5,6,7,8,11,12,13};

  // ---- memsets (2) ----
  hipMemsetAsync(ICNT, 0, (size_t)CNT_TOT * 4, stream);
  hipMemsetAsync(ACC, 0, (size_t)2 * NB * 4, stream);

  // ---- count (incl. batch counts) ----
  CPackK CP1;
  int blk = 0;
  for (int q = 0; q < 12; ++q) {
    int r = l1_rels[q];
    CP1.j[q].dst = ei[r] + REL_E[r];
    CP1.j[q].coff = CNT_OFF[r];
    CP1.j[q].E = REL_E[r];
    CP1.j[q].blk0 = blk;
    blk += (REL_E[r] + 255) / 256;
  }
  CP1.bblk0 = blk; CP1.batch = batch; CP1.pcnt = PCNT; CP1.nop = N_OP;
  blk += (N_OP + 255) / 256;
  count_k<<<blk, 256, 0, stream>>>(CP1, ICNT);

  // ---- scan -> CUR (running offsets), OFF2 (off,cnt) ----
  int nb1 = (CNT_TOT + SCAN_BLK - 1) / SCAN_BLK;   // 1133
  scan1<<<nb1, 256, 0, stream>>>(ICNT, CUR, BS, CNT_TOT);
  scan2<<<1, 256, 0, stream>>>(BS, nb1);
  scan3<<<(CNT_TOT + 255) / 256, 256, 0, stream>>>(CUR, OFF2, ICNT, BS, CNT_TOT);

  // ---- fill CSR ----
  FPackK FP;
  blk = 0;
  for (int q = 0; q < 12; ++q) {
    int r = l1_rels[q];
    FP.j[q].src = ei[r];
    FP.j[q].dst = ei[r] + REL_E[r];
    FP.j[q].coff = CNT_OFF[r];
    FP.j[q].E = REL_E[r];
    FP.j[q].blk0 = blk;
    blk += (REL_E[r] + 255) / 256;
  }
  fill_k<<<blk, 256, 0, stream>>>(FP, CUR, EDG);

  // ---- weights: 12 rel-combine + 5 root-combine (into packed WL1) + 6 bf16-transpose ----
  CombPack CP;
  for (int q = 0; q < 12; ++q) {
    int r = l1_rels[q]; int t = SRC_T[r];
    CombJob& J = CP.j[q];
    J.A = Wemb[t]; J.bin = bemb[t]; J.Mtx = c_rel[0] + (size_t)r * HD * HD;
    J.extra = nullptr;
    J.Wout = WL1 + (size_t)RELW[r] * 128;
    J.bout = WL1 + (size_t)RELI[r] * 128;
    J.F = TF[t];
  }
  for (int t = 0; t < 5; ++t) {
    CombJob& J = CP.j[12 + t];
    J.A = Wemb[t]; J.bin = bemb[t]; J.Mtx = c_root[0];
    J.extra = c_bias[0];
    J.Wout = WL1 + (size_t)ROOTW[t] * 128;
    J.bout = WL1 + (size_t)ROOTB[t] * 128;
    J.F = TF[t];
  }
  weights_prep<<<23, 256, 0, stream>>>(CP, c_root[1], c_rel[1], WT2);

  // ---- gather: one thread per (rel,dst), writes pre-averaged AGR ----
  GPack GP;
  blk = 0;
  for (int q = 0; q < 12; ++q) {
    int r = l1_rels[q]; int t = SRC_T[r];
    GP.j[q].x = xt[t];
    GP.j[q].agr = AGR + AGR_OFF[r];
    GP.j[q].coff = CNT_OFF[r];
    GP.j[q].D = REL_DSZ[r];
    GP.j[q].F = TF[t];
    GP.j[q].blk0 = blk;
    blk += (REL_DSZ[r] + 255) / 256;
  }
  gather_all<<<blk, 256, 0, stream>>>(GP, OFF2, EDG);

  // ---- layer 1: 4 rows/wave, 64 rows/block ----
  L1v2 A;
  A.x0 = xt[0]; A.x1 = xt[1]; A.x2 = xt[2]; A.x3 = xt[3]; A.x4 = xt[4];
  A.AGR = AGR; A.WL1 = WL1; A.OFF2 = OFF2;
  A.g = ng[0]; A.b = nbv[0]; A.Hb = (unsigned short*)Hb;
  layer1_v3<<<6252, 256, 0, stream>>>(A);

  // ---- layer 2: fused MFMA + ELU + LN + dot + pool ----
  l2_fused<<<(N_OP + 63) / 64, 256, 0, stream>>>(
      (const unsigned short*)Hb, (const unsigned short*)WT2,
      OFF2, EDG, c_bias[1], ng[1], nbv[1], Wlin, batch, ACC, N_OP);

  // ---- final scale ----
  final_kernel<<<(NB + 255) / 256, 256, 0, stream>>>(ACC, PCNT, blin, out);
}

// Round 9
// 604.171 us; speedup vs baseline: 3.5440x; 1.0145x over previous
//
#include <hip/hip_runtime.h>
#include <hip/hip_bf16.h>
#include <math.h>

#define HD 128
#define N_OP 100000
#define N_L1 400000
#define NB 2048
#define CNT_TOT 1160000
#define EDG_TOT 1100000

typedef short short8 __attribute__((ext_vector_type(8)));
typedef float floatx4 __attribute__((ext_vector_type(4)));

// relation tables (from reference EDGES/OFFS)
static const int REL_E[14]    = {100000,100000,100000,100000,100000,100000,100000,100000,100000,50000,50000,20000,120000,60000};
static const int REL_DSZ[14]  = {100000,100000,100000,100000,100000,100000,60000,100000,100000,50000,50000,20000,120000,60000};
static const int CNT_OFF[14]  = {0,100000,200000,300000,400000,500000,600000,660000,760000,860000,910000,960000,980000,1100000};
static const int SRC_T[14] = {1,3,2,2,0,4,4,5,6,5,6,1,2,3};
static const int TF[7]  = {4,2,10,4,8,1,1};
static const size_t AGR_OFF[14] = {0,200000,600000,1600000,2600000,3000000,3800000,4280000,4380000,0,0,4480000,4520000,5720000};
#define AGR_TOT 5960000
// WL1 packed blob row offsets (rows of 128 floats); bias row last per type
static const int RELW[14] = {4,7,12,93,23,28,70,104,106,-1,-1,40,54,79};
static const int RELI[14] = {6,11,22,103,27,36,78,105,107,-1,-1,42,64,83};
static const int ROOTW[5] = {0,38,44,66,85};
static const int ROOTB[5] = {37,43,65,84,108};
#define WL1_ROWS 109

// ---------------- bf16 helpers ----------------
__device__ inline unsigned short f2bf(float f) {
  union { float f; unsigned int u; } v; v.f = f;
  unsigned int r = v.u + 0x7FFF + ((v.u >> 16) & 1);
  return (unsigned short)(r >> 16);
}
__device__ inline float bfu2f(unsigned short u) {
  union { unsigned int i; float f; } v; v.i = ((unsigned int)u) << 16; return v.f;
}

// ============ count: int degree counts per (rel,dst) + float batch counts ============
struct CJob { const int* dst; int coff; int E; int blk0; };
struct CPackK { CJob j[12]; int bblk0; const int* batch; float* pcnt; int nop; };

__global__ void count_k(CPackK P, int* __restrict__ ICNT) {
  int b = blockIdx.x;
  if (b >= P.bblk0) {
    int i = (b - P.bblk0) * 256 + threadIdx.x;
    if (i < P.nop) atomicAdd(&P.pcnt[P.batch[i]], 1.0f);
    return;
  }
  int ji = 0;
#pragma unroll
  for (int i = 1; i < 12; ++i) if (b >= P.j[i].blk0) ji = i;
  CJob J = P.j[ji];
  int e = (b - J.blk0) * 256 + threadIdx.x;
  if (e < J.E) atomicAdd(&ICNT[J.coff + J.dst[e]], 1);
}

// ============ scans: exclusive prefix over ICNT ============
#define SCAN_BLK 1024
__global__ void scan1(const int* __restrict__ in, int* __restrict__ out,
                      int* __restrict__ bsum, int n) {
  __shared__ int sh[256];
  int t = threadIdx.x;
  int base = blockIdx.x * SCAN_BLK + t * 4;
  int v0 = 0, v1 = 0, v2 = 0, v3 = 0;
  if (base + 3 < n) { int4 q = *(const int4*)&in[base]; v0 = q.x; v1 = q.y; v2 = q.z; v3 = q.w; }
  else {
    if (base < n) v0 = in[base];
    if (base + 1 < n) v1 = in[base + 1];
    if (base + 2 < n) v2 = in[base + 2];
    if (base + 3 < n) v3 = in[base + 3];
  }
  int ts = v0 + v1 + v2 + v3;
  sh[t] = ts; __syncthreads();
  for (int o = 1; o < 256; o <<= 1) {
    int x = (t >= o) ? sh[t - o] : 0;
    __syncthreads();
    sh[t] += x;
    __syncthreads();
  }
  int excl = sh[t] - ts;
  if (base < n) out[base] = excl;
  if (base + 1 < n) out[base + 1] = excl + v0;
  if (base + 2 < n) out[base + 2] = excl + v0 + v1;
  if (base + 3 < n) out[base + 3] = excl + v0 + v1 + v2;
  if (t == 255) bsum[blockIdx.x] = sh[255];
}

__global__ void scan2(int* __restrict__ bs, int nb) {
  __shared__ int sh[256];
  int t = threadIdx.x;
  const int C = 5;
  int v[C]; int ts = 0;
#pragma unroll
  for (int i = 0; i < C; ++i) { int idx = t * C + i; v[i] = (idx < nb) ? bs[idx] : 0; ts += v[i]; }
  sh[t] = ts; __syncthreads();
  for (int o = 1; o < 256; o <<= 1) {
    int x = (t >= o) ? sh[t - o] : 0;
    __syncthreads();
    sh[t] += x;
    __syncthreads();
  }
  int run = sh[t] - ts;
#pragma unroll
  for (int i = 0; i < C; ++i) { int idx = t * C + i; if (idx < nb) bs[idx] = run; run += v[i]; }
}

__global__ void scan3(int* __restrict__ CUR, int2* __restrict__ OFF2,
                      const int* __restrict__ ICNT, const int* __restrict__ bs, int n) {
  int i = blockIdx.x * 256 + threadIdx.x;
  if (i < n) {
    int o = CUR[i] + bs[i >> 10];
    CUR[i] = o;
    OFF2[i] = make_int2(o, ICNT[i]);
  }
}

// ============ fill: EDG[pos] = src, grouped by (rel,dst) ============
struct FJob { const int* src; const int* dst; int coff; int E; int blk0; };
struct FPackK { FJob j[12]; };

__global__ void fill_k(FPackK P, int* __restrict__ CUR, int* __restrict__ EDG) {
  int b = blockIdx.x;
  int ji = 0;
#pragma unroll
  for (int i = 1; i < 12; ++i) if (b >= P.j[i].blk0) ji = i;
  FJob J = P.j[ji];
  int e = (b - J.blk0) * 256 + threadIdx.x;
  if (e < J.E) {
    int pos = atomicAdd(&CUR[J.coff + J.dst[e]], 1);
    EDG[pos] = J.src[e];
  }
}

// ============ gather_all: one thread per (rel,dst), AGR[d,:F] = mean(x[src,:F]) ============
struct GJob { const float* x; float* agr; int coff; int D; int F; int blk0; };
struct GPack { GJob j[12]; };

template <int F>
__device__ inline void gathF(const float* __restrict__ x, float* __restrict__ agr,
                             const int* __restrict__ EDG, int2 oc, int d) {
  if (oc.y == 0) return;
  float s[F];
#pragma unroll
  for (int f = 0; f < F; ++f) s[f] = 0.f;
  for (int e = 0; e < oc.y; ++e) {
    int si = EDG[oc.x + e];
    const float* xp = &x[(size_t)si * F];
#pragma unroll
    for (int f = 0; f < F; ++f) s[f] += xp[f];
  }
  float rc = 1.0f / (float)oc.y;
  float* ap = &agr[(size_t)d * F];
#pragma unroll
  for (int f = 0; f < F; ++f) ap[f] = s[f] * rc;
}

__global__ void gather_all(GPack P, const int2* __restrict__ OFF2, const int* __restrict__ EDG) {
  int b = blockIdx.x;
  int ji = 0;
#pragma unroll
  for (int i = 1; i < 12; ++i) if (b >= P.j[i].blk0) ji = i;
  GJob J = P.j[ji];
  int d = (b - J.blk0) * 256 + threadIdx.x;
  if (d >= J.D) return;
  int2 oc = OFF2[J.coff + d];
  switch (J.F) {
    case 1:  gathF<1>(J.x, J.agr, EDG, oc, d); break;
    case 2:  gathF<2>(J.x, J.agr, EDG, oc, d); break;
    case 4:  gathF<4>(J.x, J.agr, EDG, oc, d); break;
    case 8:  gathF<8>(J.x, J.agr, EDG, oc, d); break;
    default: gathF<10>(J.x, J.agr, EDG, oc, d); break;
  }
}

// ============ weight prep: 17 combine jobs (into packed WL1) + 6 bf16-transpose jobs ============
struct CombJob { const float* A; const float* bin; const float* Mtx; const float* extra; float* Wout; float* bout; int F; };
struct CombPack { CombJob j[17]; };

__global__ void weights_prep(CombPack P, const float* __restrict__ c2root,
                             const float* __restrict__ c2rel, __hip_bfloat16* __restrict__ Wt) {
  int b = blockIdx.x;
  if (b < 17) {
    if (threadIdx.x >= 128) return;
    CombJob J = P.j[b];
    int c = threadIdx.x;
    for (int f = 0; f <= J.F; ++f) {
      const float* arow = (f < J.F) ? &J.A[f * HD] : J.bin;
      float s = (f < J.F) ? 0.f : (J.extra ? J.extra[c] : 0.f);
      for (int k = 0; k < HD; ++k) s = fmaf(arow[k], J.Mtx[k * HD + c], s);
      if (f < J.F) J.Wout[f * HD + c] = s;
      else J.bout[c] = s;
    }
  } else {
    const int RID[6] = {-1, 0, 1, 2, 4, 5};
    int j = b - 17;
    const float* W = (j == 0) ? c2root : (c2rel + (size_t)RID[j] * HD * HD);
    __hip_bfloat16* o = Wt + (size_t)j * HD * 136;
    for (int i = threadIdx.x; i < HD * HD; i += 256) {
      int k = i >> 7, n = i & 127;
      o[n * 136 + k] = __float2bfloat16(W[i]);
    }
  }
}

// ============ layer-1 v4: LDS weights, 4 rows/wave; lane cols split (c4, c4+64) ============
// bank math: float4 read at byte (k*512 + 16*ln15) -> bank (4*ln15)%32 -> 2-way alias (free)
struct L1v2 {
  const float* x0; const float* x1; const float* x2; const float* x3; const float* x4;
  const float* AGR; const float* WL1; const int2* OFF2;
  const float* g; const float* b;
  unsigned short* Hb;
};

template <int F>
__device__ inline void ld_rel(float* s, const float* __restrict__ agr,
                              const int2* __restrict__ OFF2, int cb, int row) {
  int cnt = OFF2[cb + row].y;
  if (cnt > 0) {
    const float* ap = &agr[(size_t)row * F];
#pragma unroll
    for (int f = 0; f < F; ++f) s[f] = ap[f];
    s[F] = 1.f;
  } else {
#pragma unroll
    for (int f = 0; f <= F; ++f) s[f] = 0.f;
  }
}

template <int KT>
__device__ inline void l1_dot8(const float* __restrict__ Ls, const float (&s)[KT],
                               int c4, float (&a)[8]) {
  {
    float4 w0 = *(const float4*)&Ls[KT * 128 + c4];
    float4 w1 = *(const float4*)&Ls[KT * 128 + c4 + 64];
    a[0] = w0.x; a[1] = w0.y; a[2] = w0.z; a[3] = w0.w;
    a[4] = w1.x; a[5] = w1.y; a[6] = w1.z; a[7] = w1.w;
  }
#pragma unroll
  for (int k = 0; k < KT; ++k) {
    float4 w0 = *(const float4*)&Ls[k * 128 + c4];
    float4 w1 = *(const float4*)&Ls[k * 128 + c4 + 64];
    a[0] = fmaf(s[k], w0.x, a[0]); a[1] = fmaf(s[k], w0.y, a[1]);
    a[2] = fmaf(s[k], w0.z, a[2]); a[3] = fmaf(s[k], w0.w, a[3]);
    a[4] = fmaf(s[k], w1.x, a[4]); a[5] = fmaf(s[k], w1.y, a[5]);
    a[6] = fmaf(s[k], w1.z, a[6]); a[7] = fmaf(s[k], w1.w, a[7]);
  }
}

__device__ inline void l1_fin8(float (&a)[8], int c4, const float* __restrict__ g,
                               const float* __restrict__ bb,
                               unsigned short* __restrict__ Hb, int orow) {
  float p = 0.f, q = 0.f;
#pragma unroll
  for (int j = 0; j < 8; ++j) {
    a[j] = (a[j] > 0.f) ? a[j] : (expf(a[j]) - 1.f);
    p += a[j]; q += a[j] * a[j];
  }
#pragma unroll
  for (int m = 8; m >= 1; m >>= 1) {
    p += __shfl_xor(p, m, 64);
    q += __shfl_xor(q, m, 64);
  }
  float mean = p * (1.0f / HD);
  float var = q * (1.0f / HD) - mean * mean;
  float rstd = rsqrtf(var + 1e-5f);
  float4 g0 = *(const float4*)&g[c4], g1 = *(const float4*)&g[c4 + 64];
  float4 b0 = *(const float4*)&bb[c4], b1 = *(const float4*)&bb[c4 + 64];
  float gg[8] = {g0.x, g0.y, g0.z, g0.w, g1.x, g1.y, g1.z, g1.w};
  float bv[8] = {b0.x, b0.y, b0.z, b0.w, b1.x, b1.y, b1.z, b1.w};
  float o[8];
#pragma unroll
  for (int j = 0; j < 8; ++j) o[j] = (a[j] - mean) * rstd * gg[j] + bv[j];
  uint2 lo, hi;
  lo.x = (unsigned int)f2bf(o[0]) | ((unsigned int)f2bf(o[1]) << 16);
  lo.y = (unsigned int)f2bf(o[2]) | ((unsigned int)f2bf(o[3]) << 16);
  hi.x = (unsigned int)f2bf(o[4]) | ((unsigned int)f2bf(o[5]) << 16);
  hi.y = (unsigned int)f2bf(o[6]) | ((unsigned int)f2bf(o[7]) << 16);
  *(uint2*)&Hb[(size_t)orow * HD + c4] = lo;
  *(uint2*)&Hb[(size_t)orow * HD + c4 + 64] = hi;
}

__global__ __launch_bounds__(256) void layer1_v4(L1v2 A) {
  __shared__ float Ls[38 * 128];
  const int b = blockIdx.x, t = threadIdx.x;
  const int wv = t >> 6, ln = t & 63;
  const int sub = ln >> 4, c4 = (ln & 15) * 4;
  int type, seg;
  if (b < 1563) { type = 0; seg = b; }
  else if (b < 1876) { type = 1; seg = b - 1563; }
  else if (b < 3751) { type = 2; seg = b - 1876; }
  else if (b < 4689) { type = 3; seg = b - 3751; }
  else { type = 4; seg = b - 4689; }
  const int NR[5] = {38, 6, 22, 19, 24};
  const int RB[5] = {0, 38, 44, 66, 85};
  const int TR[5] = {100000, 20000, 120000, 60000, 100000};
  const int OB[5] = {0, 100000, 120000, 240000, 300000};
  {
    const float4* src = (const float4*)(A.WL1 + RB[type] * 128);
    float4* dst = (float4*)Ls;
    int n4 = NR[type] * 32;
    for (int i = t; i < n4; i += 256) dst[i] = src[i];
  }
  __syncthreads();
  const int row0 = seg * 64, M = TR[type], ob = OB[type];

  if (type == 0) {
#pragma unroll
    for (int it = 0; it < 4; ++it) {
      int row = row0 + it * 16 + wv * 4 + sub;
      if (row >= M) continue;       // uniform per 16-lane subgroup
      float s[37];
      const float* xp = &A.x0[(size_t)row * 4];
#pragma unroll
      for (int f = 0; f < 4; ++f) s[f] = xp[f];
      ld_rel<2>(s + 4, A.AGR + 0, A.OFF2, 0, row);
      ld_rel<4>(s + 7, A.AGR + 200000, A.OFF2, 100000, row);
      ld_rel<10>(s + 12, A.AGR + 600000, A.OFF2, 200000, row);
      ld_rel<4>(s + 23, A.AGR + 2600000, A.OFF2, 400000, row);
      ld_rel<8>(s + 28, A.AGR + 3000000, A.OFF2, 500000, row);
      float a[8];
      l1_dot8<37>(Ls, s, c4, a);
      l1_fin8(a, c4, A.g, A.b, A.Hb, ob + row);
    }
  } else if (type == 1) {
#pragma unroll
    for (int it = 0; it < 4; ++it) {
      int row = row0 + it * 16 + wv * 4 + sub;
      if (row >= M) continue;
      float s[5];
      const float* xp = &A.x1[(size_t)row * 2];
#pragma unroll
      for (int f = 0; f < 2; ++f) s[f] = xp[f];
      ld_rel<2>(s + 2, A.AGR + 4480000, A.OFF2, 960000, row);
      float a[8];
      l1_dot8<5>(Ls, s, c4, a);
      l1_fin8(a, c4, A.g, A.b, A.Hb, ob + row);
    }
  } else if (type == 2) {
#pragma unroll
    for (int it = 0; it < 4; ++it) {
      int row = row0 + it * 16 + wv * 4 + sub;
      if (row >= M) continue;
      float s[21];
      const float* xp = &A.x2[(size_t)row * 10];
#pragma unroll
      for (int f = 0; f < 10; ++f) s[f] = xp[f];
      ld_rel<10>(s + 10, A.AGR + 4520000, A.OFF2, 980000, row);
      float a[8];
      l1_dot8<21>(Ls, s, c4, a);
      l1_fin8(a, c4, A.g, A.b, A.Hb, ob + row);
    }
  } else if (type == 3) {
#pragma unroll
    for (int it = 0; it < 4; ++it) {
      int row = row0 + it * 16 + wv * 4 + sub;
      if (row >= M) continue;
      float s[18];
      const float* xp = &A.x3[(size_t)row * 4];
#pragma unroll
      for (int f = 0; f < 4; ++f) s[f] = xp[f];
      ld_rel<8>(s + 4, A.AGR + 3800000, A.OFF2, 600000, row);
      ld_rel<4>(s + 13, A.AGR + 5720000, A.OFF2, 1100000, row);
      float a[8];
      l1_dot8<18>(Ls, s, c4, a);
      l1_fin8(a, c4, A.g, A.b, A.Hb, ob + row);
    }
  } else {
#pragma unroll
    for (int it = 0; it < 4; ++it) {
      int row = row0 + it * 16 + wv * 4 + sub;
      if (row >= M) continue;
      float s[23];
      const float* xp = &A.x4[(size_t)row * 8];
#pragma unroll
      for (int f = 0; f < 8; ++f) s[f] = xp[f];
      ld_rel<10>(s + 8, A.AGR + 1600000, A.OFF2, 300000, row);
      ld_rel<1>(s + 19, A.AGR + 4280000, A.OFF2, 660000, row);
      ld_rel<1>(s + 21, A.AGR + 4380000, A.OFF2, 760000, row);
      float a[8];
      l1_dot8<23>(Ls, s, c4, a);
      l1_fin8(a, c4, A.g, A.b, A.Hb, ob + row);
    }
  }
}

// ============ layer-2: CSR gather -> MFMA (root + 5 rels) -> fused ELU+LN+dot+pool ============
__global__ __launch_bounds__(256, 4)
void l2_fused(const unsigned short* __restrict__ Hb, const unsigned short* __restrict__ Wall,
              const int2* __restrict__ OFF2, const int* __restrict__ EDG,
              const float* __restrict__ c2bias, const float* __restrict__ n2g,
              const float* __restrict__ n2b, const float* __restrict__ Wl,
              const int* __restrict__ batch, float* __restrict__ accb, int M) {
  const int CSR_OFF[5] = {0, 100000, 200000, 400000, 500000};   // rels 0,1,2,4,5
  const int SOFF[5]    = {100000, 240000, 120000, 0, 300000};   // Hb row offset of src type
  __shared__ unsigned short Ws[128 * 136];
  const int t = threadIdx.x, wv = t >> 6, ln = t & 63;
  const int quad = ln >> 4, ln15 = ln & 15, q8 = quad * 8;
  const int m0 = blockIdx.x * 64;
  const int rowA = m0 + wv * 16 + ln15;

  float bias_c[8], gw[8];
  float pg = 0.f, pb = 0.f;
#pragma unroll
  for (int nt = 0; nt < 8; ++nt) {
    int col = nt * 16 + ln15;
    float wl = Wl[col], gc = n2g[col], bc = n2b[col];
    bias_c[nt] = c2bias[col];
    gw[nt] = gc * wl;
    pg += gc * wl;
    pb += bc * wl;
  }
#pragma unroll
  for (int m = 8; m >= 1; m >>= 1) {
    pg += __shfl_xor(pg, m, 64);
    pb += __shfl_xor(pb, m, 64);
  }

  floatx4 acc[8];
#pragma unroll
  for (int b = 0; b < 8; ++b) acc[b] = (floatx4){0.f, 0.f, 0.f, 0.f};

  for (int term = 0; term < 6; ++term) {
    __syncthreads();
    {
      const uint4* wg = (const uint4*)(Wall + (size_t)term * 128 * 136);
      uint4* ws4 = (uint4*)Ws;
#pragma unroll
      for (int i = 0; i < 9; ++i) {
        int idx = i * 256 + t;
        if (idx < 2176) ws4[idx] = wg[idx];
      }
    }
    __syncthreads();

    short8 afr[4];
    if (term == 0) {
      if (rowA < M) {
#pragma unroll
        for (int k4 = 0; k4 < 4; ++k4)
          afr[k4] = *(const short8*)&Hb[(size_t)rowA * HD + k4 * 32 + q8];
      } else {
#pragma unroll
        for (int k4 = 0; k4 < 4; ++k4)
#pragma unroll
          for (int j = 0; j < 8; ++j) afr[k4][j] = 0;
      }
    } else {
      float sum[4][8];
#pragma unroll
      for (int k4 = 0; k4 < 4; ++k4)
#pragma unroll
        for (int j = 0; j < 8; ++j) sum[k4][j] = 0.f;
      if (rowA < M) {
        int2 oc = OFF2[CSR_OFF[term - 1] + rowA];
        if (oc.y > 0) {
          int so = SOFF[term - 1];
          for (int e = 0; e < oc.y; ++e) {
            size_t s = (size_t)(EDG[oc.x + e] + so);
#pragma unroll
            for (int k4 = 0; k4 < 4; ++k4) {
              short8 h = *(const short8*)&Hb[s * HD + k4 * 32 + q8];
#pragma unroll
              for (int j = 0; j < 8; ++j) sum[k4][j] += bfu2f((unsigned short)h[j]);
            }
          }
          float rc = 1.0f / (float)oc.y;
#pragma unroll
          for (int k4 = 0; k4 < 4; ++k4)
#pragma unroll
            for (int j = 0; j < 8; ++j) sum[k4][j] *= rc;
        }
      }
#pragma unroll
      for (int k4 = 0; k4 < 4; ++k4)
#pragma unroll
        for (int j = 0; j < 8; ++j) afr[k4][j] = (short)f2bf(sum[k4][j]);
    }

#pragma unroll
    for (int nt = 0; nt < 8; ++nt) {
      int wrow = nt * 16 + ln15;
      short8 b0 = *(const short8*)&Ws[wrow * 136 + 0 + q8];
      short8 b1 = *(const short8*)&Ws[wrow * 136 + 32 + q8];
      short8 b2 = *(const short8*)&Ws[wrow * 136 + 64 + q8];
      short8 b3 = *(const short8*)&Ws[wrow * 136 + 96 + q8];
      acc[nt] = __builtin_amdgcn_mfma_f32_16x16x32_bf16(afr[0], b0, acc[nt], 0, 0, 0);
      acc[nt] = __builtin_amdgcn_mfma_f32_16x16x32_bf16(afr[1], b1, acc[nt], 0, 0, 0);
      acc[nt] = __builtin_amdgcn_mfma_f32_16x16x32_bf16(afr[2], b2, acc[nt], 0, 0, 0);
      acc[nt] = __builtin_amdgcn_mfma_f32_16x16x32_bf16(afr[3], b3, acc[nt], 0, 0, 0);
    }
  }

  // fused epilogue: ELU + LN + dot(Wl) + batch pool
#pragma unroll
  for (int r = 0; r < 4; ++r) {
    int rowD = m0 + wv * 16 + quad * 4 + r;
    float p = 0.f, q = 0.f, s1 = 0.f;
#pragma unroll
    for (int nt = 0; nt < 8; ++nt) {
      float v = acc[nt][r] + bias_c[nt];
      float e = (v > 0.f) ? v : (expf(v) - 1.f);
      p += e; q += e * e; s1 += e * gw[nt];
    }
#pragma unroll
    for (int m = 8; m >= 1; m >>= 1) {
      p += __shfl_xor(p, m, 64);
      q += __shfl_xor(q, m, 64);
      s1 += __shfl_xor(s1, m, 64);
    }
    if (ln15 == 0 && rowD < M) {
      float mean = p * (1.0f / HD);
      float var = q * (1.0f / HD) - mean * mean;
      float rstd = rsqrtf(var + 1e-5f);
      float o = rstd * (s1 - mean * pg) + pb;
      atomicAdd(&accb[batch[rowD]], o);
    }
  }
}

__global__ void final_kernel(const float* __restrict__ accb, const float* __restrict__ pcnt,
                             const float* __restrict__ bl, float* __restrict__ out) {
  int b = blockIdx.x * 256 + threadIdx.x;
  if (b < NB) out[b] = accb[b] / fmaxf(pcnt[b], 1.0f) + bl[0];
}

// =================== host ===================
extern "C" void kernel_launch(void* const* d_in, const int* in_sizes, int n_in,
                              void* d_out, int out_size, void* d_ws, size_t ws_size,
                              hipStream_t stream) {
  const float* xt[7];
  for (int t = 0; t < 7; ++t) xt[t] = (const float*)d_in[t];
  const int* ei[14];
  for (int r = 0; r < 14; ++r) ei[r] = (const int*)d_in[7 + r];
  const int* batch = (const int*)d_in[21];
  const float* Wemb[7]; const float* bemb[7];
  for (int t = 0; t < 7; ++t) { Wemb[t] = (const float*)d_in[22 + 2 * t]; bemb[t] = (const float*)d_in[23 + 2 * t]; }
  const float* c_root[2] = {(const float*)d_in[36], (const float*)d_in[39]};
  const float* c_rel[2]  = {(const float*)d_in[37], (const float*)d_in[40]};
  const float* c_bias[2] = {(const float*)d_in[38], (const float*)d_in[41]};
  const float* ng[2] = {(const float*)d_in[42], (const float*)d_in[44]};
  const float* nbv[2] = {(const float*)d_in[43], (const float*)d_in[45]};
  const float* Wlin = (const float*)d_in[46];
  const float* blin = (const float*)d_in[47];
  float* out = (float*)d_out;

  char* base = (char*)d_ws;
  size_t off = 0;
  auto alloc = [&](size_t bytes) -> void* {
    void* p = base + off;
    off += (bytes + 255) & ~(size_t)255;
    return p;
  };
  __hip_bfloat16* Hb = (__hip_bfloat16*)alloc((size_t)N_L1 * HD * 2);
  float* AGR  = (float*)alloc((size_t)AGR_TOT * 4);
  int*   ICNT = (int*)alloc((size_t)CNT_TOT * 4);
  int*   CUR  = (int*)alloc((size_t)CNT_TOT * 4);
  int2*  OFF2 = (int2*)alloc((size_t)CNT_TOT * 8);
  int*   EDG  = (int*)alloc((size_t)EDG_TOT * 4);
  int*   BS   = (int*)alloc((size_t)1152 * 4);
  float* WL1  = (float*)alloc((size_t)WL1_ROWS * 128 * 4);
  __hip_bfloat16* WT2 = (__hip_bfloat16*)alloc((size_t)6 * HD * 136 * 2);
  float* ACC  = (float*)alloc((size_t)NB * 4);      // ACC and PCNT adjacent:
  float* PCNT = (float*)alloc((size_t)NB * 4);      // one memset covers both

  static const int l1_rels[12] = {0,1,2,3,4,5,6,7,8,11,12,13};

  // ---- memsets (2) ----
  hipMemsetAsync(ICNT, 0, (size_t)CNT_TOT * 4, stream);
  hipMemsetAsync(ACC, 0, (size_t)2 * NB * 4, stream);

  // ---- count (incl. batch counts) ----
  CPackK CP1;
  int blk = 0;
  for (int q = 0; q < 12; ++q) {
    int r = l1_rels[q];
    CP1.j[q].dst = ei[r] + REL_E[r];
    CP1.j[q].coff = CNT_OFF[r];
    CP1.j[q].E = REL_E[r];
    CP1.j[q].blk0 = blk;
    blk += (REL_E[r] + 255) / 256;
  }
  CP1.bblk0 = blk; CP1.batch = batch; CP1.pcnt = PCNT; CP1.nop = N_OP;
  blk += (N_OP + 255) / 256;
  count_k<<<blk, 256, 0, stream>>>(CP1, ICNT);

  // ---- scan -> CUR (running offsets), OFF2 (off,cnt) ----
  int nb1 = (CNT_TOT + SCAN_BLK - 1) / SCAN_BLK;   // 1133
  scan1<<<nb1, 256, 0, stream>>>(ICNT, CUR, BS, CNT_TOT);
  scan2<<<1, 256, 0, stream>>>(BS, nb1);
  scan3<<<(CNT_TOT + 255) / 256, 256, 0, stream>>>(CUR, OFF2, ICNT, BS, CNT_TOT);

  // ---- fill CSR ----
  FPackK FP;
  blk = 0;
  for (int q = 0; q < 12; ++q) {
    int r = l1_rels[q];
    FP.j[q].src = ei[r];
    FP.j[q].dst = ei[r] + REL_E[r];
    FP.j[q].coff = CNT_OFF[r];
    FP.j[q].E = REL_E[r];
    FP.j[q].blk0 = blk;
    blk += (REL_E[r] + 255) / 256;
  }
  fill_k<<<blk, 256, 0, stream>>>(FP, CUR, EDG);

  // ---- weights: 12 rel-combine + 5 root-combine (into packed WL1) + 6 bf16-transpose ----
  CombPack CP;
  for (int q = 0; q < 12; ++q) {
    int r = l1_rels[q]; int t = SRC_T[r];
    CombJob& J = CP.j[q];
    J.A = Wemb[t]; J.bin = bemb[t]; J.Mtx = c_rel[0] + (size_t)r * HD * HD;
    J.extra = nullptr;
    J.Wout = WL1 + (size_t)RELW[r] * 128;
    J.bout = WL1 + (size_t)RELI[r] * 128;
    J.F = TF[t];
  }
  for (int t = 0; t < 5; ++t) {
    CombJob& J = CP.j[12 + t];
    J.A = Wemb[t]; J.bin = bemb[t]; J.Mtx = c_root[0];
    J.extra = c_bias[0];
    J.Wout = WL1 + (size_t)ROOTW[t] * 128;
    J.bout = WL1 + (size_t)ROOTB[t] * 128;
    J.F = TF[t];
  }
  weights_prep<<<23, 256, 0, stream>>>(CP, c_root[1], c_rel[1], WT2);

  // ---- gather: one thread per (rel,dst), writes pre-averaged AGR ----
  GPack GP;
  blk = 0;
  for (int q = 0; q < 12; ++q) {
    int r = l1_rels[q]; int t = SRC_T[r];
    GP.j[q].x = xt[t];
    GP.j[q].agr = AGR + AGR_OFF[r];
    GP.j[q].coff = CNT_OFF[r];
    GP.j[q].D = REL_DSZ[r];
    GP.j[q].F = TF[t];
    GP.j[q].blk0 = blk;
    blk += (REL_DSZ[r] + 255) / 256;
  }
  gather_all<<<blk, 256, 0, stream>>>(GP, OFF2, EDG);

  // ---- layer 1: 4 rows/wave, 64 rows/block, conflict-free LDS mapping ----
  L1v2 A;
  A.x0 = xt[0]; A.x1 = xt[1]; A.x2 = xt[2]; A.x3 = xt[3]; A.x4 = xt[4];
  A.AGR = AGR; A.WL1 = WL1; A.OFF2 = OFF2;
  A.g = ng[0]; A.b = nbv[0]; A.Hb = (unsigned short*)Hb;
  layer1_v4<<<6252, 256, 0, stream>>>(A);

  // ---- layer 2: fused MFMA + ELU + LN + dot + pool ----
  l2_fused<<<(N_OP + 63) / 64, 256, 0, stream>>>(
      (const unsigned short*)Hb, (const unsigned short*)WT2,
      OFF2, EDG, c_bias[1], ng[1], nbv[1], Wlin, batch, ACC, N_OP);

  // ---- final scale ----
  final_kernel<<<(NB + 255) / 256, 256, 0, stream>>>(ACC, PCNT, blin, out);
}